// Round 9
// baseline (433.826 us; speedup 1.0000x reference)
//
#include <hip/hip_runtime.h>
#include <hip/hip_bf16.h>

#define N_SEQ 4096
#define DIMM  1536
#define NH    4
#define DK    64
#define HD    256     // NH*DK
#define QK_SCALE 0.125f
#define WSZ   393216  // 1536*256 per weight
#define KSPLIT 8
#define LOG2E 1.44269504f

typedef __bf16 bf16x8 __attribute__((ext_vector_type(8)));
typedef unsigned short u16;
typedef unsigned int u32;
typedef u16   u16x8  __attribute__((ext_vector_type(8)));
typedef u16   u16x4  __attribute__((ext_vector_type(4)));
typedef float f32x4  __attribute__((ext_vector_type(4)));
typedef float f32x16 __attribute__((ext_vector_type(16)));
typedef unsigned int u32x4 __attribute__((ext_vector_type(4)));

__device__ inline float b2f(u16 u){
    union { float f; unsigned int i; } v; v.i = ((unsigned int)u) << 16; return v.f;
}
__device__ inline u16 f2b(float f){
    __bf16 h = (__bf16)f;               // native cvt, RNE
    return __builtin_bit_cast(u16, h);
}
__device__ inline bf16x8 ldfrag(const u16* p){
    return __builtin_bit_cast(bf16x8, *(const u16x8*)p);
}
__device__ inline f32x16 zero16(){
    f32x16 v;
    #pragma unroll
    for (int i = 0; i < 16; ++i) v[i] = 0.f;
    return v;
}
#define EXP2(x) exp2f(x)   // lowers to a single v_exp_f32 on gfx950

// ---------------------------------------------------------------------------
// Prep (one launch): blocks [0,288) transpose Wq|Wk|Wv fp32 -> bf16 Wt[n][k];
// blocks [288,304) build fmtab; block 304 builds suffix-summed rel weights.
// ---------------------------------------------------------------------------
__global__ __launch_bounds__(256) void prep_kernel(const float* __restrict__ Wq,
    const float* __restrict__ Wk, const float* __restrict__ Wv, u16* __restrict__ Wt,
    unsigned char* __restrict__ fmt, const float* __restrict__ Wrel,
    u16* __restrict__ WsP, u16* __restrict__ WsM){
    int bid = blockIdx.x;
    int t = threadIdx.x;
    if (bid < 288){
        __shared__ float T[64 * 65];
        int s = bid / 96, tile = bid % 96;
        int n0 = (tile / 24) * 64;
        int k0 = (tile % 24) * 64;
        const float* W = (s == 0) ? Wq : (s == 1 ? Wk : Wv);
        int rA = t >> 3, c8 = (t & 7) * 8;
        #pragma unroll
        for (int rep = 0; rep < 2; ++rep){
            int rr = rep * 32 + rA;
            const float* p = W + (size_t)(k0 + rr) * HD + n0 + c8;
            f32x4 a = *(const f32x4*)p, b = *(const f32x4*)(p + 4);
            #pragma unroll
            for (int e = 0; e < 4; ++e){
                T[rr * 65 + c8 + e]     = a[e];
                T[rr * 65 + c8 + 4 + e] = b[e];
            }
        }
        __syncthreads();
        #pragma unroll
        for (int rep = 0; rep < 2; ++rep){
            int rn = rep * 32 + rA;
            u16x8 o;
            #pragma unroll
            for (int e = 0; e < 8; ++e) o[e] = f2b(T[(c8 + e) * 65 + rn]);
            *(u16x8*)&Wt[(size_t)s * WSZ + (size_t)(n0 + rn) * DIMM + k0 + c8] = o;
        }
        return;
    }
    if (bid == 304){
        int h = t >> 6, d = t & 63;
        float w1[32], w2[32];
        #pragma unroll
        for (int fm = 0; fm < 32; ++fm){
            w1[fm] = Wrel[(size_t)fm * HD + h * DK + d];
            w2[fm] = Wrel[(size_t)(32 + fm) * HD + h * DK + d];
        }
        float a1 = 0.f, a2 = 0.f;
        #pragma unroll
        for (int fm = 31; fm >= 0; --fm){
            a1 += w1[fm];
            a2 += w2[fm];
            WsP[(h * 32 + fm) * 64 + d] = f2b(a1 + a2);
            WsM[(h * 32 + fm) * 64 + d] = f2b(a1 - a2);
        }
        return;
    }
    int d = (bid - 288) * 256 + t;
    float lg = logf((float)(N_SEQ + 1)) * (1.0f / 32.0f);
    float ad = (float)d;
    int fm = 0;
    for (int f = 0; f < 32; ++f){
        float cw = expf(lg * (float)(f + 1)) - 1.0f;
        fm += (cw <= ad) ? 1 : 0;
    }
    fmt[d] = (unsigned char)fm;
}

// ---------------------------------------------------------------------------
// QKV projection (unchanged): per-projection blocks + reg-prefetch pipeline.
// ---------------------------------------------------------------------------
__global__ __launch_bounds__(256) void qkv_kernel(const float* __restrict__ X,
    const u16* __restrict__ Wt,
    u16* __restrict__ Q, u16* __restrict__ K, u16* __restrict__ Vt){
    __shared__ __align__(16) u16 xs[64 * 72];
    __shared__ __align__(16) u16 bs[64 * 72];
    int s  = blockIdx.x >> 2;             // 0:Q 1:K 2:V
    int n0 = (blockIdx.x & 3) * 64;
    int m0 = blockIdx.y * 64;
    int t = threadIdx.x;
    int w = t >> 6, lane = t & 63, qd = lane >> 4, l15 = lane & 15;
    int r  = t >> 3;
    int cv = (t & 7) * 8;
    f32x4 acc[4] = {{0,0,0,0},{0,0,0,0},{0,0,0,0},{0,0,0,0}};

    f32x4 xa[2], xb[2];
    u16x8 wv[2];
    auto LOAD = [&](int k0){
        #pragma unroll
        for (int rep = 0; rep < 2; ++rep){
            int rr = rep * 32 + r;
            size_t xi = (size_t)(m0 + rr) * DIMM + k0 + cv;
            xa[rep] = *(const f32x4*)(X + xi);
            xb[rep] = *(const f32x4*)(X + xi + 4);
            wv[rep] = *(const u16x8*)&Wt[(size_t)s * WSZ + (size_t)(n0 + rr) * DIMM + k0 + cv];
        }
    };
    auto STORE = [&](){
        #pragma unroll
        for (int rep = 0; rep < 2; ++rep){
            int rr = rep * 32 + r;
            u16x8 xv;
            #pragma unroll
            for (int e = 0; e < 4; ++e){ xv[e] = f2b(xa[rep][e]); xv[4 + e] = f2b(xb[rep][e]); }
            *(u16x8*)&xs[rr * 72 + cv] = xv;
            *(u16x8*)&bs[rr * 72 + cv] = wv[rep];
        }
    };

    LOAD(0);
    for (int k0 = 0; k0 < DIMM; k0 += 64){
        STORE();
        __syncthreads();
        if (k0 + 64 < DIMM) LOAD(k0 + 64);
        bf16x8 a0 = ldfrag(&xs[(w * 16 + l15) * 72 +  0 + qd * 8]);
        bf16x8 a1 = ldfrag(&xs[(w * 16 + l15) * 72 + 32 + qd * 8]);
        #pragma unroll
        for (int nt = 0; nt < 4; ++nt){
            bf16x8 b0 = ldfrag(&bs[(nt * 16 + l15) * 72 +  0 + qd * 8]);
            bf16x8 b1 = ldfrag(&bs[(nt * 16 + l15) * 72 + 32 + qd * 8]);
            acc[nt] = __builtin_amdgcn_mfma_f32_16x16x32_bf16(a0, b0, acc[nt], 0, 0, 0);
            acc[nt] = __builtin_amdgcn_mfma_f32_16x16x32_bf16(a1, b1, acc[nt], 0, 0, 0);
        }
        __syncthreads();
    }

    int row0 = m0 + w * 16 + qd * 4;
    if (s == 0){
        #pragma unroll
        for (int nt = 0; nt < 4; ++nt){
            int col = n0 + nt * 16 + l15;
            #pragma unroll
            for (int reg = 0; reg < 4; ++reg)
                Q[(size_t)(row0 + reg) * HD + col] = f2b(acc[nt][reg] * QK_SCALE);
        }
    } else if (s == 1){
        #pragma unroll
        for (int nt = 0; nt < 4; ++nt){
            int col = n0 + nt * 16 + l15;
            #pragma unroll
            for (int reg = 0; reg < 4; ++reg)
                K[(size_t)(row0 + reg) * HD + col] = f2b(acc[nt][reg]);
        }
    } else {
        #pragma unroll
        for (int nt = 0; nt < 4; ++nt){
            int col = n0 + nt * 16 + l15;
            u16x4 pv;
            #pragma unroll
            for (int reg = 0; reg < 4; ++reg) pv[reg] = f2b(acc[nt][reg]);
            *(u16x4*)&Vt[(size_t)col * N_SEQ + row0] = pv;
        }
    }
}

// ---------------------------------------------------------------------------
// Flash attention v3: double-buffered K/V LDS, ONE barrier per tile.
// Buffer b at smem + b*18432 BYTES: K = 4608 u16 (9216 B), V = next 4608 u16.
// (R6/R7 bug: V offset was computed as +9216 u16 = +18432 B -> clobbered the
// next buffer and the fmt table. Fixed: +4608 u16 = +9216 B.)
// rel tables packed (P|M<<16) u32; RELG=1: global h-major [h][4096][32],
// one aligned 128-B line per row. RELG=0 fallback keeps rel in LDS.
// ---------------------------------------------------------------------------
template<bool RELG>
__global__ __launch_bounds__(256, 4) void attn_kernel(const u16* __restrict__ Q,
    const u16* __restrict__ Kg, const u16* __restrict__ Vt,
    const u16* __restrict__ WsPg, const u16* __restrict__ WsMg,
    const unsigned char* __restrict__ fmtg,
    const float* __restrict__ CB, const float* __restrict__ PB,
    u32* __restrict__ relG,
    u16* __restrict__ OpU, float* __restrict__ mpart, float* __restrict__ lpart){
    extern __shared__ __align__(16) unsigned char smem[];
    unsigned char* fmt = smem + 36864;    // 4096
    u32* relL = (u32*)(smem + 40960);     // RELG=0 only: [128][32] u32
    u16* Qs   = (u16*)(smem);             // init alias over buf0: [128][72]
    u16* WsPs = (u16*)(smem + 18432);     // init alias over buf1: [32][72]
    u16* WsMs = (u16*)(smem + 23040);

    int i0   = blockIdx.x * 128;
    int h    = blockIdx.y;
    int half = blockIdx.z;                // 0..7
    int bid  = blockIdx.x * NH + h;       // 0..127
    int jbase = half * (N_SEQ / KSPLIT);
    const int NT = (N_SEQ / KSPLIT) / 64; // 8 tiles
    int t = threadIdx.x;
    int w = t >> 6, lane = t & 63, l31 = lane & 31, hbit = lane >> 5;
    int h8 = hbit * 8;
    int i_loc = w * 32 + l31;

    int sr = t >> 3, scv = (t & 7) * 8;
    u16x8 kr0, kr1, vr0, vr1;
    auto LOAD = [&](int j0){
        kr0 = *(const u16x8*)&Kg[(size_t)(j0 + sr)      * HD + h * DK + scv];
        kr1 = *(const u16x8*)&Kg[(size_t)(j0 + 32 + sr) * HD + h * DK + scv];
        vr0 = *(const u16x8*)&Vt[(size_t)(h * 64 + sr)      * N_SEQ + j0 + scv];
        vr1 = *(const u16x8*)&Vt[(size_t)(h * 64 + 32 + sr) * N_SEQ + j0 + scv];
    };
    auto STOREB = [&](int b){
        u16* Kb = (u16*)(smem + b * 18432);
        u16* Vb = Kb + 4608;   // +9216 BYTES (u16 elements) — the R6/R7 fix
        *(u16x8*)&Kb[(sr)      * 72 + scv] = kr0;
        *(u16x8*)&Kb[(32 + sr) * 72 + scv] = kr1;
        *(u16x8*)&Vb[(sr)      * 72 + scv] = vr0;
        *(u16x8*)&Vb[(32 + sr) * 72 + scv] = vr1;
    };
    LOAD(jbase);

    // ---- init staging ----
    #pragma unroll
    for (int rep = 0; rep < 4; ++rep){
        int vid = rep * 256 + t;
        int r  = vid >> 3;
        int cv = (vid & 7) * 8;
        *(u16x8*)&Qs[r * 72 + cv] = *(const u16x8*)&Q[(size_t)(i0 + r) * HD + h * DK + cv];
    }
    {
        int r = t >> 3, cv = (t & 7) * 8;
        *(u16x8*)&WsPs[r * 72 + cv] = *(const u16x8*)&WsPg[(h * 32 + r) * 64 + cv];
        *(u16x8*)&WsMs[r * 72 + cv] = *(const u16x8*)&WsMg[(h * 32 + r) * 64 + cv];
    }
    ((uint4*)fmt)[t] = ((const uint4*)fmtg)[t];
    __syncthreads();

    // ---- Q fragments, bias + LOG2E folded ----
    bf16x8 qcF[4], qpF[4];
    #pragma unroll
    for (int kc = 0; kc < 4; ++kc){
        bf16x8 raw = ldfrag(&Qs[i_loc * 72 + kc * 16 + h8]);
        const float* cbp = CB + h * DK + kc * 16 + h8;
        const float* pbp = PB + h * DK + kc * 16 + h8;
        bf16x8 qc, qp;
        #pragma unroll
        for (int e = 0; e < 8; ++e){
            float qf = (float)raw[e];
            qc[e] = (__bf16)((qf + cbp[e]) * LOG2E);
            qp[e] = (__bf16)((qf + pbp[e]) * LOG2E);
        }
        qcF[kc] = qc; qpF[kc] = qp;
    }

    // ---- rel tables via MFMA (log2 domain) ----
    f32x16 rP = zero16(), rM = zero16();
    #pragma unroll
    for (int kc = 0; kc < 4; ++kc){
        bf16x8 aP = ldfrag(&WsPs[l31 * 72 + kc * 16 + h8]);
        bf16x8 aM = ldfrag(&WsMs[l31 * 72 + kc * 16 + h8]);
        rP = __builtin_amdgcn_mfma_f32_32x32x16_bf16(aP, qpF[kc], rP, 0, 0, 0);
        rM = __builtin_amdgcn_mfma_f32_32x32x16_bf16(aM, qpF[kc], rM, 0, 0, 0);
    }
    __syncthreads();   // LDS reads (Qs, Wsuf) done before KV overwrites

    // rel row (32 slots = one 128-B line). Slot 0 = d==0 value in both
    // halves (fmt[0]==0 and ad==0 only at dd==0; fmt[ad]<=31 always).
    u32* relRow;
    if (RELG) relRow = relG + ((size_t)h * N_SEQ + (size_t)(i0 + i_loc)) * 32;
    else      relRow = relL + i_loc * 32;
    {
        u32 v0 = (u32)f2b((rP[0] + rM[0]) * 0.5f);
        u32 v0p = v0 | (v0 << 16);
        #pragma unroll
        for (int r = 0; r < 16; ++r){
            int fm = (r & 3) + 8 * (r >> 2) + 4 * hbit;   // fm==0 only hbit0,r0
            u32 pk = (u32)f2b(rP[r]) | ((u32)f2b(rM[r]) << 16);
            relRow[fm] = (fm == 0) ? v0p : pk;
        }
    }
    STOREB(0);               // tile 0 -> buf0 (Qs/Wsuf dead)
    LOAD(jbase + 64);        // tile 1 regs
    __syncthreads();         // buf0 + rel visible

    // ---- main K-loop: one barrier per tile ----
    float mrow = -1e30f, lacc = 0.f;
    f32x16 oacc0 = zero16(), oacc1 = zero16();

#define MFMA32(A, B, C) __builtin_amdgcn_mfma_f32_32x32x16_bf16(A, B, C, 0, 0, 0)

#define PACK8(ST, WD) { \
    _Pragma("unroll") \
    for (int q_ = 0; q_ < 8; ++q_){ \
        float pa_ = EXP2(ST[2 * q_]     - bias); \
        float pc_ = EXP2(ST[2 * q_ + 1] - bias); \
        lsum += pa_ + pc_; \
        WD[q_] = (u32)f2b(pa_) | ((u32)f2b(pc_) << 16); \
    } }

#define MKFRAG(DST, WD, ZZ) { \
    u32 a0_ = WD[(ZZ) * 4 + 0], a1_ = WD[(ZZ) * 4 + 1]; \
    u32 b0_ = WD[(ZZ) * 4 + 2], b1_ = WD[(ZZ) * 4 + 3]; \
    u32 sh0_ = (u32)__shfl_xor((int)(hbit ? a0_ : b0_), 32); \
    u32 sh1_ = (u32)__shfl_xor((int)(hbit ? a1_ : b1_), 32); \
    u32x4 fw_; \
    fw_[0] = hbit ? sh0_ : a0_; \
    fw_[1] = hbit ? sh1_ : a1_; \
    fw_[2] = hbit ? b0_  : sh0_; \
    fw_[3] = hbit ? b1_  : sh1_; \
    DST = __builtin_bit_cast(bf16x8, fw_); }

#define PVSTEP(PF, COL) { \
    oacc0 = MFMA32(PF, ldfrag(&Vcur[(l31)      * 72 + (COL) + h8]), oacc0); \
    oacc1 = MFMA32(PF, ldfrag(&Vcur[(32 + l31) * 72 + (COL) + h8]), oacc1); }

    for (int kt = 0; kt < NT; ++kt){
        int cur = kt & 1;
        int j0 = jbase + kt * 64;
        if (kt + 1 < NT) STOREB(cur ^ 1);   // regs(tile kt+1) -> other buf
        if (kt + 2 < NT) LOAD(j0 + 128);    // tile kt+2 -> regs
        const u16* Kcur = (const u16*)(smem + cur * 18432);
        const u16* Vcur = Kcur + 4608;      // +9216 BYTES — the R6/R7 fix

        // S^T = K . Q^T
        f32x16 st0 = zero16(), st1 = zero16();
        __builtin_amdgcn_s_setprio(1);
        #pragma unroll
        for (int kc = 0; kc < 4; ++kc){
            bf16x8 k0 = ldfrag(&Kcur[(l31)      * 72 + kc * 16 + h8]);
            bf16x8 k1 = ldfrag(&Kcur[(32 + l31) * 72 + kc * 16 + h8]);
            st0 = MFMA32(k0, qcF[kc], st0);
            st1 = MFMA32(k1, qcF[kc], st1);
        }
        __builtin_amdgcn_s_setprio(0);

        // rel merge: fast path folds relv into the exp bias
        int D = j0 - i0;
        int Di = D - i_loc;
        float relv = 0.f;
        bool fast = false, plus = true; int fmU = 0;
        if (D >= 128){
            int fa = fmt[D - 127], fb = fmt[D + 63];
            fast = (fa == fb); fmU = fa; plus = true;
        } else if (D <= -64){
            int fa = fmt[-D - 63], fb = fmt[-D + 127];
            fast = (fa == fb); fmU = fa; plus = false;
        }
        if (fast){
            u32 pm = relRow[fmU];
            relv = b2f(plus ? (u16)pm : (u16)(pm >> 16));
        } else {
            #pragma unroll
            for (int r = 0; r < 16; ++r){
                const int jb = (r & 3) + 8 * (r >> 2);
                int jbh = jb + 4 * hbit;
                {
                    int dd = Di + jbh;
                    int ad = dd < 0 ? -dd : dd;
                    u32 pm = relRow[fmt[ad]];
                    st0[r] += b2f(dd >= 0 ? (u16)pm : (u16)(pm >> 16));
                }
                {
                    int dd = Di + 32 + jbh;
                    int ad = dd < 0 ? -dd : dd;
                    u32 pm = relRow[fmt[ad]];
                    st1[r] += b2f(dd >= 0 ? (u16)pm : (u16)(pm >> 16));
                }
            }
        }

        // row max
        float mx = st0[0];
        #pragma unroll
        for (int r = 1; r < 16; ++r) mx = fmaxf(mx, st0[r]);
        #pragma unroll
        for (int r = 0; r < 16; ++r) mx = fmaxf(mx, st1[r]);
        mx = fmaxf(mx, __shfl_xor(mx, 32)) + relv;

        // defer-max (log2 domain, THR = 11)
        if (!__all(mx - mrow <= 11.0f)){
            float mnew = fmaxf(mrow, mx);
            float alpha = EXP2(mrow - mnew);
            mrow = mnew;
            lacc *= alpha;
            #pragma unroll
            for (int r = 0; r < 16; ++r){
                float ar = __shfl(alpha, (r & 3) + 8 * (r >> 2) + 4 * hbit);
                oacc0[r] *= ar; oacc1[r] *= ar;
            }
        }

        float bias = mrow - relv;
        float lsum = 0.f;
        u32 wds0[8], wds1[8];
        PACK8(st0, wds0)
        PACK8(st1, wds1)
        lacc += lsum + __shfl_xor(lsum, 32);

        bf16x8 pf0, pf1, pf2, pf3;
        MKFRAG(pf0, wds0, 0)
        MKFRAG(pf1, wds0, 1)
        MKFRAG(pf2, wds1, 0)
        MKFRAG(pf3, wds1, 1)
        __builtin_amdgcn_s_setprio(1);
        PVSTEP(pf0,  0)
        PVSTEP(pf1, 16)
        PVSTEP(pf2, 32)
        PVSTEP(pf3, 48)
        __builtin_amdgcn_s_setprio(0);

        __syncthreads();   // single barrier: STOREs visible, reads of cur done
    }

    // ---- write partials ----
    size_t pb = ((size_t)half * 128 + bid) * 128;
    #pragma unroll
    for (int r = 0; r < 16; ++r){
        int iO = w * 32 + (r & 3) + 8 * (r >> 2) + 4 * hbit;
        OpU[(pb + iO) * 64 + l31]      = f2b(oacc0[r]);
        OpU[(pb + iO) * 64 + 32 + l31] = f2b(oacc1[r]);
    }
    if (hbit == 0){
        mpart[pb + i_loc] = mrow;
        lpart[pb + i_loc] = lacc;
    }
#undef MFMA32
#undef PACK8
#undef MKFRAG
#undef PVSTEP
}

// ---------------------------------------------------------------------------
// Combine 8 K-eighths -> normalized bf16 Oatt.
// ---------------------------------------------------------------------------
__global__ __launch_bounds__(256) void combine_kernel(const u16* __restrict__ OpU,
    const float* __restrict__ mpart, const float* __restrict__ lpart,
    u16* __restrict__ Oatt){
    int h = blockIdx.y;
    int t = threadIdx.x;
    int r = t >> 3, cb = (t & 7) * 8;
    int i = blockIdx.x * 32 + r;
    int bid = (i >> 7) * NH + h;
    int ri = i & 127;
    size_t pr[8];
    float ms[8], ls[8];
    float m = -1e30f;
    #pragma unroll
    for (int s = 0; s < 8; ++s){
        pr[s] = ((size_t)s * 128 + bid) * 128 + ri;
        ms[s] = mpart[pr[s]];
        ls[s] = lpart[pr[s]];
        m = fmaxf(m, ms[s]);
    }
    float den = 0.f, wgt[8];
    #pragma unroll
    for (int s = 0; s < 8; ++s){ wgt[s] = EXP2(ms[s] - m); den += wgt[s] * ls[s]; }
    float inv = 1.0f / fmaxf(den, 1e-30f);
    float o[8];
    #pragma unroll
    for (int e = 0; e < 8; ++e) o[e] = 0.f;
    #pragma unroll
    for (int s = 0; s < 8; ++s){
        u16x8 a = *(const u16x8*)&OpU[pr[s] * 64 + cb];
        #pragma unroll
        for (int e = 0; e < 8; ++e) o[e] += wgt[s] * b2f(a[e]);
    }
    u16x8 rv;
    #pragma unroll
    for (int e = 0; e < 8; ++e) rv[e] = f2b(o[e] * inv);
    *(u16x8*)&Oatt[(size_t)i * HD + h * DK + cb] = rv;
}

// ---------------------------------------------------------------------------
// Output projection: out = Oattn @ Wo + bo. (unchanged)
// ---------------------------------------------------------------------------
__global__ __launch_bounds__(256) void oproj_kernel(const u16* __restrict__ A,
    const float* __restrict__ Wo, const float* __restrict__ bo,
    float* __restrict__ out, int m_base){
    __shared__ __align__(16) u16 xs[64 * 72];
    __shared__ __align__(16) u16 bs[64 * 72];
    int m0 = m_base + blockIdx.y * 64;
    int n0 = blockIdx.x * 64;
    int t = threadIdx.x;
    int w = t >> 6, lane = t & 63, qd = lane >> 4, l15 = lane & 15;
    f32x4 acc[4] = {{0,0,0,0},{0,0,0,0},{0,0,0,0},{0,0,0,0}};
    for (int k0 = 0; k0 < HD; k0 += 64){
        #pragma unroll
        for (int rep = 0; rep < 2; ++rep){
            int vid = rep * 256 + t;
            int r  = vid >> 3;
            int cv = (vid & 7) * 8;
            *(u16x8*)&xs[r * 72 + cv] = *(const u16x8*)&A[(size_t)(m0 + r) * HD + k0 + cv];
            size_t wi = (size_t)(k0 + r) * DIMM + n0 + cv;
            f32x4 wa = *(const f32x4*)(Wo + wi), wb = *(const f32x4*)(Wo + wi + 4);
            u16x8 wv;
            #pragma unroll
            for (int e = 0; e < 4; ++e){ wv[e] = f2b(wa[e]); wv[4 + e] = f2b(wb[e]); }
            #pragma unroll
            for (int e = 0; e < 8; ++e) bs[(cv + e) * 72 + r] = wv[e];
        }
        __syncthreads();
        bf16x8 a0 = ldfrag(&xs[(w * 16 + l15) * 72 +  0 + qd * 8]);
        bf16x8 a1 = ldfrag(&xs[(w * 16 + l15) * 72 + 32 + qd * 8]);
        #pragma unroll
        for (int nt = 0; nt < 4; ++nt){
            bf16x8 b0 = ldfrag(&bs[(nt * 16 + l15) * 72 +  0 + qd * 8]);
            bf16x8 b1 = ldfrag(&bs[(nt * 16 + l15) * 72 + 32 + qd * 8]);
            acc[nt] = __builtin_amdgcn_mfma_f32_16x16x32_bf16(a0, b0, acc[nt], 0, 0, 0);
            acc[nt] = __builtin_amdgcn_mfma_f32_16x16x32_bf16(a1, b1, acc[nt], 0, 0, 0);
        }
        __syncthreads();
    }
    #pragma unroll
    for (int nt = 0; nt < 4; ++nt)
        #pragma unroll
        for (int reg = 0; reg < 4; ++reg){
            int row = m0 + w * 16 + qd * 4 + reg;
            int col = n0 + nt * 16 + l15;
            out[(size_t)row * DIMM + col] = acc[nt][reg] + bo[col];
        }
}

extern "C" void kernel_launch(void* const* d_in, const int* in_sizes, int n_in,
                              void* d_out, int out_size, void* d_ws, size_t ws_size,
                              hipStream_t stream){
    const float* X  = (const float*)d_in[0];
    const float* Wq = (const float*)d_in[1];
    const float* Wk = (const float*)d_in[2];
    const float* Wv = (const float*)d_in[3];
    const float* Wr = (const float*)d_in[4];
    const float* Wo = (const float*)d_in[5];
    const float* bo = (const float*)d_in[6];
    const float* CB = (const float*)d_in[7];
    const float* PB = (const float*)d_in[8];
    float* out = (float*)d_out;
    u16* base = (u16*)d_out;   // 12,582,912 u16 slots

    // d_out scratch (u16 offsets): Qb[0,1048576) Kb[1048576,2097152)
    // Vt[2097152,3145728) Wt[3145728,4325376) (dead after qkv; OpU overlays)
    // OpU[3145728,11534336) mpart/lpart f32 after.
    u16* Qb   = base;
    u16* Kb   = base + 1048576;
    u16* Vt   = base + 2097152;
    u16* Wt   = base + 3145728;
    u16* OpU  = base + 3145728;
    float* mpart = out + 5767168;
    float* lpart = out + 5898240;

    // d_ws layout: fmt[0,4096) WsP[4096,20480) WsM[20480,36864)
    //   relG u32 [h][4096][32] @36864 (2,097,152 B) -> 2,134,016
    //   Oatt u16 @2,134,016 (2,097,152 B) -> 4,231,168
    unsigned char* fmtg = (unsigned char*)d_ws;
    u16* WsP = (u16*)((char*)d_ws + 4096);
    u16* WsM = (u16*)((char*)d_ws + 20480);
    u32* relG = (u32*)((char*)d_ws + 36864);
    bool ws_ok = ws_size >= 4231168;

    prep_kernel<<<dim3(305), 256, 0, stream>>>(Wq, Wk, Wv, Wt, fmtg, Wr, WsP, WsM);
    qkv_kernel<<<dim3(12, 64), 256, 0, stream>>>(X, Wt, Qb, Kb, Vt);

    if (ws_ok){
        u16* Oatt = (u16*)((char*)d_ws + 2134016);
        attn_kernel<true><<<dim3(32, NH, KSPLIT), 256, 40960, stream>>>(
            Qb, Kb, Vt, WsP, WsM, fmtg, CB, PB, relG, OpU, mpart, lpart);
        combine_kernel<<<dim3(128, NH), 256, 0, stream>>>(OpU, mpart, lpart, Oatt);
        oproj_kernel<<<dim3(24, 64), 256, 0, stream>>>(Oatt, Wo, bo, out, 0);
    } else {
        // fallback: rel tables in LDS (57344 B dynamic), Oatt in d_out with
        // the descending-row 3-split oproj for WAR safety.
        u16* Oatt = base;          // overlays Qb (dead after attn)
        attn_kernel<false><<<dim3(32, NH, KSPLIT), 256, 57344, stream>>>(
            Qb, Kb, Vt, WsP, WsM, fmtg, CB, PB, nullptr, OpU, mpart, lpart);
        combine_kernel<<<dim3(128, NH), 256, 0, stream>>>(OpU, mpart, lpart, Oatt);
        oproj_kernel<<<dim3(24, 58), 256, 0, stream>>>(Oatt, Wo, bo, out, 384);
        oproj_kernel<<<dim3(24,  5), 256, 0, stream>>>(Oatt, Wo, bo, out, 64);
        oproj_kernel<<<dim3(24,  1), 256, 0, stream>>>(Oatt, Wo, bo, out, 0);
    }
}

// Round 10
// 338.732 us; speedup vs baseline: 1.2807x; 1.2807x over previous
//
#include <hip/hip_runtime.h>
#include <hip/hip_bf16.h>

#define N_SEQ 4096
#define DIMM  1536
#define NH    4
#define DK    64
#define HD    256     // NH*DK
#define QK_SCALE 0.125f
#define WSZ   393216  // 1536*256 per weight
#define KSPLIT 8
#define LOG2E 1.44269504f

typedef __bf16 bf16x8 __attribute__((ext_vector_type(8)));
typedef unsigned short u16;
typedef unsigned int u32;
typedef u16   u16x8  __attribute__((ext_vector_type(8)));
typedef u16   u16x4  __attribute__((ext_vector_type(4)));
typedef float f32x4  __attribute__((ext_vector_type(4)));
typedef float f32x16 __attribute__((ext_vector_type(16)));
typedef unsigned int u32x4 __attribute__((ext_vector_type(4)));

__device__ inline float b2f(u16 u){
    union { float f; unsigned int i; } v; v.i = ((unsigned int)u) << 16; return v.f;
}
__device__ inline u16 f2b(float f){
    __bf16 h = (__bf16)f;               // native cvt, RNE
    return __builtin_bit_cast(u16, h);
}
__device__ inline bf16x8 ldfrag(const u16* p){
    return __builtin_bit_cast(bf16x8, *(const u16x8*)p);
}
__device__ inline f32x16 zero16(){
    f32x16 v;
    #pragma unroll
    for (int i = 0; i < 16; ++i) v[i] = 0.f;
    return v;
}
#define EXP2(x) exp2f(x)   // lowers to a single v_exp_f32 on gfx950

// ---------------------------------------------------------------------------
// Prep (one launch): blocks [0,288) transpose Wq|Wk|Wv fp32 -> bf16 Wt[n][k];
// blocks [288,304) build fmtab; block 304 builds suffix-summed rel weights.
// ---------------------------------------------------------------------------
__global__ __launch_bounds__(256) void prep_kernel(const float* __restrict__ Wq,
    const float* __restrict__ Wk, const float* __restrict__ Wv, u16* __restrict__ Wt,
    unsigned char* __restrict__ fmt, const float* __restrict__ Wrel,
    u16* __restrict__ WsP, u16* __restrict__ WsM){
    int bid = blockIdx.x;
    int t = threadIdx.x;
    if (bid < 288){
        __shared__ float T[64 * 65];
        int s = bid / 96, tile = bid % 96;
        int n0 = (tile / 24) * 64;
        int k0 = (tile % 24) * 64;
        const float* W = (s == 0) ? Wq : (s == 1 ? Wk : Wv);
        int rA = t >> 3, c8 = (t & 7) * 8;
        #pragma unroll
        for (int rep = 0; rep < 2; ++rep){
            int rr = rep * 32 + rA;
            const float* p = W + (size_t)(k0 + rr) * HD + n0 + c8;
            f32x4 a = *(const f32x4*)p, b = *(const f32x4*)(p + 4);
            #pragma unroll
            for (int e = 0; e < 4; ++e){
                T[rr * 65 + c8 + e]     = a[e];
                T[rr * 65 + c8 + 4 + e] = b[e];
            }
        }
        __syncthreads();
        #pragma unroll
        for (int rep = 0; rep < 2; ++rep){
            int rn = rep * 32 + rA;
            u16x8 o;
            #pragma unroll
            for (int e = 0; e < 8; ++e) o[e] = f2b(T[(c8 + e) * 65 + rn]);
            *(u16x8*)&Wt[(size_t)s * WSZ + (size_t)(n0 + rn) * DIMM + k0 + c8] = o;
        }
        return;
    }
    if (bid == 304){
        int h = t >> 6, d = t & 63;
        float w1[32], w2[32];
        #pragma unroll
        for (int fm = 0; fm < 32; ++fm){
            w1[fm] = Wrel[(size_t)fm * HD + h * DK + d];
            w2[fm] = Wrel[(size_t)(32 + fm) * HD + h * DK + d];
        }
        float a1 = 0.f, a2 = 0.f;
        #pragma unroll
        for (int fm = 31; fm >= 0; --fm){
            a1 += w1[fm];
            a2 += w2[fm];
            WsP[(h * 32 + fm) * 64 + d] = f2b(a1 + a2);
            WsM[(h * 32 + fm) * 64 + d] = f2b(a1 - a2);
        }
        return;
    }
    int d = (bid - 288) * 256 + t;
    float lg = logf((float)(N_SEQ + 1)) * (1.0f / 32.0f);
    float ad = (float)d;
    int fm = 0;
    for (int f = 0; f < 32; ++f){
        float cw = expf(lg * (float)(f + 1)) - 1.0f;
        fm += (cw <= ad) ? 1 : 0;
    }
    fmt[d] = (unsigned char)fm;
}

// ---------------------------------------------------------------------------
// QKV projection (unchanged): per-projection blocks + reg-prefetch pipeline.
// ---------------------------------------------------------------------------
__global__ __launch_bounds__(256) void qkv_kernel(const float* __restrict__ X,
    const u16* __restrict__ Wt,
    u16* __restrict__ Q, u16* __restrict__ K, u16* __restrict__ Vt){
    __shared__ __align__(16) u16 xs[64 * 72];
    __shared__ __align__(16) u16 bs[64 * 72];
    int s  = blockIdx.x >> 2;             // 0:Q 1:K 2:V
    int n0 = (blockIdx.x & 3) * 64;
    int m0 = blockIdx.y * 64;
    int t = threadIdx.x;
    int w = t >> 6, lane = t & 63, qd = lane >> 4, l15 = lane & 15;
    int r  = t >> 3;
    int cv = (t & 7) * 8;
    f32x4 acc[4] = {{0,0,0,0},{0,0,0,0},{0,0,0,0},{0,0,0,0}};

    f32x4 xa[2], xb[2];
    u16x8 wv[2];
    auto LOAD = [&](int k0){
        #pragma unroll
        for (int rep = 0; rep < 2; ++rep){
            int rr = rep * 32 + r;
            size_t xi = (size_t)(m0 + rr) * DIMM + k0 + cv;
            xa[rep] = *(const f32x4*)(X + xi);
            xb[rep] = *(const f32x4*)(X + xi + 4);
            wv[rep] = *(const u16x8*)&Wt[(size_t)s * WSZ + (size_t)(n0 + rr) * DIMM + k0 + cv];
        }
    };
    auto STORE = [&](){
        #pragma unroll
        for (int rep = 0; rep < 2; ++rep){
            int rr = rep * 32 + r;
            u16x8 xv;
            #pragma unroll
            for (int e = 0; e < 4; ++e){ xv[e] = f2b(xa[rep][e]); xv[4 + e] = f2b(xb[rep][e]); }
            *(u16x8*)&xs[rr * 72 + cv] = xv;
            *(u16x8*)&bs[rr * 72 + cv] = wv[rep];
        }
    };

    LOAD(0);
    for (int k0 = 0; k0 < DIMM; k0 += 64){
        STORE();
        __syncthreads();
        if (k0 + 64 < DIMM) LOAD(k0 + 64);
        bf16x8 a0 = ldfrag(&xs[(w * 16 + l15) * 72 +  0 + qd * 8]);
        bf16x8 a1 = ldfrag(&xs[(w * 16 + l15) * 72 + 32 + qd * 8]);
        #pragma unroll
        for (int nt = 0; nt < 4; ++nt){
            bf16x8 b0 = ldfrag(&bs[(nt * 16 + l15) * 72 +  0 + qd * 8]);
            bf16x8 b1 = ldfrag(&bs[(nt * 16 + l15) * 72 + 32 + qd * 8]);
            acc[nt] = __builtin_amdgcn_mfma_f32_16x16x32_bf16(a0, b0, acc[nt], 0, 0, 0);
            acc[nt] = __builtin_amdgcn_mfma_f32_16x16x32_bf16(a1, b1, acc[nt], 0, 0, 0);
        }
        __syncthreads();
    }

    int row0 = m0 + w * 16 + qd * 4;
    if (s == 0){
        #pragma unroll
        for (int nt = 0; nt < 4; ++nt){
            int col = n0 + nt * 16 + l15;
            #pragma unroll
            for (int reg = 0; reg < 4; ++reg)
                Q[(size_t)(row0 + reg) * HD + col] = f2b(acc[nt][reg] * QK_SCALE);
        }
    } else if (s == 1){
        #pragma unroll
        for (int nt = 0; nt < 4; ++nt){
            int col = n0 + nt * 16 + l15;
            #pragma unroll
            for (int reg = 0; reg < 4; ++reg)
                K[(size_t)(row0 + reg) * HD + col] = f2b(acc[nt][reg]);
        }
    } else {
        #pragma unroll
        for (int nt = 0; nt < 4; ++nt){
            int col = n0 + nt * 16 + l15;
            u16x4 pv;
            #pragma unroll
            for (int reg = 0; reg < 4; ++reg) pv[reg] = f2b(acc[nt][reg]);
            *(u16x4*)&Vt[(size_t)col * N_SEQ + row0] = pv;
        }
    }
}

// ---------------------------------------------------------------------------
// Flash attention v3: double-buffered K/V LDS, ONE barrier per tile.
// Buffer b at smem + b*18432 BYTES: K = 4608 u16 (9216 B), V = next 4608 u16.
// NOTE: plain __launch_bounds__(256) — the (256,4) variant capped the
// allocator at 64 VGPR and spilled ~830 MB/dispatch to scratch (R9).
// ---------------------------------------------------------------------------
template<bool RELG>
__global__ __launch_bounds__(256) void attn_kernel(const u16* __restrict__ Q,
    const u16* __restrict__ Kg, const u16* __restrict__ Vt,
    const u16* __restrict__ WsPg, const u16* __restrict__ WsMg,
    const unsigned char* __restrict__ fmtg,
    const float* __restrict__ CB, const float* __restrict__ PB,
    u32* __restrict__ relG,
    u16* __restrict__ OpU, float* __restrict__ mpart, float* __restrict__ lpart){
    extern __shared__ __align__(16) unsigned char smem[];
    unsigned char* fmt = smem + 36864;    // 4096
    u32* relL = (u32*)(smem + 40960);     // RELG=0 only: [128][32] u32
    u16* Qs   = (u16*)(smem);             // init alias over buf0: [128][72]
    u16* WsPs = (u16*)(smem + 18432);     // init alias over buf1: [32][72]
    u16* WsMs = (u16*)(smem + 23040);

    int i0   = blockIdx.x * 128;
    int h    = blockIdx.y;
    int half = blockIdx.z;                // 0..7
    int bid  = blockIdx.x * NH + h;       // 0..127
    int jbase = half * (N_SEQ / KSPLIT);
    const int NT = (N_SEQ / KSPLIT) / 64; // 8 tiles
    int t = threadIdx.x;
    int w = t >> 6, lane = t & 63, l31 = lane & 31, hbit = lane >> 5;
    int h8 = hbit * 8;
    int i_loc = w * 32 + l31;

    int sr = t >> 3, scv = (t & 7) * 8;
    u16x8 kr0, kr1, vr0, vr1;
    auto LOAD = [&](int j0){
        kr0 = *(const u16x8*)&Kg[(size_t)(j0 + sr)      * HD + h * DK + scv];
        kr1 = *(const u16x8*)&Kg[(size_t)(j0 + 32 + sr) * HD + h * DK + scv];
        vr0 = *(const u16x8*)&Vt[(size_t)(h * 64 + sr)      * N_SEQ + j0 + scv];
        vr1 = *(const u16x8*)&Vt[(size_t)(h * 64 + 32 + sr) * N_SEQ + j0 + scv];
    };
    auto STOREB = [&](int b){
        u16* Kb = (u16*)(smem + b * 18432);
        u16* Vb = Kb + 4608;   // +9216 BYTES (u16 elements)
        *(u16x8*)&Kb[(sr)      * 72 + scv] = kr0;
        *(u16x8*)&Kb[(32 + sr) * 72 + scv] = kr1;
        *(u16x8*)&Vb[(sr)      * 72 + scv] = vr0;
        *(u16x8*)&Vb[(32 + sr) * 72 + scv] = vr1;
    };
    LOAD(jbase);

    // ---- init staging ----
    #pragma unroll
    for (int rep = 0; rep < 4; ++rep){
        int vid = rep * 256 + t;
        int r  = vid >> 3;
        int cv = (vid & 7) * 8;
        *(u16x8*)&Qs[r * 72 + cv] = *(const u16x8*)&Q[(size_t)(i0 + r) * HD + h * DK + cv];
    }
    {
        int r = t >> 3, cv = (t & 7) * 8;
        *(u16x8*)&WsPs[r * 72 + cv] = *(const u16x8*)&WsPg[(h * 32 + r) * 64 + cv];
        *(u16x8*)&WsMs[r * 72 + cv] = *(const u16x8*)&WsMg[(h * 32 + r) * 64 + cv];
    }
    ((uint4*)fmt)[t] = ((const uint4*)fmtg)[t];
    __syncthreads();

    // ---- Q fragments, bias + LOG2E folded ----
    bf16x8 qcF[4], qpF[4];
    #pragma unroll
    for (int kc = 0; kc < 4; ++kc){
        bf16x8 raw = ldfrag(&Qs[i_loc * 72 + kc * 16 + h8]);
        const float* cbp = CB + h * DK + kc * 16 + h8;
        const float* pbp = PB + h * DK + kc * 16 + h8;
        bf16x8 qc, qp;
        #pragma unroll
        for (int e = 0; e < 8; ++e){
            float qf = (float)raw[e];
            qc[e] = (__bf16)((qf + cbp[e]) * LOG2E);
            qp[e] = (__bf16)((qf + pbp[e]) * LOG2E);
        }
        qcF[kc] = qc; qpF[kc] = qp;
    }

    // ---- rel tables via MFMA (log2 domain) ----
    f32x16 rP = zero16(), rM = zero16();
    #pragma unroll
    for (int kc = 0; kc < 4; ++kc){
        bf16x8 aP = ldfrag(&WsPs[l31 * 72 + kc * 16 + h8]);
        bf16x8 aM = ldfrag(&WsMs[l31 * 72 + kc * 16 + h8]);
        rP = __builtin_amdgcn_mfma_f32_32x32x16_bf16(aP, qpF[kc], rP, 0, 0, 0);
        rM = __builtin_amdgcn_mfma_f32_32x32x16_bf16(aM, qpF[kc], rM, 0, 0, 0);
    }
    __syncthreads();   // LDS reads (Qs, Wsuf) done before KV overwrites

    // rel row (32 slots = one 128-B line). Slot 0 = d==0 value in both
    // halves (fmt[0]==0 and ad==0 only at dd==0; fmt[ad]<=31 always).
    u32* relRow;
    if (RELG) relRow = relG + ((size_t)h * N_SEQ + (size_t)(i0 + i_loc)) * 32;
    else      relRow = relL + i_loc * 32;
    {
        u32 v0 = (u32)f2b((rP[0] + rM[0]) * 0.5f);
        u32 v0p = v0 | (v0 << 16);
        #pragma unroll
        for (int r = 0; r < 16; ++r){
            int fm = (r & 3) + 8 * (r >> 2) + 4 * hbit;   // fm==0 only hbit0,r0
            u32 pk = (u32)f2b(rP[r]) | ((u32)f2b(rM[r]) << 16);
            relRow[fm] = (fm == 0) ? v0p : pk;
        }
    }
    STOREB(0);               // tile 0 -> buf0 (Qs/Wsuf dead)
    LOAD(jbase + 64);        // tile 1 regs
    __syncthreads();         // buf0 + rel visible

    // ---- main K-loop: one barrier per tile ----
    float mrow = -1e30f, lacc = 0.f;
    f32x16 oacc0 = zero16(), oacc1 = zero16();

#define MFMA32(A, B, C) __builtin_amdgcn_mfma_f32_32x32x16_bf16(A, B, C, 0, 0, 0)

#define PACK8(ST, WD) { \
    _Pragma("unroll") \
    for (int q_ = 0; q_ < 8; ++q_){ \
        float pa_ = EXP2(ST[2 * q_]     - bias); \
        float pc_ = EXP2(ST[2 * q_ + 1] - bias); \
        lsum += pa_ + pc_; \
        WD[q_] = (u32)f2b(pa_) | ((u32)f2b(pc_) << 16); \
    } }

#define MKFRAG(DST, WD, ZZ) { \
    u32 a0_ = WD[(ZZ) * 4 + 0], a1_ = WD[(ZZ) * 4 + 1]; \
    u32 b0_ = WD[(ZZ) * 4 + 2], b1_ = WD[(ZZ) * 4 + 3]; \
    u32 sh0_ = (u32)__shfl_xor((int)(hbit ? a0_ : b0_), 32); \
    u32 sh1_ = (u32)__shfl_xor((int)(hbit ? a1_ : b1_), 32); \
    u32x4 fw_; \
    fw_[0] = hbit ? sh0_ : a0_; \
    fw_[1] = hbit ? sh1_ : a1_; \
    fw_[2] = hbit ? b0_  : sh0_; \
    fw_[3] = hbit ? b1_  : sh1_; \
    DST = __builtin_bit_cast(bf16x8, fw_); }

#define PVSTEP(PF, COL) { \
    oacc0 = MFMA32(PF, ldfrag(&Vcur[(l31)      * 72 + (COL) + h8]), oacc0); \
    oacc1 = MFMA32(PF, ldfrag(&Vcur[(32 + l31) * 72 + (COL) + h8]), oacc1); }

    for (int kt = 0; kt < NT; ++kt){
        int cur = kt & 1;
        int j0 = jbase + kt * 64;
        if (kt + 1 < NT) STOREB(cur ^ 1);   // regs(tile kt+1) -> other buf
        if (kt + 2 < NT) LOAD(j0 + 128);    // tile kt+2 -> regs
        const u16* Kcur = (const u16*)(smem + cur * 18432);
        const u16* Vcur = Kcur + 4608;      // +9216 BYTES

        // S^T = K . Q^T
        f32x16 st0 = zero16(), st1 = zero16();
        __builtin_amdgcn_s_setprio(1);
        #pragma unroll
        for (int kc = 0; kc < 4; ++kc){
            bf16x8 k0 = ldfrag(&Kcur[(l31)      * 72 + kc * 16 + h8]);
            bf16x8 k1 = ldfrag(&Kcur[(32 + l31) * 72 + kc * 16 + h8]);
            st0 = MFMA32(k0, qcF[kc], st0);
            st1 = MFMA32(k1, qcF[kc], st1);
        }
        __builtin_amdgcn_s_setprio(0);

        // rel merge: fast path folds relv into the exp bias
        int D = j0 - i0;
        int Di = D - i_loc;
        float relv = 0.f;
        bool fast = false, plus = true; int fmU = 0;
        if (D >= 128){
            int fa = fmt[D - 127], fb = fmt[D + 63];
            fast = (fa == fb); fmU = fa; plus = true;
        } else if (D <= -64){
            int fa = fmt[-D - 63], fb = fmt[-D + 127];
            fast = (fa == fb); fmU = fa; plus = false;
        }
        if (fast){
            u32 pm = relRow[fmU];
            relv = b2f(plus ? (u16)pm : (u16)(pm >> 16));
        } else {
            #pragma unroll
            for (int r = 0; r < 16; ++r){
                const int jb = (r & 3) + 8 * (r >> 2);
                int jbh = jb + 4 * hbit;
                {
                    int dd = Di + jbh;
                    int ad = dd < 0 ? -dd : dd;
                    u32 pm = relRow[fmt[ad]];
                    st0[r] += b2f(dd >= 0 ? (u16)pm : (u16)(pm >> 16));
                }
                {
                    int dd = Di + 32 + jbh;
                    int ad = dd < 0 ? -dd : dd;
                    u32 pm = relRow[fmt[ad]];
                    st1[r] += b2f(dd >= 0 ? (u16)pm : (u16)(pm >> 16));
                }
            }
        }

        // row max
        float mx = st0[0];
        #pragma unroll
        for (int r = 1; r < 16; ++r) mx = fmaxf(mx, st0[r]);
        #pragma unroll
        for (int r = 0; r < 16; ++r) mx = fmaxf(mx, st1[r]);
        mx = fmaxf(mx, __shfl_xor(mx, 32)) + relv;

        // defer-max (log2 domain, THR = 11)
        if (!__all(mx - mrow <= 11.0f)){
            float mnew = fmaxf(mrow, mx);
            float alpha = EXP2(mrow - mnew);
            mrow = mnew;
            lacc *= alpha;
            #pragma unroll
            for (int r = 0; r < 16; ++r){
                float ar = __shfl(alpha, (r & 3) + 8 * (r >> 2) + 4 * hbit);
                oacc0[r] *= ar; oacc1[r] *= ar;
            }
        }

        float bias = mrow - relv;
        float lsum = 0.f;
        u32 wds0[8], wds1[8];
        PACK8(st0, wds0)
        PACK8(st1, wds1)
        lacc += lsum + __shfl_xor(lsum, 32);

        bf16x8 pf0, pf1, pf2, pf3;
        MKFRAG(pf0, wds0, 0)
        MKFRAG(pf1, wds0, 1)
        MKFRAG(pf2, wds1, 0)
        MKFRAG(pf3, wds1, 1)
        __builtin_amdgcn_s_setprio(1);
        PVSTEP(pf0,  0)
        PVSTEP(pf1, 16)
        PVSTEP(pf2, 32)
        PVSTEP(pf3, 48)
        __builtin_amdgcn_s_setprio(0);

        __syncthreads();   // single barrier: STOREs visible, reads of cur done
    }

    // ---- write partials ----
    size_t pb = ((size_t)half * 128 + bid) * 128;
    #pragma unroll
    for (int r = 0; r < 16; ++r){
        int iO = w * 32 + (r & 3) + 8 * (r >> 2) + 4 * hbit;
        OpU[(pb + iO) * 64 + l31]      = f2b(oacc0[r]);
        OpU[(pb + iO) * 64 + 32 + l31] = f2b(oacc1[r]);
    }
    if (hbit == 0){
        mpart[pb + i_loc] = mrow;
        lpart[pb + i_loc] = lacc;
    }
#undef MFMA32
#undef PACK8
#undef MKFRAG
#undef PVSTEP
}

// ---------------------------------------------------------------------------
// Combine 8 K-eighths -> normalized bf16 Oatt.
// ---------------------------------------------------------------------------
__global__ __launch_bounds__(256) void combine_kernel(const u16* __restrict__ OpU,
    const float* __restrict__ mpart, const float* __restrict__ lpart,
    u16* __restrict__ Oatt){
    int h = blockIdx.y;
    int t = threadIdx.x;
    int r = t >> 3, cb = (t & 7) * 8;
    int i = blockIdx.x * 32 + r;
    int bid = (i >> 7) * NH + h;
    int ri = i & 127;
    size_t pr[8];
    float ms[8], ls[8];
    float m = -1e30f;
    #pragma unroll
    for (int s = 0; s < 8; ++s){
        pr[s] = ((size_t)s * 128 + bid) * 128 + ri;
        ms[s] = mpart[pr[s]];
        ls[s] = lpart[pr[s]];
        m = fmaxf(m, ms[s]);
    }
    float den = 0.f, wgt[8];
    #pragma unroll
    for (int s = 0; s < 8; ++s){ wgt[s] = EXP2(ms[s] - m); den += wgt[s] * ls[s]; }
    float inv = 1.0f / fmaxf(den, 1e-30f);
    float o[8];
    #pragma unroll
    for (int e = 0; e < 8; ++e) o[e] = 0.f;
    #pragma unroll
    for (int s = 0; s < 8; ++s){
        u16x8 a = *(const u16x8*)&OpU[pr[s] * 64 + cb];
        #pragma unroll
        for (int e = 0; e < 8; ++e) o[e] += wgt[s] * b2f(a[e]);
    }
    u16x8 rv;
    #pragma unroll
    for (int e = 0; e < 8; ++e) rv[e] = f2b(o[e] * inv);
    *(u16x8*)&Oatt[(size_t)i * HD + h * DK + cb] = rv;
}

// ---------------------------------------------------------------------------
// Output projection: out = Oattn @ Wo + bo. (unchanged)
// ---------------------------------------------------------------------------
__global__ __launch_bounds__(256) void oproj_kernel(const u16* __restrict__ A,
    const float* __restrict__ Wo, const float* __restrict__ bo,
    float* __restrict__ out, int m_base){
    __shared__ __align__(16) u16 xs[64 * 72];
    __shared__ __align__(16) u16 bs[64 * 72];
    int m0 = m_base + blockIdx.y * 64;
    int n0 = blockIdx.x * 64;
    int t = threadIdx.x;
    int w = t >> 6, lane = t & 63, qd = lane >> 4, l15 = lane & 15;
    f32x4 acc[4] = {{0,0,0,0},{0,0,0,0},{0,0,0,0},{0,0,0,0}};
    for (int k0 = 0; k0 < HD; k0 += 64){
        #pragma unroll
        for (int rep = 0; rep < 2; ++rep){
            int vid = rep * 256 + t;
            int r  = vid >> 3;
            int cv = (vid & 7) * 8;
            *(u16x8*)&xs[r * 72 + cv] = *(const u16x8*)&A[(size_t)(m0 + r) * HD + k0 + cv];
            size_t wi = (size_t)(k0 + r) * DIMM + n0 + cv;
            f32x4 wa = *(const f32x4*)(Wo + wi), wb = *(const f32x4*)(Wo + wi + 4);
            u16x8 wv;
            #pragma unroll
            for (int e = 0; e < 4; ++e){ wv[e] = f2b(wa[e]); wv[4 + e] = f2b(wb[e]); }
            #pragma unroll
            for (int e = 0; e < 8; ++e) bs[(cv + e) * 72 + r] = wv[e];
        }
        __syncthreads();
        bf16x8 a0 = ldfrag(&xs[(w * 16 + l15) * 72 +  0 + qd * 8]);
        bf16x8 a1 = ldfrag(&xs[(w * 16 + l15) * 72 + 32 + qd * 8]);
        #pragma unroll
        for (int nt = 0; nt < 4; ++nt){
            bf16x8 b0 = ldfrag(&bs[(nt * 16 + l15) * 72 +  0 + qd * 8]);
            bf16x8 b1 = ldfrag(&bs[(nt * 16 + l15) * 72 + 32 + qd * 8]);
            acc[nt] = __builtin_amdgcn_mfma_f32_16x16x32_bf16(a0, b0, acc[nt], 0, 0, 0);
            acc[nt] = __builtin_amdgcn_mfma_f32_16x16x32_bf16(a1, b1, acc[nt], 0, 0, 0);
        }
        __syncthreads();
    }
    #pragma unroll
    for (int nt = 0; nt < 4; ++nt)
        #pragma unroll
        for (int reg = 0; reg < 4; ++reg){
            int row = m0 + w * 16 + qd * 4 + reg;
            int col = n0 + nt * 16 + l15;
            out[(size_t)row * DIMM + col] = acc[nt][reg] + bo[col];
        }
}

extern "C" void kernel_launch(void* const* d_in, const int* in_sizes, int n_in,
                              void* d_out, int out_size, void* d_ws, size_t ws_size,
                              hipStream_t stream){
    const float* X  = (const float*)d_in[0];
    const float* Wq = (const float*)d_in[1];
    const float* Wk = (const float*)d_in[2];
    const float* Wv = (const float*)d_in[3];
    const float* Wr = (const float*)d_in[4];
    const float* Wo = (const float*)d_in[5];
    const float* bo = (const float*)d_in[6];
    const float* CB = (const float*)d_in[7];
    const float* PB = (const float*)d_in[8];
    float* out = (float*)d_out;
    u16* base = (u16*)d_out;   // 12,582,912 u16 slots

    // d_out scratch (u16 offsets): Qb[0,1048576) Kb[1048576,2097152)
    // Vt[2097152,3145728) Wt[3145728,4325376) (dead after qkv; OpU overlays)
    // OpU[3145728,11534336) mpart/lpart f32 after.
    u16* Qb   = base;
    u16* Kb   = base + 1048576;
    u16* Vt   = base + 2097152;
    u16* Wt   = base + 3145728;
    u16* OpU  = base + 3145728;
    float* mpart = out + 5767168;
    float* lpart = out + 5898240;

    // d_ws layout: fmt[0,4096) WsP[4096,20480) WsM[20480,36864)
    //   relG u32 [h][4096][32] @36864 (2,097,152 B) -> 2,134,016
    //   Oatt u16 @2,134,016 (2,097,152 B) -> 4,231,168
    unsigned char* fmtg = (unsigned char*)d_ws;
    u16* WsP = (u16*)((char*)d_ws + 4096);
    u16* WsM = (u16*)((char*)d_ws + 20480);
    u32* relG = (u32*)((char*)d_ws + 36864);
    bool ws_ok = ws_size >= 4231168;

    prep_kernel<<<dim3(305), 256, 0, stream>>>(Wq, Wk, Wv, Wt, fmtg, Wr, WsP, WsM);
    qkv_kernel<<<dim3(12, 64), 256, 0, stream>>>(X, Wt, Qb, Kb, Vt);

    if (ws_ok){
        u16* Oatt = (u16*)((char*)d_ws + 2134016);
        attn_kernel<true><<<dim3(32, NH, KSPLIT), 256, 40960, stream>>>(
            Qb, Kb, Vt, WsP, WsM, fmtg, CB, PB, relG, OpU, mpart, lpart);
        combine_kernel<<<dim3(128, NH), 256, 0, stream>>>(OpU, mpart, lpart, Oatt);
        oproj_kernel<<<dim3(24, 64), 256, 0, stream>>>(Oatt, Wo, bo, out, 0);
    } else {
        // fallback: rel tables in LDS (57344 B dynamic), Oatt in d_out with
        // the descending-row 3-split oproj for WAR safety.
        u16* Oatt = base;          // overlays Qb (dead after attn)
        attn_kernel<false><<<dim3(32, NH, KSPLIT), 256, 57344, stream>>>(
            Qb, Kb, Vt, WsP, WsM, fmtg, CB, PB, nullptr, OpU, mpart, lpart);
        combine_kernel<<<dim3(128, NH), 256, 0, stream>>>(OpU, mpart, lpart, Oatt);
        oproj_kernel<<<dim3(24, 58), 256, 0, stream>>>(Oatt, Wo, bo, out, 384);
        oproj_kernel<<<dim3(24,  5), 256, 0, stream>>>(Oatt, Wo, bo, out, 64);
        oproj_kernel<<<dim3(24,  1), 256, 0, stream>>>(Oatt, Wo, bo, out, 0);
    }
}

// Round 11
// 206.693 us; speedup vs baseline: 2.0989x; 1.6388x over previous
//
#include <hip/hip_runtime.h>
#include <hip/hip_bf16.h>

#define N_SEQ 4096
#define DIMM  1536
#define NH    4
#define DK    64
#define HD    256     // NH*DK
#define QK_SCALE 0.125f
#define WSZ   393216  // 1536*256 per weight
#define KSPLIT 8
#define LOG2E 1.44269504f

typedef __bf16 bf16x8 __attribute__((ext_vector_type(8)));
typedef unsigned short u16;
typedef unsigned int u32;
typedef u16   u16x8  __attribute__((ext_vector_type(8)));
typedef u16   u16x4  __attribute__((ext_vector_type(4)));
typedef float f32x4  __attribute__((ext_vector_type(4)));
typedef float f32x16 __attribute__((ext_vector_type(16)));
typedef unsigned int u32x4 __attribute__((ext_vector_type(4)));

__device__ inline float b2f(u16 u){
    union { float f; unsigned int i; } v; v.i = ((unsigned int)u) << 16; return v.f;
}
__device__ inline u16 f2b(float f){
    __bf16 h = (__bf16)f;               // native cvt, RNE
    return __builtin_bit_cast(u16, h);
}
__device__ inline bf16x8 ldfrag(const u16* p){
    return __builtin_bit_cast(bf16x8, *(const u16x8*)p);
}
__device__ inline f32x16 zero16(){
    f32x16 v;
    #pragma unroll
    for (int i = 0; i < 16; ++i) v[i] = 0.f;
    return v;
}
#define EXP2(x) exp2f(x)   // lowers to a single v_exp_f32 on gfx950

// ---------------------------------------------------------------------------
// Prep (one launch): blocks [0,288) transpose Wq|Wk|Wv fp32 -> bf16 Wt[n][k];
// blocks [288,304) build fmtab; block 304 builds suffix-summed rel weights.
// ---------------------------------------------------------------------------
__global__ __launch_bounds__(256) void prep_kernel(const float* __restrict__ Wq,
    const float* __restrict__ Wk, const float* __restrict__ Wv, u16* __restrict__ Wt,
    unsigned char* __restrict__ fmt, const float* __restrict__ Wrel,
    u16* __restrict__ WsP, u16* __restrict__ WsM){
    int bid = blockIdx.x;
    int t = threadIdx.x;
    if (bid < 288){
        __shared__ float T[64 * 65];
        int s = bid / 96, tile = bid % 96;
        int n0 = (tile / 24) * 64;
        int k0 = (tile % 24) * 64;
        const float* W = (s == 0) ? Wq : (s == 1 ? Wk : Wv);
        int rA = t >> 3, c8 = (t & 7) * 8;
        #pragma unroll
        for (int rep = 0; rep < 2; ++rep){
            int rr = rep * 32 + rA;
            const float* p = W + (size_t)(k0 + rr) * HD + n0 + c8;
            f32x4 a = *(const f32x4*)p, b = *(const f32x4*)(p + 4);
            #pragma unroll
            for (int e = 0; e < 4; ++e){
                T[rr * 65 + c8 + e]     = a[e];
                T[rr * 65 + c8 + 4 + e] = b[e];
            }
        }
        __syncthreads();
        #pragma unroll
        for (int rep = 0; rep < 2; ++rep){
            int rn = rep * 32 + rA;
            u16x8 o;
            #pragma unroll
            for (int e = 0; e < 8; ++e) o[e] = f2b(T[(c8 + e) * 65 + rn]);
            *(u16x8*)&Wt[(size_t)s * WSZ + (size_t)(n0 + rn) * DIMM + k0 + c8] = o;
        }
        return;
    }
    if (bid == 304){
        int h = t >> 6, d = t & 63;
        float w1[32], w2[32];
        #pragma unroll
        for (int fm = 0; fm < 32; ++fm){
            w1[fm] = Wrel[(size_t)fm * HD + h * DK + d];
            w2[fm] = Wrel[(size_t)(32 + fm) * HD + h * DK + d];
        }
        float a1 = 0.f, a2 = 0.f;
        #pragma unroll
        for (int fm = 31; fm >= 0; --fm){
            a1 += w1[fm];
            a2 += w2[fm];
            WsP[(h * 32 + fm) * 64 + d] = f2b(a1 + a2);
            WsM[(h * 32 + fm) * 64 + d] = f2b(a1 - a2);
        }
        return;
    }
    int d = (bid - 288) * 256 + t;
    float lg = logf((float)(N_SEQ + 1)) * (1.0f / 32.0f);
    float ad = (float)d;
    int fm = 0;
    for (int f = 0; f < 32; ++f){
        float cw = expf(lg * (float)(f + 1)) - 1.0f;
        fm += (cw <= ad) ? 1 : 0;
    }
    fmt[d] = (unsigned char)fm;
}

// ---------------------------------------------------------------------------
// QKV projection: per-projection blocks + reg-prefetch pipeline. (unchanged)
// ---------------------------------------------------------------------------
__global__ __launch_bounds__(256) void qkv_kernel(const float* __restrict__ X,
    const u16* __restrict__ Wt,
    u16* __restrict__ Q, u16* __restrict__ K, u16* __restrict__ Vt){
    __shared__ __align__(16) u16 xs[64 * 72];
    __shared__ __align__(16) u16 bs[64 * 72];
    int s  = blockIdx.x >> 2;             // 0:Q 1:K 2:V
    int n0 = (blockIdx.x & 3) * 64;
    int m0 = blockIdx.y * 64;
    int t = threadIdx.x;
    int w = t >> 6, lane = t & 63, qd = lane >> 4, l15 = lane & 15;
    int r  = t >> 3;
    int cv = (t & 7) * 8;
    f32x4 acc[4] = {{0,0,0,0},{0,0,0,0},{0,0,0,0},{0,0,0,0}};

    f32x4 xa[2], xb[2];
    u16x8 wv[2];
    auto LOAD = [&](int k0){
        #pragma unroll
        for (int rep = 0; rep < 2; ++rep){
            int rr = rep * 32 + r;
            size_t xi = (size_t)(m0 + rr) * DIMM + k0 + cv;
            xa[rep] = *(const f32x4*)(X + xi);
            xb[rep] = *(const f32x4*)(X + xi + 4);
            wv[rep] = *(const u16x8*)&Wt[(size_t)s * WSZ + (size_t)(n0 + rr) * DIMM + k0 + cv];
        }
    };
    auto STORE = [&](){
        #pragma unroll
        for (int rep = 0; rep < 2; ++rep){
            int rr = rep * 32 + r;
            u16x8 xv;
            #pragma unroll
            for (int e = 0; e < 4; ++e){ xv[e] = f2b(xa[rep][e]); xv[4 + e] = f2b(xb[rep][e]); }
            *(u16x8*)&xs[rr * 72 + cv] = xv;
            *(u16x8*)&bs[rr * 72 + cv] = wv[rep];
        }
    };

    LOAD(0);
    for (int k0 = 0; k0 < DIMM; k0 += 64){
        STORE();
        __syncthreads();
        if (k0 + 64 < DIMM) LOAD(k0 + 64);
        bf16x8 a0 = ldfrag(&xs[(w * 16 + l15) * 72 +  0 + qd * 8]);
        bf16x8 a1 = ldfrag(&xs[(w * 16 + l15) * 72 + 32 + qd * 8]);
        #pragma unroll
        for (int nt = 0; nt < 4; ++nt){
            bf16x8 b0 = ldfrag(&bs[(nt * 16 + l15) * 72 +  0 + qd * 8]);
            bf16x8 b1 = ldfrag(&bs[(nt * 16 + l15) * 72 + 32 + qd * 8]);
            acc[nt] = __builtin_amdgcn_mfma_f32_16x16x32_bf16(a0, b0, acc[nt], 0, 0, 0);
            acc[nt] = __builtin_amdgcn_mfma_f32_16x16x32_bf16(a1, b1, acc[nt], 0, 0, 0);
        }
        __syncthreads();
    }

    int row0 = m0 + w * 16 + qd * 4;
    if (s == 0){
        #pragma unroll
        for (int nt = 0; nt < 4; ++nt){
            int col = n0 + nt * 16 + l15;
            #pragma unroll
            for (int reg = 0; reg < 4; ++reg)
                Q[(size_t)(row0 + reg) * HD + col] = f2b(acc[nt][reg] * QK_SCALE);
        }
    } else if (s == 1){
        #pragma unroll
        for (int nt = 0; nt < 4; ++nt){
            int col = n0 + nt * 16 + l15;
            #pragma unroll
            for (int reg = 0; reg < 4; ++reg)
                K[(size_t)(row0 + reg) * HD + col] = f2b(acc[nt][reg]);
        }
    } else {
        #pragma unroll
        for (int nt = 0; nt < 4; ++nt){
            int col = n0 + nt * 16 + l15;
            u16x4 pv;
            #pragma unroll
            for (int reg = 0; reg < 4; ++reg) pv[reg] = f2b(acc[nt][reg]);
            *(u16x4*)&Vt[(size_t)col * N_SEQ + row0] = pv;
        }
    }
}

// ---------------------------------------------------------------------------
// Flash attention — REVERTED to the R5-proven kernel verbatim (68.7 µs
// measured): static 39936-B LDS, rel tables in LDS, single K/V buffer with
// reg-prefetch, two barriers/tile. The R6-R10 dbuf+global-rel branch
// measured 3x slower (global rel = uncoalesced dependent load per tile).
// ---------------------------------------------------------------------------
__global__ __launch_bounds__(256) void attn_kernel(const u16* __restrict__ Q,
    const u16* __restrict__ Kg, const u16* __restrict__ Vt,
    const u16* __restrict__ WsPg, const u16* __restrict__ WsMg,
    const unsigned char* __restrict__ fmtg,
    const float* __restrict__ CB, const float* __restrict__ PB,
    u16* __restrict__ OpU, float* __restrict__ mpart, float* __restrict__ lpart){
    __shared__ __align__(16) unsigned char smem[39936];
    u16* Ks   = (u16*)(smem);             // [64][72]  main loop
    u16* Vts  = (u16*)(smem + 9216);      // [64][72]  main loop
    u16* Qs   = (u16*)(smem);             // init alias: [128][72]
    u16* relP = (u16*)(smem + 18432);     // [128][34] u16 (slot 0 = d==0 value)
    u16* relM = (u16*)(smem + 27136);     // [128][34] u16
    unsigned char* fmt = smem + 35840;    // 4096
    u16* WsPs = (u16*)(smem + 18432);     // init alias: [32][72]
    u16* WsMs = (u16*)(smem + 23040);

    int i0   = blockIdx.x * 128;
    int h    = blockIdx.y;
    int half = blockIdx.z;                // 0..7
    int bid  = blockIdx.x * NH + h;       // 0..127
    int jbase = half * (N_SEQ / KSPLIT);
    const int NT = (N_SEQ / KSPLIT) / 64; // 8 tiles
    int t = threadIdx.x;
    int w = t >> 6, lane = t & 63, l31 = lane & 31, hbit = lane >> 5;
    int h8 = hbit * 8;
    int i_loc = w * 32 + l31;             // this lane's softmax row (block-local)

    int sr = t >> 3, scv = (t & 7) * 8;
    u16x8 kr0, kr1, vr0, vr1;
    auto LOAD = [&](int j0){
        kr0 = *(const u16x8*)&Kg[(size_t)(j0 + sr)      * HD + h * DK + scv];
        kr1 = *(const u16x8*)&Kg[(size_t)(j0 + 32 + sr) * HD + h * DK + scv];
        vr0 = *(const u16x8*)&Vt[(size_t)(h * 64 + sr)      * N_SEQ + j0 + scv];
        vr1 = *(const u16x8*)&Vt[(size_t)(h * 64 + 32 + sr) * N_SEQ + j0 + scv];
    };
    auto STORE = [&](){
        *(u16x8*)&Ks [(sr)      * 72 + scv] = kr0;
        *(u16x8*)&Ks [(32 + sr) * 72 + scv] = kr1;
        *(u16x8*)&Vts[(sr)      * 72 + scv] = vr0;
        *(u16x8*)&Vts[(32 + sr) * 72 + scv] = vr1;
    };
    LOAD(jbase);

    // ---- init staging: Q rows (raw bf16), Wsuf slices, fmt ----
    #pragma unroll
    for (int rep = 0; rep < 4; ++rep){
        int vid = rep * 256 + t;
        int r  = vid >> 3;
        int cv = (vid & 7) * 8;
        *(u16x8*)&Qs[r * 72 + cv] = *(const u16x8*)&Q[(size_t)(i0 + r) * HD + h * DK + cv];
    }
    {
        int r = t >> 3, cv = (t & 7) * 8;
        *(u16x8*)&WsPs[r * 72 + cv] = *(const u16x8*)&WsPg[(h * 32 + r) * 64 + cv];
        *(u16x8*)&WsMs[r * 72 + cv] = *(const u16x8*)&WsMg[(h * 32 + r) * 64 + cv];
    }
    ((uint4*)fmt)[t] = ((const uint4*)fmtg)[t];
    __syncthreads();

    // ---- per-lane Q fragments (B-operand layout), bias + LOG2E folded ----
    bf16x8 qcF[4], qpF[4];
    #pragma unroll
    for (int kc = 0; kc < 4; ++kc){
        bf16x8 raw = ldfrag(&Qs[i_loc * 72 + kc * 16 + h8]);
        const float* cbp = CB + h * DK + kc * 16 + h8;
        const float* pbp = PB + h * DK + kc * 16 + h8;
        bf16x8 qc, qp;
        #pragma unroll
        for (int e = 0; e < 8; ++e){
            float qf = (float)raw[e];
            qc[e] = (__bf16)((qf + cbp[e]) * LOG2E);
            qp[e] = (__bf16)((qf + pbp[e]) * LOG2E);
        }
        qcF[kc] = qc; qpF[kc] = qp;
    }

    // ---- rel tables via MFMA: C[fm][i] = Wsuf[fm] . qp[i]  (log2 domain) ----
    f32x16 rP = zero16(), rM = zero16();
    #pragma unroll
    for (int kc = 0; kc < 4; ++kc){
        bf16x8 aP = ldfrag(&WsPs[l31 * 72 + kc * 16 + h8]);
        bf16x8 aM = ldfrag(&WsMs[l31 * 72 + kc * 16 + h8]);
        rP = __builtin_amdgcn_mfma_f32_32x32x16_bf16(aP, qpF[kc], rP, 0, 0, 0);
        rM = __builtin_amdgcn_mfma_f32_32x32x16_bf16(aM, qpF[kc], rM, 0, 0, 0);
    }
    __syncthreads();   // all LDS reads (Qs, Wsuf) done before overwrites

    // fm==0 happens only at dd==0 (cw_1 > 0), so slot 0 stores the d==0
    // value (s1 only) and the slow path indexes by fm with NO select.
    #pragma unroll
    for (int r = 0; r < 16; ++r){
        int fm = (r & 3) + 8 * (r >> 2) + 4 * hbit;
        relP[i_loc * 34 + fm] = f2b(rP[r]);
        relM[i_loc * 34 + fm] = f2b(rM[r]);
    }
    if (hbit == 0)
        relP[i_loc * 34 + 0] = f2b((rP[0] + rM[0]) * 0.5f);  // d==0: s1
    STORE();           // K/V tile 0 into seg0 (Qs dead)
    __syncthreads();

    // ---- main K-loop ----
    float mrow = -1e30f, lacc = 0.f;
    f32x16 oacc0 = zero16(), oacc1 = zero16();

#define MFMA32(A, B, C) __builtin_amdgcn_mfma_f32_32x32x16_bf16(A, B, C, 0, 0, 0)

#define PACK8(ST, WD) { \
    _Pragma("unroll") \
    for (int q_ = 0; q_ < 8; ++q_){ \
        float pa_ = EXP2(ST[2 * q_]     - bias); \
        float pc_ = EXP2(ST[2 * q_ + 1] - bias); \
        lsum += pa_ + pc_; \
        WD[q_] = (unsigned int)f2b(pa_) | ((unsigned int)f2b(pc_) << 16); \
    } }

    // halved-shuffle fragment build: send (hbit ? a : b), receive the
    // other half's counterpart; 2 shuffles per fragment instead of 4.
#define MKFRAG(DST, WD, ZZ) { \
    unsigned int a0_ = WD[(ZZ) * 4 + 0], a1_ = WD[(ZZ) * 4 + 1]; \
    unsigned int b0_ = WD[(ZZ) * 4 + 2], b1_ = WD[(ZZ) * 4 + 3]; \
    unsigned int sh0_ = (unsigned int)__shfl_xor((int)(hbit ? a0_ : b0_), 32); \
    unsigned int sh1_ = (unsigned int)__shfl_xor((int)(hbit ? a1_ : b1_), 32); \
    u32x4 fw_; \
    fw_[0] = hbit ? sh0_ : a0_; \
    fw_[1] = hbit ? sh1_ : a1_; \
    fw_[2] = hbit ? b0_  : sh0_; \
    fw_[3] = hbit ? b1_  : sh1_; \
    DST = __builtin_bit_cast(bf16x8, fw_); }

#define PVSTEP(PF, COL) { \
    oacc0 = MFMA32(PF, ldfrag(&Vts[(l31)      * 72 + (COL) + h8]), oacc0); \
    oacc1 = MFMA32(PF, ldfrag(&Vts[(32 + l31) * 72 + (COL) + h8]), oacc1); }

    const u16* relP_i = relP + i_loc * 34;
    const u16* relM_i = relM + i_loc * 34;

    for (int kt = 0; kt < NT; ++kt){
        int j0 = jbase + kt * 64;
        if (kt + 1 < NT) LOAD(j0 + 64);

        // S^T = K . Q^T : st0 = rows j 0..31, st1 = rows j 32..63; col i = lane&31
        f32x16 st0 = zero16(), st1 = zero16();
        __builtin_amdgcn_s_setprio(1);
        #pragma unroll
        for (int kc = 0; kc < 4; ++kc){
            bf16x8 k0 = ldfrag(&Ks[(l31)      * 72 + kc * 16 + h8]);
            bf16x8 k1 = ldfrag(&Ks[(32 + l31) * 72 + kc * 16 + h8]);
            st0 = MFMA32(k0, qcF[kc], st0);
            st1 = MFMA32(k1, qcF[kc], st1);
        }
        __builtin_amdgcn_s_setprio(0);

        // rel merge: fast path keeps st raw and folds relv into the exp bias
        int D = j0 - i0;
        int Di = D - i_loc;
        float relv = 0.f;
        bool fast = false; int fmU = 0; const u16* tabU = relP_i;
        if (D >= 128){
            int fa = fmt[D - 127], fb = fmt[D + 63];
            fast = (fa == fb); fmU = fa; tabU = relP_i;
        } else if (D <= -64){
            int fa = fmt[-D - 63], fb = fmt[-D + 127];
            fast = (fa == fb); fmU = fa; tabU = relM_i;
        }
        if (fast){
            relv = b2f(tabU[fmU]);
        } else {
            #pragma unroll
            for (int r = 0; r < 16; ++r){
                const int jb = (r & 3) + 8 * (r >> 2);
                int jbh = jb + 4 * hbit;
                {
                    int dd = Di + jbh;
                    int ad = dd < 0 ? -dd : dd;
                    int fm = fmt[ad];
                    const u16* tab = (dd >= 0) ? relP_i : relM_i;
                    st0[r] += b2f(tab[fm]);
                }
                {
                    int dd = Di + 32 + jbh;
                    int ad = dd < 0 ? -dd : dd;
                    int fm = fmt[ad];
                    const u16* tab = (dd >= 0) ? relP_i : relM_i;
                    st1[r] += b2f(tab[fm]);
                }
            }
        }

        // row max (lane-local + one cross-half shuffle); relv added once
        float mx = st0[0];
        #pragma unroll
        for (int r = 1; r < 16; ++r) mx = fmaxf(mx, st0[r]);
        #pragma unroll
        for (int r = 0; r < 16; ++r) mx = fmaxf(mx, st1[r]);
        mx = fmaxf(mx, __shfl_xor(mx, 32)) + relv;

        // defer-max (log2 domain, THR = 11 ~ e^7.6)
        if (!__all(mx - mrow <= 11.0f)){
            float mnew = fmaxf(mrow, mx);
            float alpha = EXP2(mrow - mnew);
            mrow = mnew;
            lacc *= alpha;
            #pragma unroll
            for (int r = 0; r < 16; ++r){
                float ar = __shfl(alpha, (r & 3) + 8 * (r >> 2) + 4 * hbit);
                oacc0[r] *= ar; oacc1[r] *= ar;
            }
        }

        // P = exp2(st - bias), bias = mrow - relv; l from unrounded floats
        float bias = mrow - relv;
        float lsum = 0.f;
        unsigned int wds0[8], wds1[8];
        PACK8(st0, wds0)
        PACK8(st1, wds1)
        lacc += lsum + __shfl_xor(lsum, 32);

        // in-register transpose to PV A-fragments (rows i = lane&31)
        bf16x8 pf0, pf1, pf2, pf3;
        MKFRAG(pf0, wds0, 0)   // j  0..15
        MKFRAG(pf1, wds0, 1)   // j 16..31
        MKFRAG(pf2, wds1, 0)   // j 32..47
        MKFRAG(pf3, wds1, 1)   // j 48..63
        __builtin_amdgcn_s_setprio(1);
        PVSTEP(pf0,  0)
        PVSTEP(pf1, 16)
        PVSTEP(pf2, 32)
        PVSTEP(pf3, 48)
        __builtin_amdgcn_s_setprio(0);

        __syncthreads();
        if (kt + 1 < NT) STORE();
        __syncthreads();
    }

    // ---- write partials ----
    size_t pb = ((size_t)half * 128 + bid) * 128;
    #pragma unroll
    for (int r = 0; r < 16; ++r){
        int iO = w * 32 + (r & 3) + 8 * (r >> 2) + 4 * hbit;
        OpU[(pb + iO) * 64 + l31]      = f2b(oacc0[r]);
        OpU[(pb + iO) * 64 + 32 + l31] = f2b(oacc1[r]);
    }
    if (hbit == 0){
        mpart[pb + i_loc] = mrow;
        lpart[pb + i_loc] = lacc;
    }
#undef MFMA32
#undef PACK8
#undef MKFRAG
#undef PVSTEP
}

// ---------------------------------------------------------------------------
// Combine 8 K-eighths -> normalized bf16 Oatt (512 blocks).
// ---------------------------------------------------------------------------
__global__ __launch_bounds__(256) void combine_kernel(const u16* __restrict__ OpU,
    const float* __restrict__ mpart, const float* __restrict__ lpart,
    u16* __restrict__ Oatt){
    int h = blockIdx.y;
    int t = threadIdx.x;
    int r = t >> 3, cb = (t & 7) * 8;
    int i = blockIdx.x * 32 + r;
    int bid = (i >> 7) * NH + h;
    int ri = i & 127;
    size_t pr[8];
    float ms[8], ls[8];
    float m = -1e30f;
    #pragma unroll
    for (int s = 0; s < 8; ++s){
        pr[s] = ((size_t)s * 128 + bid) * 128 + ri;
        ms[s] = mpart[pr[s]];
        ls[s] = lpart[pr[s]];
        m = fmaxf(m, ms[s]);
    }
    float den = 0.f, wgt[8];
    #pragma unroll
    for (int s = 0; s < 8; ++s){ wgt[s] = EXP2(ms[s] - m); den += wgt[s] * ls[s]; }
    float inv = 1.0f / fmaxf(den, 1e-30f);
    float o[8];
    #pragma unroll
    for (int e = 0; e < 8; ++e) o[e] = 0.f;
    #pragma unroll
    for (int s = 0; s < 8; ++s){
        u16x8 a = *(const u16x8*)&OpU[pr[s] * 64 + cb];
        #pragma unroll
        for (int e = 0; e < 8; ++e) o[e] += wgt[s] * b2f(a[e]);
    }
    u16x8 rv;
    #pragma unroll
    for (int e = 0; e < 8; ++e) rv[e] = f2b(o[e] * inv);
    *(u16x8*)&Oatt[(size_t)i * HD + h * DK + cb] = rv;
}

// ---------------------------------------------------------------------------
// Output projection: out = Oattn @ Wo + bo. (unchanged)
// ---------------------------------------------------------------------------
__global__ __launch_bounds__(256) void oproj_kernel(const u16* __restrict__ A,
    const float* __restrict__ Wo, const float* __restrict__ bo,
    float* __restrict__ out, int m_base){
    __shared__ __align__(16) u16 xs[64 * 72];
    __shared__ __align__(16) u16 bs[64 * 72];
    int m0 = m_base + blockIdx.y * 64;
    int n0 = blockIdx.x * 64;
    int t = threadIdx.x;
    int w = t >> 6, lane = t & 63, qd = lane >> 4, l15 = lane & 15;
    f32x4 acc[4] = {{0,0,0,0},{0,0,0,0},{0,0,0,0},{0,0,0,0}};
    for (int k0 = 0; k0 < HD; k0 += 64){
        #pragma unroll
        for (int rep = 0; rep < 2; ++rep){
            int vid = rep * 256 + t;
            int r  = vid >> 3;
            int cv = (vid & 7) * 8;
            *(u16x8*)&xs[r * 72 + cv] = *(const u16x8*)&A[(size_t)(m0 + r) * HD + k0 + cv];
            size_t wi = (size_t)(k0 + r) * DIMM + n0 + cv;
            f32x4 wa = *(const f32x4*)(Wo + wi), wb = *(const f32x4*)(Wo + wi + 4);
            u16x8 wv;
            #pragma unroll
            for (int e = 0; e < 4; ++e){ wv[e] = f2b(wa[e]); wv[4 + e] = f2b(wb[e]); }
            #pragma unroll
            for (int e = 0; e < 8; ++e) bs[(cv + e) * 72 + r] = wv[e];
        }
        __syncthreads();
        bf16x8 a0 = ldfrag(&xs[(w * 16 + l15) * 72 +  0 + qd * 8]);
        bf16x8 a1 = ldfrag(&xs[(w * 16 + l15) * 72 + 32 + qd * 8]);
        #pragma unroll
        for (int nt = 0; nt < 4; ++nt){
            bf16x8 b0 = ldfrag(&bs[(nt * 16 + l15) * 72 +  0 + qd * 8]);
            bf16x8 b1 = ldfrag(&bs[(nt * 16 + l15) * 72 + 32 + qd * 8]);
            acc[nt] = __builtin_amdgcn_mfma_f32_16x16x32_bf16(a0, b0, acc[nt], 0, 0, 0);
            acc[nt] = __builtin_amdgcn_mfma_f32_16x16x32_bf16(a1, b1, acc[nt], 0, 0, 0);
        }
        __syncthreads();
    }
    #pragma unroll
    for (int nt = 0; nt < 4; ++nt)
        #pragma unroll
        for (int reg = 0; reg < 4; ++reg){
            int row = m0 + w * 16 + qd * 4 + reg;
            int col = n0 + nt * 16 + l15;
            out[(size_t)row * DIMM + col] = acc[nt][reg] + bo[col];
        }
}

extern "C" void kernel_launch(void* const* d_in, const int* in_sizes, int n_in,
                              void* d_out, int out_size, void* d_ws, size_t ws_size,
                              hipStream_t stream){
    const float* X  = (const float*)d_in[0];
    const float* Wq = (const float*)d_in[1];
    const float* Wk = (const float*)d_in[2];
    const float* Wv = (const float*)d_in[3];
    const float* Wr = (const float*)d_in[4];
    const float* Wo = (const float*)d_in[5];
    const float* bo = (const float*)d_in[6];
    const float* CB = (const float*)d_in[7];
    const float* PB = (const float*)d_in[8];
    float* out = (float*)d_out;
    u16* base = (u16*)d_out;   // 12,582,912 u16 slots

    // d_out scratch (u16 offsets): Qb[0,1048576) Kb[1048576,2097152)
    // Vt[2097152,3145728) Wt[3145728,4325376) (dead after qkv; OpU overlays)
    // OpU[3145728,11534336) mpart/lpart f32 after.
    u16* Qb   = base;
    u16* Kb   = base + 1048576;
    u16* Vt   = base + 2097152;
    u16* Wt   = base + 3145728;
    u16* OpU  = base + 3145728;
    float* mpart = out + 5767168;
    float* lpart = out + 5898240;

    // d_ws layout: fmt[0,4096) WsP[4096,20480) WsM[20480,36864)
    //   Oatt u16 @36864 (2,097,152 B) -> 2,134,016
    unsigned char* fmtg = (unsigned char*)d_ws;
    u16* WsP = (u16*)((char*)d_ws + 4096);
    u16* WsM = (u16*)((char*)d_ws + 20480);
    bool ws_ok = ws_size >= 2134016;

    prep_kernel<<<dim3(305), 256, 0, stream>>>(Wq, Wk, Wv, Wt, fmtg, Wr, WsP, WsM);
    qkv_kernel<<<dim3(12, 64), 256, 0, stream>>>(X, Wt, Qb, Kb, Vt);
    attn_kernel<<<dim3(32, NH, KSPLIT), 256, 0, stream>>>(Qb, Kb, Vt, WsP, WsM,
                                                          fmtg, CB, PB,
                                                          OpU, mpart, lpart);

    if (ws_ok){
        u16* Oatt = (u16*)((char*)d_ws + 36864);
        combine_kernel<<<dim3(128, NH), 256, 0, stream>>>(OpU, mpart, lpart, Oatt);
        oproj_kernel<<<dim3(24, 64), 256, 0, stream>>>(Oatt, Wo, bo, out, 0);
    } else {
        // fallback: Oatt in d_out (overlays dead Qb) with descending-row
        // 3-split oproj for WAR safety.
        u16* Oatt = base;
        combine_kernel<<<dim3(128, NH), 256, 0, stream>>>(OpU, mpart, lpart, Oatt);
        oproj_kernel<<<dim3(24, 58), 256, 0, stream>>>(Oatt, Wo, bo, out, 384);
        oproj_kernel<<<dim3(24,  5), 256, 0, stream>>>(Oatt, Wo, bo, out, 64);
        oproj_kernel<<<dim3(24,  1), 256, 0, stream>>>(Oatt, Wo, bo, out, 0);
    }
}

// Round 12
// 199.546 us; speedup vs baseline: 2.1741x; 1.0358x over previous
//
#include <hip/hip_runtime.h>
#include <hip/hip_bf16.h>

#define N_SEQ 4096
#define DIMM  1536
#define NH    4
#define DK    64
#define HD    256     // NH*DK
#define QK_SCALE 0.125f
#define WSZ   393216  // 1536*256 per weight
#define KSPLIT 8
#define LOG2E 1.44269504f

typedef __bf16 bf16x8 __attribute__((ext_vector_type(8)));
typedef unsigned short u16;
typedef unsigned int u32;
typedef u16   u16x8  __attribute__((ext_vector_type(8)));
typedef u16   u16x4  __attribute__((ext_vector_type(4)));
typedef float f32x4  __attribute__((ext_vector_type(4)));
typedef float f32x16 __attribute__((ext_vector_type(16)));
typedef unsigned int u32x4 __attribute__((ext_vector_type(4)));

__device__ inline float b2f(u16 u){
    union { float f; unsigned int i; } v; v.i = ((unsigned int)u) << 16; return v.f;
}
__device__ inline u16 f2b(float f){
    __bf16 h = (__bf16)f;               // native cvt, RNE
    return __builtin_bit_cast(u16, h);
}
__device__ inline bf16x8 ldfrag(const u16* p){
    return __builtin_bit_cast(bf16x8, *(const u16x8*)p);
}
__device__ inline f32x16 zero16(){
    f32x16 v;
    #pragma unroll
    for (int i = 0; i < 16; ++i) v[i] = 0.f;
    return v;
}
#define EXP2(x) exp2f(x)   // lowers to a single v_exp_f32 on gfx950

// ---------------------------------------------------------------------------
// Prep (one launch): [0,288) Wq|Wk|Wv fp32 -> bf16 Wt[n][k] transpose;
// [288,304) fmtab; 304 suffix-summed rel weights; [305,401) Wo fp32 ->
// bf16 WoT[n][k] transpose (only launched when workspace fits).
// ---------------------------------------------------------------------------
__global__ __launch_bounds__(256) void prep_kernel(const float* __restrict__ Wq,
    const float* __restrict__ Wk, const float* __restrict__ Wv, u16* __restrict__ Wt,
    unsigned char* __restrict__ fmt, const float* __restrict__ Wrel,
    u16* __restrict__ WsP, u16* __restrict__ WsM,
    const float* __restrict__ Wo, u16* __restrict__ WoT){
    int bid = blockIdx.x;
    int t = threadIdx.x;
    if (bid < 288){
        __shared__ float T[64 * 65];
        int s = bid / 96, tile = bid % 96;
        int n0 = (tile / 24) * 64;
        int k0 = (tile % 24) * 64;
        const float* W = (s == 0) ? Wq : (s == 1 ? Wk : Wv);
        int rA = t >> 3, c8 = (t & 7) * 8;
        #pragma unroll
        for (int rep = 0; rep < 2; ++rep){
            int rr = rep * 32 + rA;
            const float* p = W + (size_t)(k0 + rr) * HD + n0 + c8;
            f32x4 a = *(const f32x4*)p, b = *(const f32x4*)(p + 4);
            #pragma unroll
            for (int e = 0; e < 4; ++e){
                T[rr * 65 + c8 + e]     = a[e];
                T[rr * 65 + c8 + 4 + e] = b[e];
            }
        }
        __syncthreads();
        #pragma unroll
        for (int rep = 0; rep < 2; ++rep){
            int rn = rep * 32 + rA;
            u16x8 o;
            #pragma unroll
            for (int e = 0; e < 8; ++e) o[e] = f2b(T[(c8 + e) * 65 + rn]);
            *(u16x8*)&Wt[(size_t)s * WSZ + (size_t)(n0 + rn) * DIMM + k0 + c8] = o;
        }
        return;
    }
    if (bid >= 305){
        // Wo [256][1536] fp32 -> WoT [1536][256] bf16
        __shared__ float T[64 * 65];
        int tile = bid - 305;             // 0..95
        int n0 = (tile / 4) * 64;         // 24 n-tiles
        int k0 = (tile % 4) * 64;         // 4 k-tiles
        int rA = t >> 3, c8 = (t & 7) * 8;
        #pragma unroll
        for (int rep = 0; rep < 2; ++rep){
            int rr = rep * 32 + rA;
            const float* p = Wo + (size_t)(k0 + rr) * DIMM + n0 + c8;
            f32x4 a = *(const f32x4*)p, b = *(const f32x4*)(p + 4);
            #pragma unroll
            for (int e = 0; e < 4; ++e){
                T[rr * 65 + c8 + e]     = a[e];
                T[rr * 65 + c8 + 4 + e] = b[e];
            }
        }
        __syncthreads();
        #pragma unroll
        for (int rep = 0; rep < 2; ++rep){
            int rn = rep * 32 + rA;
            u16x8 o;
            #pragma unroll
            for (int e = 0; e < 8; ++e) o[e] = f2b(T[(c8 + e) * 65 + rn]);
            *(u16x8*)&WoT[(size_t)(n0 + rn) * HD + k0 + c8] = o;
        }
        return;
    }
    if (bid == 304){
        int h = t >> 6, d = t & 63;
        float w1[32], w2[32];
        #pragma unroll
        for (int fm = 0; fm < 32; ++fm){
            w1[fm] = Wrel[(size_t)fm * HD + h * DK + d];
            w2[fm] = Wrel[(size_t)(32 + fm) * HD + h * DK + d];
        }
        float a1 = 0.f, a2 = 0.f;
        #pragma unroll
        for (int fm = 31; fm >= 0; --fm){
            a1 += w1[fm];
            a2 += w2[fm];
            WsP[(h * 32 + fm) * 64 + d] = f2b(a1 + a2);
            WsM[(h * 32 + fm) * 64 + d] = f2b(a1 - a2);
        }
        return;
    }
    int d = (bid - 288) * 256 + t;
    float lg = logf((float)(N_SEQ + 1)) * (1.0f / 32.0f);
    float ad = (float)d;
    int fm = 0;
    for (int f = 0; f < 32; ++f){
        float cw = expf(lg * (float)(f + 1)) - 1.0f;
        fm += (cw <= ad) ? 1 : 0;
    }
    fmt[d] = (unsigned char)fm;
}

// ---------------------------------------------------------------------------
// QKV projection v3: M-tile 32 (grid 12 x 128 = 1536 blocks, 6/CU) +
// reg-prefetch pipeline. Wave (wr,wc) = (w&1, w>>1): rows wr*16+16,
// cols wc*32+32 (2 col-tiles).
// ---------------------------------------------------------------------------
__global__ __launch_bounds__(256) void qkv_kernel(const float* __restrict__ X,
    const u16* __restrict__ Wt,
    u16* __restrict__ Q, u16* __restrict__ K, u16* __restrict__ Vt){
    __shared__ __align__(16) u16 xs[32 * 72];
    __shared__ __align__(16) u16 bs[64 * 72];
    int s  = blockIdx.x >> 2;             // 0:Q 1:K 2:V
    int n0 = (blockIdx.x & 3) * 64;
    int m0 = blockIdx.y * 32;
    int t = threadIdx.x;
    int w = t >> 6, lane = t & 63, qd = lane >> 4, l15 = lane & 15;
    int wr = w & 1, wc = w >> 1;
    int r  = t >> 3;                      // 0..31
    int cv = (t & 7) * 8;
    f32x4 acc[2] = {{0,0,0,0},{0,0,0,0}};

    f32x4 xa, xb;
    u16x8 wv[2];
    auto LOAD = [&](int k0){
        size_t xi = (size_t)(m0 + r) * DIMM + k0 + cv;
        xa = *(const f32x4*)(X + xi);
        xb = *(const f32x4*)(X + xi + 4);
        #pragma unroll
        for (int rep = 0; rep < 2; ++rep){
            int rr = rep * 32 + r;
            wv[rep] = *(const u16x8*)&Wt[(size_t)s * WSZ + (size_t)(n0 + rr) * DIMM + k0 + cv];
        }
    };
    auto STORE = [&](){
        u16x8 xv;
        #pragma unroll
        for (int e = 0; e < 4; ++e){ xv[e] = f2b(xa[e]); xv[4 + e] = f2b(xb[e]); }
        *(u16x8*)&xs[r * 72 + cv] = xv;
        #pragma unroll
        for (int rep = 0; rep < 2; ++rep){
            int rr = rep * 32 + r;
            *(u16x8*)&bs[rr * 72 + cv] = wv[rep];
        }
    };

    LOAD(0);
    for (int k0 = 0; k0 < DIMM; k0 += 64){
        STORE();
        __syncthreads();
        if (k0 + 64 < DIMM) LOAD(k0 + 64);
        bf16x8 a0 = ldfrag(&xs[(wr * 16 + l15) * 72 +  0 + qd * 8]);
        bf16x8 a1 = ldfrag(&xs[(wr * 16 + l15) * 72 + 32 + qd * 8]);
        #pragma unroll
        for (int nt = 0; nt < 2; ++nt){
            int nb = wc * 32 + nt * 16;
            bf16x8 b0 = ldfrag(&bs[(nb + l15) * 72 +  0 + qd * 8]);
            bf16x8 b1 = ldfrag(&bs[(nb + l15) * 72 + 32 + qd * 8]);
            acc[nt] = __builtin_amdgcn_mfma_f32_16x16x32_bf16(a0, b0, acc[nt], 0, 0, 0);
            acc[nt] = __builtin_amdgcn_mfma_f32_16x16x32_bf16(a1, b1, acc[nt], 0, 0, 0);
        }
        __syncthreads();
    }

    int row0 = m0 + wr * 16 + qd * 4;
    if (s == 0){
        #pragma unroll
        for (int nt = 0; nt < 2; ++nt){
            int col = n0 + wc * 32 + nt * 16 + l15;
            #pragma unroll
            for (int reg = 0; reg < 4; ++reg)
                Q[(size_t)(row0 + reg) * HD + col] = f2b(acc[nt][reg] * QK_SCALE);
        }
    } else if (s == 1){
        #pragma unroll
        for (int nt = 0; nt < 2; ++nt){
            int col = n0 + wc * 32 + nt * 16 + l15;
            #pragma unroll
            for (int reg = 0; reg < 4; ++reg)
                K[(size_t)(row0 + reg) * HD + col] = f2b(acc[nt][reg]);
        }
    } else {
        #pragma unroll
        for (int nt = 0; nt < 2; ++nt){
            int col = n0 + wc * 32 + nt * 16 + l15;
            u16x4 pv;
            #pragma unroll
            for (int reg = 0; reg < 4; ++reg) pv[reg] = f2b(acc[nt][reg]);
            *(u16x4*)&Vt[(size_t)col * N_SEQ + row0] = pv;
        }
    }
}

// ---------------------------------------------------------------------------
// Flash attention — R5-proven kernel, byte-identical to R11 (68.8 µs).
// ---------------------------------------------------------------------------
__global__ __launch_bounds__(256) void attn_kernel(const u16* __restrict__ Q,
    const u16* __restrict__ Kg, const u16* __restrict__ Vt,
    const u16* __restrict__ WsPg, const u16* __restrict__ WsMg,
    const unsigned char* __restrict__ fmtg,
    const float* __restrict__ CB, const float* __restrict__ PB,
    u16* __restrict__ OpU, float* __restrict__ mpart, float* __restrict__ lpart){
    __shared__ __align__(16) unsigned char smem[39936];
    u16* Ks   = (u16*)(smem);             // [64][72]  main loop
    u16* Vts  = (u16*)(smem + 9216);      // [64][72]  main loop
    u16* Qs   = (u16*)(smem);             // init alias: [128][72]
    u16* relP = (u16*)(smem + 18432);     // [128][34] u16 (slot 0 = d==0 value)
    u16* relM = (u16*)(smem + 27136);     // [128][34] u16
    unsigned char* fmt = smem + 35840;    // 4096
    u16* WsPs = (u16*)(smem + 18432);     // init alias: [32][72]
    u16* WsMs = (u16*)(smem + 23040);

    int i0   = blockIdx.x * 128;
    int h    = blockIdx.y;
    int half = blockIdx.z;                // 0..7
    int bid  = blockIdx.x * NH + h;       // 0..127
    int jbase = half * (N_SEQ / KSPLIT);
    const int NT = (N_SEQ / KSPLIT) / 64; // 8 tiles
    int t = threadIdx.x;
    int w = t >> 6, lane = t & 63, l31 = lane & 31, hbit = lane >> 5;
    int h8 = hbit * 8;
    int i_loc = w * 32 + l31;             // this lane's softmax row (block-local)

    int sr = t >> 3, scv = (t & 7) * 8;
    u16x8 kr0, kr1, vr0, vr1;
    auto LOAD = [&](int j0){
        kr0 = *(const u16x8*)&Kg[(size_t)(j0 + sr)      * HD + h * DK + scv];
        kr1 = *(const u16x8*)&Kg[(size_t)(j0 + 32 + sr) * HD + h * DK + scv];
        vr0 = *(const u16x8*)&Vt[(size_t)(h * 64 + sr)      * N_SEQ + j0 + scv];
        vr1 = *(const u16x8*)&Vt[(size_t)(h * 64 + 32 + sr) * N_SEQ + j0 + scv];
    };
    auto STORE = [&](){
        *(u16x8*)&Ks [(sr)      * 72 + scv] = kr0;
        *(u16x8*)&Ks [(32 + sr) * 72 + scv] = kr1;
        *(u16x8*)&Vts[(sr)      * 72 + scv] = vr0;
        *(u16x8*)&Vts[(32 + sr) * 72 + scv] = vr1;
    };
    LOAD(jbase);

    // ---- init staging: Q rows (raw bf16), Wsuf slices, fmt ----
    #pragma unroll
    for (int rep = 0; rep < 4; ++rep){
        int vid = rep * 256 + t;
        int r  = vid >> 3;
        int cv = (vid & 7) * 8;
        *(u16x8*)&Qs[r * 72 + cv] = *(const u16x8*)&Q[(size_t)(i0 + r) * HD + h * DK + cv];
    }
    {
        int r = t >> 3, cv = (t & 7) * 8;
        *(u16x8*)&WsPs[r * 72 + cv] = *(const u16x8*)&WsPg[(h * 32 + r) * 64 + cv];
        *(u16x8*)&WsMs[r * 72 + cv] = *(const u16x8*)&WsMg[(h * 32 + r) * 64 + cv];
    }
    ((uint4*)fmt)[t] = ((const uint4*)fmtg)[t];
    __syncthreads();

    // ---- per-lane Q fragments (B-operand layout), bias + LOG2E folded ----
    bf16x8 qcF[4], qpF[4];
    #pragma unroll
    for (int kc = 0; kc < 4; ++kc){
        bf16x8 raw = ldfrag(&Qs[i_loc * 72 + kc * 16 + h8]);
        const float* cbp = CB + h * DK + kc * 16 + h8;
        const float* pbp = PB + h * DK + kc * 16 + h8;
        bf16x8 qc, qp;
        #pragma unroll
        for (int e = 0; e < 8; ++e){
            float qf = (float)raw[e];
            qc[e] = (__bf16)((qf + cbp[e]) * LOG2E);
            qp[e] = (__bf16)((qf + pbp[e]) * LOG2E);
        }
        qcF[kc] = qc; qpF[kc] = qp;
    }

    // ---- rel tables via MFMA: C[fm][i] = Wsuf[fm] . qp[i]  (log2 domain) ----
    f32x16 rP = zero16(), rM = zero16();
    #pragma unroll
    for (int kc = 0; kc < 4; ++kc){
        bf16x8 aP = ldfrag(&WsPs[l31 * 72 + kc * 16 + h8]);
        bf16x8 aM = ldfrag(&WsMs[l31 * 72 + kc * 16 + h8]);
        rP = __builtin_amdgcn_mfma_f32_32x32x16_bf16(aP, qpF[kc], rP, 0, 0, 0);
        rM = __builtin_amdgcn_mfma_f32_32x32x16_bf16(aM, qpF[kc], rM, 0, 0, 0);
    }
    __syncthreads();   // all LDS reads (Qs, Wsuf) done before overwrites

    // fm==0 happens only at dd==0 (cw_1 > 0), so slot 0 stores the d==0
    // value (s1 only) and the slow path indexes by fm with NO select.
    #pragma unroll
    for (int r = 0; r < 16; ++r){
        int fm = (r & 3) + 8 * (r >> 2) + 4 * hbit;
        relP[i_loc * 34 + fm] = f2b(rP[r]);
        relM[i_loc * 34 + fm] = f2b(rM[r]);
    }
    if (hbit == 0)
        relP[i_loc * 34 + 0] = f2b((rP[0] + rM[0]) * 0.5f);  // d==0: s1
    STORE();           // K/V tile 0 into seg0 (Qs dead)
    __syncthreads();

    // ---- main K-loop ----
    float mrow = -1e30f, lacc = 0.f;
    f32x16 oacc0 = zero16(), oacc1 = zero16();

#define MFMA32(A, B, C) __builtin_amdgcn_mfma_f32_32x32x16_bf16(A, B, C, 0, 0, 0)

#define PACK8(ST, WD) { \
    _Pragma("unroll") \
    for (int q_ = 0; q_ < 8; ++q_){ \
        float pa_ = EXP2(ST[2 * q_]     - bias); \
        float pc_ = EXP2(ST[2 * q_ + 1] - bias); \
        lsum += pa_ + pc_; \
        WD[q_] = (unsigned int)f2b(pa_) | ((unsigned int)f2b(pc_) << 16); \
    } }

    // halved-shuffle fragment build: send (hbit ? a : b), receive the
    // other half's counterpart; 2 shuffles per fragment instead of 4.
#define MKFRAG(DST, WD, ZZ) { \
    unsigned int a0_ = WD[(ZZ) * 4 + 0], a1_ = WD[(ZZ) * 4 + 1]; \
    unsigned int b0_ = WD[(ZZ) * 4 + 2], b1_ = WD[(ZZ) * 4 + 3]; \
    unsigned int sh0_ = (unsigned int)__shfl_xor((int)(hbit ? a0_ : b0_), 32); \
    unsigned int sh1_ = (unsigned int)__shfl_xor((int)(hbit ? a1_ : b1_), 32); \
    u32x4 fw_; \
    fw_[0] = hbit ? sh0_ : a0_; \
    fw_[1] = hbit ? sh1_ : a1_; \
    fw_[2] = hbit ? b0_  : sh0_; \
    fw_[3] = hbit ? b1_  : sh1_; \
    DST = __builtin_bit_cast(bf16x8, fw_); }

#define PVSTEP(PF, COL) { \
    oacc0 = MFMA32(PF, ldfrag(&Vts[(l31)      * 72 + (COL) + h8]), oacc0); \
    oacc1 = MFMA32(PF, ldfrag(&Vts[(32 + l31) * 72 + (COL) + h8]), oacc1); }

    const u16* relP_i = relP + i_loc * 34;
    const u16* relM_i = relM + i_loc * 34;

    for (int kt = 0; kt < NT; ++kt){
        int j0 = jbase + kt * 64;
        if (kt + 1 < NT) LOAD(j0 + 64);

        // S^T = K . Q^T : st0 = rows j 0..31, st1 = rows j 32..63; col i = lane&31
        f32x16 st0 = zero16(), st1 = zero16();
        __builtin_amdgcn_s_setprio(1);
        #pragma unroll
        for (int kc = 0; kc < 4; ++kc){
            bf16x8 k0 = ldfrag(&Ks[(l31)      * 72 + kc * 16 + h8]);
            bf16x8 k1 = ldfrag(&Ks[(32 + l31) * 72 + kc * 16 + h8]);
            st0 = MFMA32(k0, qcF[kc], st0);
            st1 = MFMA32(k1, qcF[kc], st1);
        }
        __builtin_amdgcn_s_setprio(0);

        // rel merge: fast path keeps st raw and folds relv into the exp bias
        int D = j0 - i0;
        int Di = D - i_loc;
        float relv = 0.f;
        bool fast = false; int fmU = 0; const u16* tabU = relP_i;
        if (D >= 128){
            int fa = fmt[D - 127], fb = fmt[D + 63];
            fast = (fa == fb); fmU = fa; tabU = relP_i;
        } else if (D <= -64){
            int fa = fmt[-D - 63], fb = fmt[-D + 127];
            fast = (fa == fb); fmU = fa; tabU = relM_i;
        }
        if (fast){
            relv = b2f(tabU[fmU]);
        } else {
            #pragma unroll
            for (int r = 0; r < 16; ++r){
                const int jb = (r & 3) + 8 * (r >> 2);
                int jbh = jb + 4 * hbit;
                {
                    int dd = Di + jbh;
                    int ad = dd < 0 ? -dd : dd;
                    int fm = fmt[ad];
                    const u16* tab = (dd >= 0) ? relP_i : relM_i;
                    st0[r] += b2f(tab[fm]);
                }
                {
                    int dd = Di + 32 + jbh;
                    int ad = dd < 0 ? -dd : dd;
                    int fm = fmt[ad];
                    const u16* tab = (dd >= 0) ? relP_i : relM_i;
                    st1[r] += b2f(tab[fm]);
                }
            }
        }

        // row max (lane-local + one cross-half shuffle); relv added once
        float mx = st0[0];
        #pragma unroll
        for (int r = 1; r < 16; ++r) mx = fmaxf(mx, st0[r]);
        #pragma unroll
        for (int r = 0; r < 16; ++r) mx = fmaxf(mx, st1[r]);
        mx = fmaxf(mx, __shfl_xor(mx, 32)) + relv;

        // defer-max (log2 domain, THR = 11 ~ e^7.6)
        if (!__all(mx - mrow <= 11.0f)){
            float mnew = fmaxf(mrow, mx);
            float alpha = EXP2(mrow - mnew);
            mrow = mnew;
            lacc *= alpha;
            #pragma unroll
            for (int r = 0; r < 16; ++r){
                float ar = __shfl(alpha, (r & 3) + 8 * (r >> 2) + 4 * hbit);
                oacc0[r] *= ar; oacc1[r] *= ar;
            }
        }

        // P = exp2(st - bias), bias = mrow - relv; l from unrounded floats
        float bias = mrow - relv;
        float lsum = 0.f;
        unsigned int wds0[8], wds1[8];
        PACK8(st0, wds0)
        PACK8(st1, wds1)
        lacc += lsum + __shfl_xor(lsum, 32);

        // in-register transpose to PV A-fragments (rows i = lane&31)
        bf16x8 pf0, pf1, pf2, pf3;
        MKFRAG(pf0, wds0, 0)   // j  0..15
        MKFRAG(pf1, wds0, 1)   // j 16..31
        MKFRAG(pf2, wds1, 0)   // j 32..47
        MKFRAG(pf3, wds1, 1)   // j 48..63
        __builtin_amdgcn_s_setprio(1);
        PVSTEP(pf0,  0)
        PVSTEP(pf1, 16)
        PVSTEP(pf2, 32)
        PVSTEP(pf3, 48)
        __builtin_amdgcn_s_setprio(0);

        __syncthreads();
        if (kt + 1 < NT) STORE();
        __syncthreads();
    }

    // ---- write partials ----
    size_t pb = ((size_t)half * 128 + bid) * 128;
    #pragma unroll
    for (int r = 0; r < 16; ++r){
        int iO = w * 32 + (r & 3) + 8 * (r >> 2) + 4 * hbit;
        OpU[(pb + iO) * 64 + l31]      = f2b(oacc0[r]);
        OpU[(pb + iO) * 64 + 32 + l31] = f2b(oacc1[r]);
    }
    if (hbit == 0){
        mpart[pb + i_loc] = mrow;
        lpart[pb + i_loc] = lacc;
    }
#undef MFMA32
#undef PACK8
#undef MKFRAG
#undef PVSTEP
}

// ---------------------------------------------------------------------------
// Combine 8 K-eighths -> normalized bf16 Oatt (512 blocks).
// ---------------------------------------------------------------------------
__global__ __launch_bounds__(256) void combine_kernel(const u16* __restrict__ OpU,
    const float* __restrict__ mpart, const float* __restrict__ lpart,
    u16* __restrict__ Oatt){
    int h = blockIdx.y;
    int t = threadIdx.x;
    int r = t >> 3, cb = (t & 7) * 8;
    int i = blockIdx.x * 32 + r;
    int bid = (i >> 7) * NH + h;
    int ri = i & 127;
    size_t pr[8];
    float ms[8], ls[8];
    float m = -1e30f;
    #pragma unroll
    for (int s = 0; s < 8; ++s){
        pr[s] = ((size_t)s * 128 + bid) * 128 + ri;
        ms[s] = mpart[pr[s]];
        ls[s] = lpart[pr[s]];
        m = fmaxf(m, ms[s]);
    }
    float den = 0.f, wgt[8];
    #pragma unroll
    for (int s = 0; s < 8; ++s){ wgt[s] = EXP2(ms[s] - m); den += wgt[s] * ls[s]; }
    float inv = 1.0f / fmaxf(den, 1e-30f);
    float o[8];
    #pragma unroll
    for (int e = 0; e < 8; ++e) o[e] = 0.f;
    #pragma unroll
    for (int s = 0; s < 8; ++s){
        u16x8 a = *(const u16x8*)&OpU[pr[s] * 64 + cb];
        #pragma unroll
        for (int e = 0; e < 8; ++e) o[e] += wgt[s] * b2f(a[e]);
    }
    u16x8 rv;
    #pragma unroll
    for (int e = 0; e < 8; ++e) rv[e] = f2b(o[e] * inv);
    *(u16x8*)&Oatt[(size_t)i * HD + h * DK + cb] = rv;
}

// ---------------------------------------------------------------------------
// Output projection (bf16 WoT path): out = Oattn @ Wo + bo. Staging is a
// clean u16x8 load+store for BOTH operands (no fp32 cvt, no scalar
// transposed stores).
// ---------------------------------------------------------------------------
__global__ __launch_bounds__(256) void oproj_kernel(const u16* __restrict__ A,
    const u16* __restrict__ WoT, const float* __restrict__ bo,
    float* __restrict__ out, int m_base){
    __shared__ __align__(16) u16 xs[64 * 72];
    __shared__ __align__(16) u16 bs[64 * 72];
    int m0 = m_base + blockIdx.y * 64;
    int n0 = blockIdx.x * 64;
    int t = threadIdx.x;
    int w = t >> 6, lane = t & 63, qd = lane >> 4, l15 = lane & 15;
    f32x4 acc[4] = {{0,0,0,0},{0,0,0,0},{0,0,0,0},{0,0,0,0}};
    for (int k0 = 0; k0 < HD; k0 += 64){
        #pragma unroll
        for (int rep = 0; rep < 2; ++rep){
            int vid = rep * 256 + t;
            int r  = vid >> 3;
            int cv = (vid & 7) * 8;
            *(u16x8*)&xs[r * 72 + cv] = *(const u16x8*)&A[(size_t)(m0 + r) * HD + k0 + cv];
            *(u16x8*)&bs[r * 72 + cv] = *(const u16x8*)&WoT[(size_t)(n0 + r) * HD + k0 + cv];
        }
        __syncthreads();
        bf16x8 a0 = ldfrag(&xs[(w * 16 + l15) * 72 +  0 + qd * 8]);
        bf16x8 a1 = ldfrag(&xs[(w * 16 + l15) * 72 + 32 + qd * 8]);
        #pragma unroll
        for (int nt = 0; nt < 4; ++nt){
            bf16x8 b0 = ldfrag(&bs[(nt * 16 + l15) * 72 +  0 + qd * 8]);
            bf16x8 b1 = ldfrag(&bs[(nt * 16 + l15) * 72 + 32 + qd * 8]);
            acc[nt] = __builtin_amdgcn_mfma_f32_16x16x32_bf16(a0, b0, acc[nt], 0, 0, 0);
            acc[nt] = __builtin_amdgcn_mfma_f32_16x16x32_bf16(a1, b1, acc[nt], 0, 0, 0);
        }
        __syncthreads();
    }
    #pragma unroll
    for (int nt = 0; nt < 4; ++nt)
        #pragma unroll
        for (int reg = 0; reg < 4; ++reg){
            int row = m0 + w * 16 + qd * 4 + reg;
            int col = n0 + nt * 16 + l15;
            out[(size_t)row * DIMM + col] = acc[nt][reg] + bo[col];
        }
}

// ---------------------------------------------------------------------------
// Output projection (fp32 Wo fallback, unchanged from R11).
// ---------------------------------------------------------------------------
__global__ __launch_bounds__(256) void oproj_f32_kernel(const u16* __restrict__ A,
    const float* __restrict__ Wo, const float* __restrict__ bo,
    float* __restrict__ out, int m_base){
    __shared__ __align__(16) u16 xs[64 * 72];
    __shared__ __align__(16) u16 bs[64 * 72];
    int m0 = m_base + blockIdx.y * 64;
    int n0 = blockIdx.x * 64;
    int t = threadIdx.x;
    int w = t >> 6, lane = t & 63, qd = lane >> 4, l15 = lane & 15;
    f32x4 acc[4] = {{0,0,0,0},{0,0,0,0},{0,0,0,0},{0,0,0,0}};
    for (int k0 = 0; k0 < HD; k0 += 64){
        #pragma unroll
        for (int rep = 0; rep < 2; ++rep){
            int vid = rep * 256 + t;
            int r  = vid >> 3;
            int cv = (vid & 7) * 8;
            *(u16x8*)&xs[r * 72 + cv] = *(const u16x8*)&A[(size_t)(m0 + r) * HD + k0 + cv];
            size_t wi = (size_t)(k0 + r) * DIMM + n0 + cv;
            f32x4 wa = *(const f32x4*)(Wo + wi), wb = *(const f32x4*)(Wo + wi + 4);
            u16x8 wv;
            #pragma unroll
            for (int e = 0; e < 4; ++e){ wv[e] = f2b(wa[e]); wv[4 + e] = f2b(wb[e]); }
            #pragma unroll
            for (int e = 0; e < 8; ++e) bs[(cv + e) * 72 + r] = wv[e];
        }
        __syncthreads();
        bf16x8 a0 = ldfrag(&xs[(w * 16 + l15) * 72 +  0 + qd * 8]);
        bf16x8 a1 = ldfrag(&xs[(w * 16 + l15) * 72 + 32 + qd * 8]);
        #pragma unroll
        for (int nt = 0; nt < 4; ++nt){
            bf16x8 b0 = ldfrag(&bs[(nt * 16 + l15) * 72 +  0 + qd * 8]);
            bf16x8 b1 = ldfrag(&bs[(nt * 16 + l15) * 72 + 32 + qd * 8]);
            acc[nt] = __builtin_amdgcn_mfma_f32_16x16x32_bf16(a0, b0, acc[nt], 0, 0, 0);
            acc[nt] = __builtin_amdgcn_mfma_f32_16x16x32_bf16(a1, b1, acc[nt], 0, 0, 0);
        }
        __syncthreads();
    }
    #pragma unroll
    for (int nt = 0; nt < 4; ++nt)
        #pragma unroll
        for (int reg = 0; reg < 4; ++reg){
            int row = m0 + w * 16 + qd * 4 + reg;
            int col = n0 + nt * 16 + l15;
            out[(size_t)row * DIMM + col] = acc[nt][reg] + bo[col];
        }
}

extern "C" void kernel_launch(void* const* d_in, const int* in_sizes, int n_in,
                              void* d_out, int out_size, void* d_ws, size_t ws_size,
                              hipStream_t stream){
    const float* X  = (const float*)d_in[0];
    const float* Wq = (const float*)d_in[1];
    const float* Wk = (const float*)d_in[2];
    const float* Wv = (const float*)d_in[3];
    const float* Wr = (const float*)d_in[4];
    const float* Wo = (const float*)d_in[5];
    const float* bo = (const float*)d_in[6];
    const float* CB = (const float*)d_in[7];
    const float* PB = (const float*)d_in[8];
    float* out = (float*)d_out;
    u16* base = (u16*)d_out;   // 12,582,912 u16 slots

    // d_out scratch (u16 offsets): Qb[0,1048576) Kb[1048576,2097152)
    // Vt[2097152,3145728) Wt[3145728,4325376) (dead after qkv; OpU overlays)
    // OpU[3145728,11534336) mpart/lpart f32 after.
    u16* Qb   = base;
    u16* Kb   = base + 1048576;
    u16* Vt   = base + 2097152;
    u16* Wt   = base + 3145728;
    u16* OpU  = base + 3145728;
    float* mpart = out + 5767168;
    float* lpart = out + 5898240;

    // d_ws layout: fmt[0,4096) WsP[4096,20480) WsM[20480,36864)
    //   WoT u16 @36864 (786,432 B) -> 823,296
    //   Oatt u16 @823,296 (2,097,152 B) -> 2,920,448
    unsigned char* fmtg = (unsigned char*)d_ws;
    u16* WsP = (u16*)((char*)d_ws + 4096);
    u16* WsM = (u16*)((char*)d_ws + 20480);
    u16* WoT = (u16*)((char*)d_ws + 36864);
    bool ws_ok = ws_size >= 2920448;

    prep_kernel<<<dim3(ws_ok ? 401 : 305), 256, 0, stream>>>(
        Wq, Wk, Wv, Wt, fmtg, Wr, WsP, WsM, Wo, WoT);
    qkv_kernel<<<dim3(12, 128), 256, 0, stream>>>(X, Wt, Qb, Kb, Vt);
    attn_kernel<<<dim3(32, NH, KSPLIT), 256, 0, stream>>>(Qb, Kb, Vt, WsP, WsM,
                                                          fmtg, CB, PB,
                                                          OpU, mpart, lpart);

    if (ws_ok){
        u16* Oatt = (u16*)((char*)d_ws + 823296);
        combine_kernel<<<dim3(128, NH), 256, 0, stream>>>(OpU, mpart, lpart, Oatt);
        oproj_kernel<<<dim3(24, 64), 256, 0, stream>>>(Oatt, WoT, bo, out, 0);
    } else {
        // fallback: Oatt in d_out (overlays dead Qb) with descending-row
        // 3-split fp32-Wo oproj for WAR safety.
        u16* Oatt = base;
        combine_kernel<<<dim3(128, NH), 256, 0, stream>>>(OpU, mpart, lpart, Oatt);
        oproj_f32_kernel<<<dim3(24, 58), 256, 0, stream>>>(Oatt, Wo, bo, out, 384);
        oproj_f32_kernel<<<dim3(24,  5), 256, 0, stream>>>(Oatt, Wo, bo, out, 64);
        oproj_f32_kernel<<<dim3(24,  1), 256, 0, stream>>>(Oatt, Wo, bo, out, 0);
    }
}

// Round 13
// 198.021 us; speedup vs baseline: 2.1908x; 1.0077x over previous
//
#include <hip/hip_runtime.h>
#include <hip/hip_bf16.h>

#define N_SEQ 4096
#define DIMM  1536
#define NH    4
#define DK    64
#define HD    256     // NH*DK
#define QK_SCALE 0.125f
#define WSZ   393216  // 1536*256 per weight
#define KSPLIT 8
#define LOG2E 1.44269504f

typedef __bf16 bf16x8 __attribute__((ext_vector_type(8)));
typedef unsigned short u16;
typedef unsigned int u32;
typedef u16   u16x8  __attribute__((ext_vector_type(8)));
typedef u16   u16x4  __attribute__((ext_vector_type(4)));
typedef float f32x4  __attribute__((ext_vector_type(4)));
typedef float f32x16 __attribute__((ext_vector_type(16)));
typedef unsigned int u32x4 __attribute__((ext_vector_type(4)));

__device__ inline float b2f(u16 u){
    union { float f; unsigned int i; } v; v.i = ((unsigned int)u) << 16; return v.f;
}
__device__ inline u16 f2b(float f){
    __bf16 h = (__bf16)f;               // native cvt, RNE
    return __builtin_bit_cast(u16, h);
}
__device__ inline bf16x8 ldfrag(const u16* p){
    return __builtin_bit_cast(bf16x8, *(const u16x8*)p);
}
__device__ inline f32x16 zero16(){
    f32x16 v;
    #pragma unroll
    for (int i = 0; i < 16; ++i) v[i] = 0.f;
    return v;
}
#define EXP2(x) exp2f(x)   // lowers to a single v_exp_f32 on gfx950

// ---------------------------------------------------------------------------
// Prep (one launch): [0,288) Wq|Wk|Wv fp32 -> bf16 Wt[n][k] transpose;
// [288,304) fmtab; 304 suffix-summed rel weights; [305,401) Wo fp32 ->
// bf16 WoT[n][k] transpose (only launched when workspace fits).
// ---------------------------------------------------------------------------
__global__ __launch_bounds__(256) void prep_kernel(const float* __restrict__ Wq,
    const float* __restrict__ Wk, const float* __restrict__ Wv, u16* __restrict__ Wt,
    unsigned char* __restrict__ fmt, const float* __restrict__ Wrel,
    u16* __restrict__ WsP, u16* __restrict__ WsM,
    const float* __restrict__ Wo, u16* __restrict__ WoT){
    int bid = blockIdx.x;
    int t = threadIdx.x;
    if (bid < 288){
        __shared__ float T[64 * 65];
        int s = bid / 96, tile = bid % 96;
        int n0 = (tile / 24) * 64;
        int k0 = (tile % 24) * 64;
        const float* W = (s == 0) ? Wq : (s == 1 ? Wk : Wv);
        int rA = t >> 3, c8 = (t & 7) * 8;
        #pragma unroll
        for (int rep = 0; rep < 2; ++rep){
            int rr = rep * 32 + rA;
            const float* p = W + (size_t)(k0 + rr) * HD + n0 + c8;
            f32x4 a = *(const f32x4*)p, b = *(const f32x4*)(p + 4);
            #pragma unroll
            for (int e = 0; e < 4; ++e){
                T[rr * 65 + c8 + e]     = a[e];
                T[rr * 65 + c8 + 4 + e] = b[e];
            }
        }
        __syncthreads();
        #pragma unroll
        for (int rep = 0; rep < 2; ++rep){
            int rn = rep * 32 + rA;
            u16x8 o;
            #pragma unroll
            for (int e = 0; e < 8; ++e) o[e] = f2b(T[(c8 + e) * 65 + rn]);
            *(u16x8*)&Wt[(size_t)s * WSZ + (size_t)(n0 + rn) * DIMM + k0 + c8] = o;
        }
        return;
    }
    if (bid >= 305){
        // Wo [256][1536] fp32 -> WoT [1536][256] bf16
        __shared__ float T[64 * 65];
        int tile = bid - 305;             // 0..95
        int n0 = (tile / 4) * 64;         // 24 n-tiles
        int k0 = (tile % 4) * 64;         // 4 k-tiles
        int rA = t >> 3, c8 = (t & 7) * 8;
        #pragma unroll
        for (int rep = 0; rep < 2; ++rep){
            int rr = rep * 32 + rA;
            const float* p = Wo + (size_t)(k0 + rr) * DIMM + n0 + c8;
            f32x4 a = *(const f32x4*)p, b = *(const f32x4*)(p + 4);
            #pragma unroll
            for (int e = 0; e < 4; ++e){
                T[rr * 65 + c8 + e]     = a[e];
                T[rr * 65 + c8 + 4 + e] = b[e];
            }
        }
        __syncthreads();
        #pragma unroll
        for (int rep = 0; rep < 2; ++rep){
            int rn = rep * 32 + rA;
            u16x8 o;
            #pragma unroll
            for (int e = 0; e < 8; ++e) o[e] = f2b(T[(c8 + e) * 65 + rn]);
            *(u16x8*)&WoT[(size_t)(n0 + rn) * HD + k0 + c8] = o;
        }
        return;
    }
    if (bid == 304){
        int h = t >> 6, d = t & 63;
        float w1[32], w2[32];
        #pragma unroll
        for (int fm = 0; fm < 32; ++fm){
            w1[fm] = Wrel[(size_t)fm * HD + h * DK + d];
            w2[fm] = Wrel[(size_t)(32 + fm) * HD + h * DK + d];
        }
        float a1 = 0.f, a2 = 0.f;
        #pragma unroll
        for (int fm = 31; fm >= 0; --fm){
            a1 += w1[fm];
            a2 += w2[fm];
            WsP[(h * 32 + fm) * 64 + d] = f2b(a1 + a2);
            WsM[(h * 32 + fm) * 64 + d] = f2b(a1 - a2);
        }
        return;
    }
    int d = (bid - 288) * 256 + t;
    float lg = logf((float)(N_SEQ + 1)) * (1.0f / 32.0f);
    float ad = (float)d;
    int fm = 0;
    for (int f = 0; f < 32; ++f){
        float cw = expf(lg * (float)(f + 1)) - 1.0f;
        fm += (cw <= ad) ? 1 : 0;
    }
    fmt[d] = (unsigned char)fm;
}

// ---------------------------------------------------------------------------
// QKV projection v4: 1D grid (1536 blocks) with CHUNKED XCD SWIZZLE.
// The 12 blocks (3 proj x 4 n-tiles) sharing an X m-tile are consecutive in
// work order; default dispatch round-robins them over the 8 non-coherent
// per-XCD L2s, so X is re-fetched ~8x from L3. Chunking (xcd = lid&7, 192
// consecutive work items per XCD) makes each XCD's X working set (16
// m-groups x 196 KB = 3.1 MB) L2-resident. 1536%8==0 -> bijective.
// ---------------------------------------------------------------------------
__global__ __launch_bounds__(256) void qkv_kernel(const float* __restrict__ X,
    const u16* __restrict__ Wt,
    u16* __restrict__ Q, u16* __restrict__ K, u16* __restrict__ Vt){
    __shared__ __align__(16) u16 xs[32 * 72];
    __shared__ __align__(16) u16 bs[64 * 72];
    int lid = blockIdx.x;                 // 0..1535
    int xcd = lid & 7, loc = lid >> 3;
    int sw  = xcd * 192 + loc;            // chunked work id
    int mg  = sw / 12, inner = sw % 12;
    int s  = inner >> 2;                  // 0:Q 1:K 2:V
    int n0 = (inner & 3) * 64;
    int m0 = mg * 32;
    int t = threadIdx.x;
    int w = t >> 6, lane = t & 63, qd = lane >> 4, l15 = lane & 15;
    int wr = w & 1, wc = w >> 1;
    int r  = t >> 3;                      // 0..31
    int cv = (t & 7) * 8;
    f32x4 acc[2] = {{0,0,0,0},{0,0,0,0}};

    f32x4 xa, xb;
    u16x8 wv[2];
    auto LOAD = [&](int k0){
        size_t xi = (size_t)(m0 + r) * DIMM + k0 + cv;
        xa = *(const f32x4*)(X + xi);
        xb = *(const f32x4*)(X + xi + 4);
        #pragma unroll
        for (int rep = 0; rep < 2; ++rep){
            int rr = rep * 32 + r;
            wv[rep] = *(const u16x8*)&Wt[(size_t)s * WSZ + (size_t)(n0 + rr) * DIMM + k0 + cv];
        }
    };
    auto STORE = [&](){
        u16x8 xv;
        #pragma unroll
        for (int e = 0; e < 4; ++e){ xv[e] = f2b(xa[e]); xv[4 + e] = f2b(xb[e]); }
        *(u16x8*)&xs[r * 72 + cv] = xv;
        #pragma unroll
        for (int rep = 0; rep < 2; ++rep){
            int rr = rep * 32 + r;
            *(u16x8*)&bs[rr * 72 + cv] = wv[rep];
        }
    };

    LOAD(0);
    for (int k0 = 0; k0 < DIMM; k0 += 64){
        STORE();
        __syncthreads();
        if (k0 + 64 < DIMM) LOAD(k0 + 64);
        bf16x8 a0 = ldfrag(&xs[(wr * 16 + l15) * 72 +  0 + qd * 8]);
        bf16x8 a1 = ldfrag(&xs[(wr * 16 + l15) * 72 + 32 + qd * 8]);
        #pragma unroll
        for (int nt = 0; nt < 2; ++nt){
            int nb = wc * 32 + nt * 16;
            bf16x8 b0 = ldfrag(&bs[(nb + l15) * 72 +  0 + qd * 8]);
            bf16x8 b1 = ldfrag(&bs[(nb + l15) * 72 + 32 + qd * 8]);
            acc[nt] = __builtin_amdgcn_mfma_f32_16x16x32_bf16(a0, b0, acc[nt], 0, 0, 0);
            acc[nt] = __builtin_amdgcn_mfma_f32_16x16x32_bf16(a1, b1, acc[nt], 0, 0, 0);
        }
        __syncthreads();
    }

    int row0 = m0 + wr * 16 + qd * 4;
    if (s == 0){
        #pragma unroll
        for (int nt = 0; nt < 2; ++nt){
            int col = n0 + wc * 32 + nt * 16 + l15;
            #pragma unroll
            for (int reg = 0; reg < 4; ++reg)
                Q[(size_t)(row0 + reg) * HD + col] = f2b(acc[nt][reg] * QK_SCALE);
        }
    } else if (s == 1){
        #pragma unroll
        for (int nt = 0; nt < 2; ++nt){
            int col = n0 + wc * 32 + nt * 16 + l15;
            #pragma unroll
            for (int reg = 0; reg < 4; ++reg)
                K[(size_t)(row0 + reg) * HD + col] = f2b(acc[nt][reg]);
        }
    } else {
        #pragma unroll
        for (int nt = 0; nt < 2; ++nt){
            int col = n0 + wc * 32 + nt * 16 + l15;
            u16x4 pv;
            #pragma unroll
            for (int reg = 0; reg < 4; ++reg) pv[reg] = f2b(acc[nt][reg]);
            *(u16x4*)&Vt[(size_t)col * N_SEQ + row0] = pv;
        }
    }
}

// ---------------------------------------------------------------------------
// Flash attention — R5-proven kernel, byte-identical to R11/R12 (68.5 µs).
// ---------------------------------------------------------------------------
__global__ __launch_bounds__(256) void attn_kernel(const u16* __restrict__ Q,
    const u16* __restrict__ Kg, const u16* __restrict__ Vt,
    const u16* __restrict__ WsPg, const u16* __restrict__ WsMg,
    const unsigned char* __restrict__ fmtg,
    const float* __restrict__ CB, const float* __restrict__ PB,
    u16* __restrict__ OpU, float* __restrict__ mpart, float* __restrict__ lpart){
    __shared__ __align__(16) unsigned char smem[39936];
    u16* Ks   = (u16*)(smem);             // [64][72]  main loop
    u16* Vts  = (u16*)(smem + 9216);      // [64][72]  main loop
    u16* Qs   = (u16*)(smem);             // init alias: [128][72]
    u16* relP = (u16*)(smem + 18432);     // [128][34] u16 (slot 0 = d==0 value)
    u16* relM = (u16*)(smem + 27136);     // [128][34] u16
    unsigned char* fmt = smem + 35840;    // 4096
    u16* WsPs = (u16*)(smem + 18432);     // init alias: [32][72]
    u16* WsMs = (u16*)(smem + 23040);

    int i0   = blockIdx.x * 128;
    int h    = blockIdx.y;
    int half = blockIdx.z;                // 0..7
    int bid  = blockIdx.x * NH + h;       // 0..127
    int jbase = half * (N_SEQ / KSPLIT);
    const int NT = (N_SEQ / KSPLIT) / 64; // 8 tiles
    int t = threadIdx.x;
    int w = t >> 6, lane = t & 63, l31 = lane & 31, hbit = lane >> 5;
    int h8 = hbit * 8;
    int i_loc = w * 32 + l31;             // this lane's softmax row (block-local)

    int sr = t >> 3, scv = (t & 7) * 8;
    u16x8 kr0, kr1, vr0, vr1;
    auto LOAD = [&](int j0){
        kr0 = *(const u16x8*)&Kg[(size_t)(j0 + sr)      * HD + h * DK + scv];
        kr1 = *(const u16x8*)&Kg[(size_t)(j0 + 32 + sr) * HD + h * DK + scv];
        vr0 = *(const u16x8*)&Vt[(size_t)(h * 64 + sr)      * N_SEQ + j0 + scv];
        vr1 = *(const u16x8*)&Vt[(size_t)(h * 64 + 32 + sr) * N_SEQ + j0 + scv];
    };
    auto STORE = [&](){
        *(u16x8*)&Ks [(sr)      * 72 + scv] = kr0;
        *(u16x8*)&Ks [(32 + sr) * 72 + scv] = kr1;
        *(u16x8*)&Vts[(sr)      * 72 + scv] = vr0;
        *(u16x8*)&Vts[(32 + sr) * 72 + scv] = vr1;
    };
    LOAD(jbase);

    // ---- init staging: Q rows (raw bf16), Wsuf slices, fmt ----
    #pragma unroll
    for (int rep = 0; rep < 4; ++rep){
        int vid = rep * 256 + t;
        int r  = vid >> 3;
        int cv = (vid & 7) * 8;
        *(u16x8*)&Qs[r * 72 + cv] = *(const u16x8*)&Q[(size_t)(i0 + r) * HD + h * DK + cv];
    }
    {
        int r = t >> 3, cv = (t & 7) * 8;
        *(u16x8*)&WsPs[r * 72 + cv] = *(const u16x8*)&WsPg[(h * 32 + r) * 64 + cv];
        *(u16x8*)&WsMs[r * 72 + cv] = *(const u16x8*)&WsMg[(h * 32 + r) * 64 + cv];
    }
    ((uint4*)fmt)[t] = ((const uint4*)fmtg)[t];
    __syncthreads();

    // ---- per-lane Q fragments (B-operand layout), bias + LOG2E folded ----
    bf16x8 qcF[4], qpF[4];
    #pragma unroll
    for (int kc = 0; kc < 4; ++kc){
        bf16x8 raw = ldfrag(&Qs[i_loc * 72 + kc * 16 + h8]);
        const float* cbp = CB + h * DK + kc * 16 + h8;
        const float* pbp = PB + h * DK + kc * 16 + h8;
        bf16x8 qc, qp;
        #pragma unroll
        for (int e = 0; e < 8; ++e){
            float qf = (float)raw[e];
            qc[e] = (__bf16)((qf + cbp[e]) * LOG2E);
            qp[e] = (__bf16)((qf + pbp[e]) * LOG2E);
        }
        qcF[kc] = qc; qpF[kc] = qp;
    }

    // ---- rel tables via MFMA: C[fm][i] = Wsuf[fm] . qp[i]  (log2 domain) ----
    f32x16 rP = zero16(), rM = zero16();
    #pragma unroll
    for (int kc = 0; kc < 4; ++kc){
        bf16x8 aP = ldfrag(&WsPs[l31 * 72 + kc * 16 + h8]);
        bf16x8 aM = ldfrag(&WsMs[l31 * 72 + kc * 16 + h8]);
        rP = __builtin_amdgcn_mfma_f32_32x32x16_bf16(aP, qpF[kc], rP, 0, 0, 0);
        rM = __builtin_amdgcn_mfma_f32_32x32x16_bf16(aM, qpF[kc], rM, 0, 0, 0);
    }
    __syncthreads();   // all LDS reads (Qs, Wsuf) done before overwrites

    // fm==0 happens only at dd==0 (cw_1 > 0), so slot 0 stores the d==0
    // value (s1 only) and the slow path indexes by fm with NO select.
    #pragma unroll
    for (int r = 0; r < 16; ++r){
        int fm = (r & 3) + 8 * (r >> 2) + 4 * hbit;
        relP[i_loc * 34 + fm] = f2b(rP[r]);
        relM[i_loc * 34 + fm] = f2b(rM[r]);
    }
    if (hbit == 0)
        relP[i_loc * 34 + 0] = f2b((rP[0] + rM[0]) * 0.5f);  // d==0: s1
    STORE();           // K/V tile 0 into seg0 (Qs dead)
    __syncthreads();

    // ---- main K-loop ----
    float mrow = -1e30f, lacc = 0.f;
    f32x16 oacc0 = zero16(), oacc1 = zero16();

#define MFMA32(A, B, C) __builtin_amdgcn_mfma_f32_32x32x16_bf16(A, B, C, 0, 0, 0)

#define PACK8(ST, WD) { \
    _Pragma("unroll") \
    for (int q_ = 0; q_ < 8; ++q_){ \
        float pa_ = EXP2(ST[2 * q_]     - bias); \
        float pc_ = EXP2(ST[2 * q_ + 1] - bias); \
        lsum += pa_ + pc_; \
        WD[q_] = (unsigned int)f2b(pa_) | ((unsigned int)f2b(pc_) << 16); \
    } }

    // halved-shuffle fragment build: send (hbit ? a : b), receive the
    // other half's counterpart; 2 shuffles per fragment instead of 4.
#define MKFRAG(DST, WD, ZZ) { \
    unsigned int a0_ = WD[(ZZ) * 4 + 0], a1_ = WD[(ZZ) * 4 + 1]; \
    unsigned int b0_ = WD[(ZZ) * 4 + 2], b1_ = WD[(ZZ) * 4 + 3]; \
    unsigned int sh0_ = (unsigned int)__shfl_xor((int)(hbit ? a0_ : b0_), 32); \
    unsigned int sh1_ = (unsigned int)__shfl_xor((int)(hbit ? a1_ : b1_), 32); \
    u32x4 fw_; \
    fw_[0] = hbit ? sh0_ : a0_; \
    fw_[1] = hbit ? sh1_ : a1_; \
    fw_[2] = hbit ? b0_  : sh0_; \
    fw_[3] = hbit ? b1_  : sh1_; \
    DST = __builtin_bit_cast(bf16x8, fw_); }

#define PVSTEP(PF, COL) { \
    oacc0 = MFMA32(PF, ldfrag(&Vts[(l31)      * 72 + (COL) + h8]), oacc0); \
    oacc1 = MFMA32(PF, ldfrag(&Vts[(32 + l31) * 72 + (COL) + h8]), oacc1); }

    const u16* relP_i = relP + i_loc * 34;
    const u16* relM_i = relM + i_loc * 34;

    for (int kt = 0; kt < NT; ++kt){
        int j0 = jbase + kt * 64;
        if (kt + 1 < NT) LOAD(j0 + 64);

        // S^T = K . Q^T : st0 = rows j 0..31, st1 = rows j 32..63; col i = lane&31
        f32x16 st0 = zero16(), st1 = zero16();
        __builtin_amdgcn_s_setprio(1);
        #pragma unroll
        for (int kc = 0; kc < 4; ++kc){
            bf16x8 k0 = ldfrag(&Ks[(l31)      * 72 + kc * 16 + h8]);
            bf16x8 k1 = ldfrag(&Ks[(32 + l31) * 72 + kc * 16 + h8]);
            st0 = MFMA32(k0, qcF[kc], st0);
            st1 = MFMA32(k1, qcF[kc], st1);
        }
        __builtin_amdgcn_s_setprio(0);

        // rel merge: fast path keeps st raw and folds relv into the exp bias
        int D = j0 - i0;
        int Di = D - i_loc;
        float relv = 0.f;
        bool fast = false; int fmU = 0; const u16* tabU = relP_i;
        if (D >= 128){
            int fa = fmt[D - 127], fb = fmt[D + 63];
            fast = (fa == fb); fmU = fa; tabU = relP_i;
        } else if (D <= -64){
            int fa = fmt[-D - 63], fb = fmt[-D + 127];
            fast = (fa == fb); fmU = fa; tabU = relM_i;
        }
        if (fast){
            relv = b2f(tabU[fmU]);
        } else {
            #pragma unroll
            for (int r = 0; r < 16; ++r){
                const int jb = (r & 3) + 8 * (r >> 2);
                int jbh = jb + 4 * hbit;
                {
                    int dd = Di + jbh;
                    int ad = dd < 0 ? -dd : dd;
                    int fm = fmt[ad];
                    const u16* tab = (dd >= 0) ? relP_i : relM_i;
                    st0[r] += b2f(tab[fm]);
                }
                {
                    int dd = Di + 32 + jbh;
                    int ad = dd < 0 ? -dd : dd;
                    int fm = fmt[ad];
                    const u16* tab = (dd >= 0) ? relP_i : relM_i;
                    st1[r] += b2f(tab[fm]);
                }
            }
        }

        // row max (lane-local + one cross-half shuffle); relv added once
        float mx = st0[0];
        #pragma unroll
        for (int r = 1; r < 16; ++r) mx = fmaxf(mx, st0[r]);
        #pragma unroll
        for (int r = 0; r < 16; ++r) mx = fmaxf(mx, st1[r]);
        mx = fmaxf(mx, __shfl_xor(mx, 32)) + relv;

        // defer-max (log2 domain, THR = 11 ~ e^7.6)
        if (!__all(mx - mrow <= 11.0f)){
            float mnew = fmaxf(mrow, mx);
            float alpha = EXP2(mrow - mnew);
            mrow = mnew;
            lacc *= alpha;
            #pragma unroll
            for (int r = 0; r < 16; ++r){
                float ar = __shfl(alpha, (r & 3) + 8 * (r >> 2) + 4 * hbit);
                oacc0[r] *= ar; oacc1[r] *= ar;
            }
        }

        // P = exp2(st - bias), bias = mrow - relv; l from unrounded floats
        float bias = mrow - relv;
        float lsum = 0.f;
        unsigned int wds0[8], wds1[8];
        PACK8(st0, wds0)
        PACK8(st1, wds1)
        lacc += lsum + __shfl_xor(lsum, 32);

        // in-register transpose to PV A-fragments (rows i = lane&31)
        bf16x8 pf0, pf1, pf2, pf3;
        MKFRAG(pf0, wds0, 0)   // j  0..15
        MKFRAG(pf1, wds0, 1)   // j 16..31
        MKFRAG(pf2, wds1, 0)   // j 32..47
        MKFRAG(pf3, wds1, 1)   // j 48..63
        __builtin_amdgcn_s_setprio(1);
        PVSTEP(pf0,  0)
        PVSTEP(pf1, 16)
        PVSTEP(pf2, 32)
        PVSTEP(pf3, 48)
        __builtin_amdgcn_s_setprio(0);

        __syncthreads();
        if (kt + 1 < NT) STORE();
        __syncthreads();
    }

    // ---- write partials ----
    size_t pb = ((size_t)half * 128 + bid) * 128;
    #pragma unroll
    for (int r = 0; r < 16; ++r){
        int iO = w * 32 + (r & 3) + 8 * (r >> 2) + 4 * hbit;
        OpU[(pb + iO) * 64 + l31]      = f2b(oacc0[r]);
        OpU[(pb + iO) * 64 + 32 + l31] = f2b(oacc1[r]);
    }
    if (hbit == 0){
        mpart[pb + i_loc] = mrow;
        lpart[pb + i_loc] = lacc;
    }
#undef MFMA32
#undef PACK8
#undef MKFRAG
#undef PVSTEP
}

// ---------------------------------------------------------------------------
// Combine 8 K-eighths -> normalized bf16 Oatt (512 blocks).
// ---------------------------------------------------------------------------
__global__ __launch_bounds__(256) void combine_kernel(const u16* __restrict__ OpU,
    const float* __restrict__ mpart, const float* __restrict__ lpart,
    u16* __restrict__ Oatt){
    int h = blockIdx.y;
    int t = threadIdx.x;
    int r = t >> 3, cb = (t & 7) * 8;
    int i = blockIdx.x * 32 + r;
    int bid = (i >> 7) * NH + h;
    int ri = i & 127;
    size_t pr[8];
    float ms[8], ls[8];
    float m = -1e30f;
    #pragma unroll
    for (int s = 0; s < 8; ++s){
        pr[s] = ((size_t)s * 128 + bid) * 128 + ri;
        ms[s] = mpart[pr[s]];
        ls[s] = lpart[pr[s]];
        m = fmaxf(m, ms[s]);
    }
    float den = 0.f, wgt[8];
    #pragma unroll
    for (int s = 0; s < 8; ++s){ wgt[s] = EXP2(ms[s] - m); den += wgt[s] * ls[s]; }
    float inv = 1.0f / fmaxf(den, 1e-30f);
    float o[8];
    #pragma unroll
    for (int e = 0; e < 8; ++e) o[e] = 0.f;
    #pragma unroll
    for (int s = 0; s < 8; ++s){
        u16x8 a = *(const u16x8*)&OpU[pr[s] * 64 + cb];
        #pragma unroll
        for (int e = 0; e < 8; ++e) o[e] += wgt[s] * b2f(a[e]);
    }
    u16x8 rv;
    #pragma unroll
    for (int e = 0; e < 8; ++e) rv[e] = f2b(o[e] * inv);
    *(u16x8*)&Oatt[(size_t)i * HD + h * DK + cb] = rv;
}

// ---------------------------------------------------------------------------
// Output projection (bf16 WoT path): out = Oattn @ Wo + bo.
// ---------------------------------------------------------------------------
__global__ __launch_bounds__(256) void oproj_kernel(const u16* __restrict__ A,
    const u16* __restrict__ WoT, const float* __restrict__ bo,
    float* __restrict__ out, int m_base){
    __shared__ __align__(16) u16 xs[64 * 72];
    __shared__ __align__(16) u16 bs[64 * 72];
    int m0 = m_base + blockIdx.y * 64;
    int n0 = blockIdx.x * 64;
    int t = threadIdx.x;
    int w = t >> 6, lane = t & 63, qd = lane >> 4, l15 = lane & 15;
    f32x4 acc[4] = {{0,0,0,0},{0,0,0,0},{0,0,0,0},{0,0,0,0}};
    for (int k0 = 0; k0 < HD; k0 += 64){
        #pragma unroll
        for (int rep = 0; rep < 2; ++rep){
            int vid = rep * 256 + t;
            int r  = vid >> 3;
            int cv = (vid & 7) * 8;
            *(u16x8*)&xs[r * 72 + cv] = *(const u16x8*)&A[(size_t)(m0 + r) * HD + k0 + cv];
            *(u16x8*)&bs[r * 72 + cv] = *(const u16x8*)&WoT[(size_t)(n0 + r) * HD + k0 + cv];
        }
        __syncthreads();
        bf16x8 a0 = ldfrag(&xs[(w * 16 + l15) * 72 +  0 + qd * 8]);
        bf16x8 a1 = ldfrag(&xs[(w * 16 + l15) * 72 + 32 + qd * 8]);
        #pragma unroll
        for (int nt = 0; nt < 4; ++nt){
            bf16x8 b0 = ldfrag(&bs[(nt * 16 + l15) * 72 +  0 + qd * 8]);
            bf16x8 b1 = ldfrag(&bs[(nt * 16 + l15) * 72 + 32 + qd * 8]);
            acc[nt] = __builtin_amdgcn_mfma_f32_16x16x32_bf16(a0, b0, acc[nt], 0, 0, 0);
            acc[nt] = __builtin_amdgcn_mfma_f32_16x16x32_bf16(a1, b1, acc[nt], 0, 0, 0);
        }
        __syncthreads();
    }
    #pragma unroll
    for (int nt = 0; nt < 4; ++nt)
        #pragma unroll
        for (int reg = 0; reg < 4; ++reg){
            int row = m0 + w * 16 + qd * 4 + reg;
            int col = n0 + nt * 16 + l15;
            out[(size_t)row * DIMM + col] = acc[nt][reg] + bo[col];
        }
}

// ---------------------------------------------------------------------------
// Output projection (fp32 Wo fallback).
// ---------------------------------------------------------------------------
__global__ __launch_bounds__(256) void oproj_f32_kernel(const u16* __restrict__ A,
    const float* __restrict__ Wo, const float* __restrict__ bo,
    float* __restrict__ out, int m_base){
    __shared__ __align__(16) u16 xs[64 * 72];
    __shared__ __align__(16) u16 bs[64 * 72];
    int m0 = m_base + blockIdx.y * 64;
    int n0 = blockIdx.x * 64;
    int t = threadIdx.x;
    int w = t >> 6, lane = t & 63, qd = lane >> 4, l15 = lane & 15;
    f32x4 acc[4] = {{0,0,0,0},{0,0,0,0},{0,0,0,0},{0,0,0,0}};
    for (int k0 = 0; k0 < HD; k0 += 64){
        #pragma unroll
        for (int rep = 0; rep < 2; ++rep){
            int vid = rep * 256 + t;
            int r  = vid >> 3;
            int cv = (vid & 7) * 8;
            *(u16x8*)&xs[r * 72 + cv] = *(const u16x8*)&A[(size_t)(m0 + r) * HD + k0 + cv];
            size_t wi = (size_t)(k0 + r) * DIMM + n0 + cv;
            f32x4 wa = *(const f32x4*)(Wo + wi), wb = *(const f32x4*)(Wo + wi + 4);
            u16x8 wv;
            #pragma unroll
            for (int e = 0; e < 4; ++e){ wv[e] = f2b(wa[e]); wv[4 + e] = f2b(wb[e]); }
            #pragma unroll
            for (int e = 0; e < 8; ++e) bs[(cv + e) * 72 + r] = wv[e];
        }
        __syncthreads();
        bf16x8 a0 = ldfrag(&xs[(w * 16 + l15) * 72 +  0 + qd * 8]);
        bf16x8 a1 = ldfrag(&xs[(w * 16 + l15) * 72 + 32 + qd * 8]);
        #pragma unroll
        for (int nt = 0; nt < 4; ++nt){
            bf16x8 b0 = ldfrag(&bs[(nt * 16 + l15) * 72 +  0 + qd * 8]);
            bf16x8 b1 = ldfrag(&bs[(nt * 16 + l15) * 72 + 32 + qd * 8]);
            acc[nt] = __builtin_amdgcn_mfma_f32_16x16x32_bf16(a0, b0, acc[nt], 0, 0, 0);
            acc[nt] = __builtin_amdgcn_mfma_f32_16x16x32_bf16(a1, b1, acc[nt], 0, 0, 0);
        }
        __syncthreads();
    }
    #pragma unroll
    for (int nt = 0; nt < 4; ++nt)
        #pragma unroll
        for (int reg = 0; reg < 4; ++reg){
            int row = m0 + w * 16 + qd * 4 + reg;
            int col = n0 + nt * 16 + l15;
            out[(size_t)row * DIMM + col] = acc[nt][reg] + bo[col];
        }
}

extern "C" void kernel_launch(void* const* d_in, const int* in_sizes, int n_in,
                              void* d_out, int out_size, void* d_ws, size_t ws_size,
                              hipStream_t stream){
    const float* X  = (const float*)d_in[0];
    const float* Wq = (const float*)d_in[1];
    const float* Wk = (const float*)d_in[2];
    const float* Wv = (const float*)d_in[3];
    const float* Wr = (const float*)d_in[4];
    const float* Wo = (const float*)d_in[5];
    const float* bo = (const float*)d_in[6];
    const float* CB = (const float*)d_in[7];
    const float* PB = (const float*)d_in[8];
    float* out = (float*)d_out;
    u16* base = (u16*)d_out;   // 12,582,912 u16 slots

    // d_out scratch (u16 offsets): Qb[0,1048576) Kb[1048576,2097152)
    // Vt[2097152,3145728) Wt[3145728,4325376) (dead after qkv; OpU overlays)
    // OpU[3145728,11534336) mpart/lpart f32 after.
    u16* Qb   = base;
    u16* Kb   = base + 1048576;
    u16* Vt   = base + 2097152;
    u16* Wt   = base + 3145728;
    u16* OpU  = base + 3145728;
    float* mpart = out + 5767168;
    float* lpart = out + 5898240;

    // d_ws layout: fmt[0,4096) WsP[4096,20480) WsM[20480,36864)
    //   WoT u16 @36864 (786,432 B) -> 823,296
    //   Oatt u16 @823,296 (2,097,152 B) -> 2,920,448
    unsigned char* fmtg = (unsigned char*)d_ws;
    u16* WsP = (u16*)((char*)d_ws + 4096);
    u16* WsM = (u16*)((char*)d_ws + 20480);
    u16* WoT = (u16*)((char*)d_ws + 36864);
    bool ws_ok = ws_size >= 2920448;

    prep_kernel<<<dim3(ws_ok ? 401 : 305), 256, 0, stream>>>(
        Wq, Wk, Wv, Wt, fmtg, Wr, WsP, WsM, Wo, WoT);
    qkv_kernel<<<dim3(1536), 256, 0, stream>>>(X, Wt, Qb, Kb, Vt);
    attn_kernel<<<dim3(32, NH, KSPLIT), 256, 0, stream>>>(Qb, Kb, Vt, WsP, WsM,
                                                          fmtg, CB, PB,
                                                          OpU, mpart, lpart);

    if (ws_ok){
        u16* Oatt = (u16*)((char*)d_ws + 823296);
        combine_kernel<<<dim3(128, NH), 256, 0, stream>>>(OpU, mpart, lpart, Oatt);
        oproj_kernel<<<dim3(24, 64), 256, 0, stream>>>(Oatt, WoT, bo, out, 0);
    } else {
        // fallback: Oatt in d_out (overlays dead Qb) with descending-row
        // 3-split fp32-Wo oproj for WAR safety.
        u16* Oatt = base;
        combine_kernel<<<dim3(128, NH), 256, 0, stream>>>(OpU, mpart, lpart, Oatt);
        oproj_f32_kernel<<<dim3(24, 58), 256, 0, stream>>>(Oatt, Wo, bo, out, 384);
        oproj_f32_kernel<<<dim3(24,  5), 256, 0, stream>>>(Oatt, Wo, bo, out, 64);
        oproj_f32_kernel<<<dim3(24,  1), 256, 0, stream>>>(Oatt, Wo, bo, out, 0);
    }
}

// Round 14
// 196.934 us; speedup vs baseline: 2.2029x; 1.0055x over previous
//
#include <hip/hip_runtime.h>
#include <hip/hip_bf16.h>

#define N_SEQ 4096
#define DIMM  1536
#define NH    4
#define DK    64
#define HD    256     // NH*DK
#define QK_SCALE 0.125f
#define WSZ   393216  // 1536*256 per weight
#define KSPLIT 8
#define LOG2E 1.44269504f

typedef __bf16 bf16x8 __attribute__((ext_vector_type(8)));
typedef unsigned short u16;
typedef unsigned int u32;
typedef u16   u16x8  __attribute__((ext_vector_type(8)));
typedef u16   u16x4  __attribute__((ext_vector_type(4)));
typedef float f32x4  __attribute__((ext_vector_type(4)));
typedef float f32x16 __attribute__((ext_vector_type(16)));
typedef unsigned int u32x4 __attribute__((ext_vector_type(4)));

__device__ inline float b2f(u16 u){
    union { float f; unsigned int i; } v; v.i = ((unsigned int)u) << 16; return v.f;
}
__device__ inline u16 f2b(float f){
    __bf16 h = (__bf16)f;               // native cvt, RNE
    return __builtin_bit_cast(u16, h);
}
__device__ inline bf16x8 ldfrag(const u16* p){
    return __builtin_bit_cast(bf16x8, *(const u16x8*)p);
}
__device__ inline f32x16 zero16(){
    f32x16 v;
    #pragma unroll
    for (int i = 0; i < 16; ++i) v[i] = 0.f;
    return v;
}
#define EXP2(x) exp2f(x)   // lowers to a single v_exp_f32 on gfx950

// ---------------------------------------------------------------------------
// Prep (one launch): [0,288) Wq|Wk|Wv fp32 -> bf16 Wt[n][k] transpose;
// [288,304) fmtab; 304 suffix-summed rel weights; [305,401) Wo fp32 ->
// bf16 WoT[n][k] transpose (only launched when workspace fits).
// ---------------------------------------------------------------------------
__global__ __launch_bounds__(256) void prep_kernel(const float* __restrict__ Wq,
    const float* __restrict__ Wk, const float* __restrict__ Wv, u16* __restrict__ Wt,
    unsigned char* __restrict__ fmt, const float* __restrict__ Wrel,
    u16* __restrict__ WsP, u16* __restrict__ WsM,
    const float* __restrict__ Wo, u16* __restrict__ WoT){
    int bid = blockIdx.x;
    int t = threadIdx.x;
    if (bid < 288){
        __shared__ float T[64 * 65];
        int s = bid / 96, tile = bid % 96;
        int n0 = (tile / 24) * 64;
        int k0 = (tile % 24) * 64;
        const float* W = (s == 0) ? Wq : (s == 1 ? Wk : Wv);
        int rA = t >> 3, c8 = (t & 7) * 8;
        #pragma unroll
        for (int rep = 0; rep < 2; ++rep){
            int rr = rep * 32 + rA;
            const float* p = W + (size_t)(k0 + rr) * HD + n0 + c8;
            f32x4 a = *(const f32x4*)p, b = *(const f32x4*)(p + 4);
            #pragma unroll
            for (int e = 0; e < 4; ++e){
                T[rr * 65 + c8 + e]     = a[e];
                T[rr * 65 + c8 + 4 + e] = b[e];
            }
        }
        __syncthreads();
        #pragma unroll
        for (int rep = 0; rep < 2; ++rep){
            int rn = rep * 32 + rA;
            u16x8 o;
            #pragma unroll
            for (int e = 0; e < 8; ++e) o[e] = f2b(T[(c8 + e) * 65 + rn]);
            *(u16x8*)&Wt[(size_t)s * WSZ + (size_t)(n0 + rn) * DIMM + k0 + c8] = o;
        }
        return;
    }
    if (bid >= 305){
        // Wo [256][1536] fp32 -> WoT [1536][256] bf16
        __shared__ float T[64 * 65];
        int tile = bid - 305;             // 0..95
        int n0 = (tile / 4) * 64;         // 24 n-tiles
        int k0 = (tile % 4) * 64;         // 4 k-tiles
        int rA = t >> 3, c8 = (t & 7) * 8;
        #pragma unroll
        for (int rep = 0; rep < 2; ++rep){
            int rr = rep * 32 + rA;
            const float* p = Wo + (size_t)(k0 + rr) * DIMM + n0 + c8;
            f32x4 a = *(const f32x4*)p, b = *(const f32x4*)(p + 4);
            #pragma unroll
            for (int e = 0; e < 4; ++e){
                T[rr * 65 + c8 + e]     = a[e];
                T[rr * 65 + c8 + 4 + e] = b[e];
            }
        }
        __syncthreads();
        #pragma unroll
        for (int rep = 0; rep < 2; ++rep){
            int rn = rep * 32 + rA;
            u16x8 o;
            #pragma unroll
            for (int e = 0; e < 8; ++e) o[e] = f2b(T[(c8 + e) * 65 + rn]);
            *(u16x8*)&WoT[(size_t)(n0 + rn) * HD + k0 + c8] = o;
        }
        return;
    }
    if (bid == 304){
        int h = t >> 6, d = t & 63;
        float w1[32], w2[32];
        #pragma unroll
        for (int fm = 0; fm < 32; ++fm){
            w1[fm] = Wrel[(size_t)fm * HD + h * DK + d];
            w2[fm] = Wrel[(size_t)(32 + fm) * HD + h * DK + d];
        }
        float a1 = 0.f, a2 = 0.f;
        #pragma unroll
        for (int fm = 31; fm >= 0; --fm){
            a1 += w1[fm];
            a2 += w2[fm];
            WsP[(h * 32 + fm) * 64 + d] = f2b(a1 + a2);
            WsM[(h * 32 + fm) * 64 + d] = f2b(a1 - a2);
        }
        return;
    }
    int d = (bid - 288) * 256 + t;
    float lg = logf((float)(N_SEQ + 1)) * (1.0f / 32.0f);
    float ad = (float)d;
    int fm = 0;
    for (int f = 0; f < 32; ++f){
        float cw = expf(lg * (float)(f + 1)) - 1.0f;
        fm += (cw <= ad) ? 1 : 0;
    }
    fmt[d] = (unsigned char)fm;
}

// ---------------------------------------------------------------------------
// QKV projection v5: BK=128 (12 iterations, half the barriers) + chunked XCD
// swizzle. LDS 26 KB -> 6 blocks/CU. Per iter/thread: X 1x16 fp32, W 2x16
// bf16, all 16B-vector ops.
// ---------------------------------------------------------------------------
__global__ __launch_bounds__(256) void qkv_kernel(const float* __restrict__ X,
    const u16* __restrict__ Wt,
    u16* __restrict__ Q, u16* __restrict__ K, u16* __restrict__ Vt){
    __shared__ __align__(16) u16 xs[32 * 136];
    __shared__ __align__(16) u16 bs[64 * 136];
    int lid = blockIdx.x;                 // 0..1535
    int xcd = lid & 7, loc = lid >> 3;
    int sw  = xcd * 192 + loc;            // chunked work id
    int mg  = sw / 12, inner = sw % 12;
    int s  = inner >> 2;                  // 0:Q 1:K 2:V
    int n0 = (inner & 3) * 64;
    int m0 = mg * 32;
    int t = threadIdx.x;
    int w = t >> 6, lane = t & 63, qd = lane >> 4, l15 = lane & 15;
    int wr = w & 1, wc = w >> 1;
    int r  = t >> 3;                      // 0..31
    int cv = (t & 7) * 16;                // 16-wide column chunk
    f32x4 acc[2] = {{0,0,0,0},{0,0,0,0}};

    f32x4 xa[4];
    u16x8 wv[4];
    auto LOAD = [&](int k0){
        size_t xi = (size_t)(m0 + r) * DIMM + k0 + cv;
        #pragma unroll
        for (int e = 0; e < 4; ++e) xa[e] = *(const f32x4*)(X + xi + e * 4);
        #pragma unroll
        for (int rep = 0; rep < 2; ++rep){
            int rr = rep * 32 + r;
            const u16* wp = &Wt[(size_t)s * WSZ + (size_t)(n0 + rr) * DIMM + k0 + cv];
            wv[rep * 2]     = *(const u16x8*)wp;
            wv[rep * 2 + 1] = *(const u16x8*)(wp + 8);
        }
    };
    auto STORE = [&](){
        u16x8 xv0, xv1;
        #pragma unroll
        for (int e = 0; e < 4; ++e){
            xv0[e] = f2b(xa[0][e]); xv0[4 + e] = f2b(xa[1][e]);
            xv1[e] = f2b(xa[2][e]); xv1[4 + e] = f2b(xa[3][e]);
        }
        *(u16x8*)&xs[r * 136 + cv]     = xv0;
        *(u16x8*)&xs[r * 136 + cv + 8] = xv1;
        #pragma unroll
        for (int rep = 0; rep < 2; ++rep){
            int rr = rep * 32 + r;
            *(u16x8*)&bs[rr * 136 + cv]     = wv[rep * 2];
            *(u16x8*)&bs[rr * 136 + cv + 8] = wv[rep * 2 + 1];
        }
    };

    LOAD(0);
    for (int k0 = 0; k0 < DIMM; k0 += 128){
        STORE();
        __syncthreads();
        if (k0 + 128 < DIMM) LOAD(k0 + 128);
        #pragma unroll
        for (int kc = 0; kc < 4; ++kc){
            bf16x8 a = ldfrag(&xs[(wr * 16 + l15) * 136 + kc * 32 + qd * 8]);
            #pragma unroll
            for (int nt = 0; nt < 2; ++nt){
                int nb = wc * 32 + nt * 16;
                bf16x8 b = ldfrag(&bs[(nb + l15) * 136 + kc * 32 + qd * 8]);
                acc[nt] = __builtin_amdgcn_mfma_f32_16x16x32_bf16(a, b, acc[nt], 0, 0, 0);
            }
        }
        __syncthreads();
    }

    int row0 = m0 + wr * 16 + qd * 4;
    if (s == 0){
        #pragma unroll
        for (int nt = 0; nt < 2; ++nt){
            int col = n0 + wc * 32 + nt * 16 + l15;
            #pragma unroll
            for (int reg = 0; reg < 4; ++reg)
                Q[(size_t)(row0 + reg) * HD + col] = f2b(acc[nt][reg] * QK_SCALE);
        }
    } else if (s == 1){
        #pragma unroll
        for (int nt = 0; nt < 2; ++nt){
            int col = n0 + wc * 32 + nt * 16 + l15;
            #pragma unroll
            for (int reg = 0; reg < 4; ++reg)
                K[(size_t)(row0 + reg) * HD + col] = f2b(acc[nt][reg]);
        }
    } else {
        #pragma unroll
        for (int nt = 0; nt < 2; ++nt){
            int col = n0 + wc * 32 + nt * 16 + l15;
            u16x4 pv;
            #pragma unroll
            for (int reg = 0; reg < 4; ++reg) pv[reg] = f2b(acc[nt][reg]);
            *(u16x4*)&Vt[(size_t)col * N_SEQ + row0] = pv;
        }
    }
}

// ---------------------------------------------------------------------------
// Flash attention — R5-proven kernel, byte-identical (68.5 µs measured).
// ---------------------------------------------------------------------------
__global__ __launch_bounds__(256) void attn_kernel(const u16* __restrict__ Q,
    const u16* __restrict__ Kg, const u16* __restrict__ Vt,
    const u16* __restrict__ WsPg, const u16* __restrict__ WsMg,
    const unsigned char* __restrict__ fmtg,
    const float* __restrict__ CB, const float* __restrict__ PB,
    u16* __restrict__ OpU, float* __restrict__ mpart, float* __restrict__ lpart){
    __shared__ __align__(16) unsigned char smem[39936];
    u16* Ks   = (u16*)(smem);             // [64][72]  main loop
    u16* Vts  = (u16*)(smem + 9216);      // [64][72]  main loop
    u16* Qs   = (u16*)(smem);             // init alias: [128][72]
    u16* relP = (u16*)(smem + 18432);     // [128][34] u16 (slot 0 = d==0 value)
    u16* relM = (u16*)(smem + 27136);     // [128][34] u16
    unsigned char* fmt = smem + 35840;    // 4096
    u16* WsPs = (u16*)(smem + 18432);     // init alias: [32][72]
    u16* WsMs = (u16*)(smem + 23040);

    int i0   = blockIdx.x * 128;
    int h    = blockIdx.y;
    int half = blockIdx.z;                // 0..7
    int bid  = blockIdx.x * NH + h;       // 0..127
    int jbase = half * (N_SEQ / KSPLIT);
    const int NT = (N_SEQ / KSPLIT) / 64; // 8 tiles
    int t = threadIdx.x;
    int w = t >> 6, lane = t & 63, l31 = lane & 31, hbit = lane >> 5;
    int h8 = hbit * 8;
    int i_loc = w * 32 + l31;             // this lane's softmax row (block-local)

    int sr = t >> 3, scv = (t & 7) * 8;
    u16x8 kr0, kr1, vr0, vr1;
    auto LOAD = [&](int j0){
        kr0 = *(const u16x8*)&Kg[(size_t)(j0 + sr)      * HD + h * DK + scv];
        kr1 = *(const u16x8*)&Kg[(size_t)(j0 + 32 + sr) * HD + h * DK + scv];
        vr0 = *(const u16x8*)&Vt[(size_t)(h * 64 + sr)      * N_SEQ + j0 + scv];
        vr1 = *(const u16x8*)&Vt[(size_t)(h * 64 + 32 + sr) * N_SEQ + j0 + scv];
    };
    auto STORE = [&](){
        *(u16x8*)&Ks [(sr)      * 72 + scv] = kr0;
        *(u16x8*)&Ks [(32 + sr) * 72 + scv] = kr1;
        *(u16x8*)&Vts[(sr)      * 72 + scv] = vr0;
        *(u16x8*)&Vts[(32 + sr) * 72 + scv] = vr1;
    };
    LOAD(jbase);

    // ---- init staging: Q rows (raw bf16), Wsuf slices, fmt ----
    #pragma unroll
    for (int rep = 0; rep < 4; ++rep){
        int vid = rep * 256 + t;
        int r  = vid >> 3;
        int cv = (vid & 7) * 8;
        *(u16x8*)&Qs[r * 72 + cv] = *(const u16x8*)&Q[(size_t)(i0 + r) * HD + h * DK + cv];
    }
    {
        int r = t >> 3, cv = (t & 7) * 8;
        *(u16x8*)&WsPs[r * 72 + cv] = *(const u16x8*)&WsPg[(h * 32 + r) * 64 + cv];
        *(u16x8*)&WsMs[r * 72 + cv] = *(const u16x8*)&WsMg[(h * 32 + r) * 64 + cv];
    }
    ((uint4*)fmt)[t] = ((const uint4*)fmtg)[t];
    __syncthreads();

    // ---- per-lane Q fragments (B-operand layout), bias + LOG2E folded ----
    bf16x8 qcF[4], qpF[4];
    #pragma unroll
    for (int kc = 0; kc < 4; ++kc){
        bf16x8 raw = ldfrag(&Qs[i_loc * 72 + kc * 16 + h8]);
        const float* cbp = CB + h * DK + kc * 16 + h8;
        const float* pbp = PB + h * DK + kc * 16 + h8;
        bf16x8 qc, qp;
        #pragma unroll
        for (int e = 0; e < 8; ++e){
            float qf = (float)raw[e];
            qc[e] = (__bf16)((qf + cbp[e]) * LOG2E);
            qp[e] = (__bf16)((qf + pbp[e]) * LOG2E);
        }
        qcF[kc] = qc; qpF[kc] = qp;
    }

    // ---- rel tables via MFMA: C[fm][i] = Wsuf[fm] . qp[i]  (log2 domain) ----
    f32x16 rP = zero16(), rM = zero16();
    #pragma unroll
    for (int kc = 0; kc < 4; ++kc){
        bf16x8 aP = ldfrag(&WsPs[l31 * 72 + kc * 16 + h8]);
        bf16x8 aM = ldfrag(&WsMs[l31 * 72 + kc * 16 + h8]);
        rP = __builtin_amdgcn_mfma_f32_32x32x16_bf16(aP, qpF[kc], rP, 0, 0, 0);
        rM = __builtin_amdgcn_mfma_f32_32x32x16_bf16(aM, qpF[kc], rM, 0, 0, 0);
    }
    __syncthreads();   // all LDS reads (Qs, Wsuf) done before overwrites

    // fm==0 happens only at dd==0 (cw_1 > 0), so slot 0 stores the d==0
    // value (s1 only) and the slow path indexes by fm with NO select.
    #pragma unroll
    for (int r = 0; r < 16; ++r){
        int fm = (r & 3) + 8 * (r >> 2) + 4 * hbit;
        relP[i_loc * 34 + fm] = f2b(rP[r]);
        relM[i_loc * 34 + fm] = f2b(rM[r]);
    }
    if (hbit == 0)
        relP[i_loc * 34 + 0] = f2b((rP[0] + rM[0]) * 0.5f);  // d==0: s1
    STORE();           // K/V tile 0 into seg0 (Qs dead)
    __syncthreads();

    // ---- main K-loop ----
    float mrow = -1e30f, lacc = 0.f;
    f32x16 oacc0 = zero16(), oacc1 = zero16();

#define MFMA32(A, B, C) __builtin_amdgcn_mfma_f32_32x32x16_bf16(A, B, C, 0, 0, 0)

#define PACK8(ST, WD) { \
    _Pragma("unroll") \
    for (int q_ = 0; q_ < 8; ++q_){ \
        float pa_ = EXP2(ST[2 * q_]     - bias); \
        float pc_ = EXP2(ST[2 * q_ + 1] - bias); \
        lsum += pa_ + pc_; \
        WD[q_] = (unsigned int)f2b(pa_) | ((unsigned int)f2b(pc_) << 16); \
    } }

    // halved-shuffle fragment build: send (hbit ? a : b), receive the
    // other half's counterpart; 2 shuffles per fragment instead of 4.
#define MKFRAG(DST, WD, ZZ) { \
    unsigned int a0_ = WD[(ZZ) * 4 + 0], a1_ = WD[(ZZ) * 4 + 1]; \
    unsigned int b0_ = WD[(ZZ) * 4 + 2], b1_ = WD[(ZZ) * 4 + 3]; \
    unsigned int sh0_ = (unsigned int)__shfl_xor((int)(hbit ? a0_ : b0_), 32); \
    unsigned int sh1_ = (unsigned int)__shfl_xor((int)(hbit ? a1_ : b1_), 32); \
    u32x4 fw_; \
    fw_[0] = hbit ? sh0_ : a0_; \
    fw_[1] = hbit ? sh1_ : a1_; \
    fw_[2] = hbit ? b0_  : sh0_; \
    fw_[3] = hbit ? b1_  : sh1_; \
    DST = __builtin_bit_cast(bf16x8, fw_); }

#define PVSTEP(PF, COL) { \
    oacc0 = MFMA32(PF, ldfrag(&Vts[(l31)      * 72 + (COL) + h8]), oacc0); \
    oacc1 = MFMA32(PF, ldfrag(&Vts[(32 + l31) * 72 + (COL) + h8]), oacc1); }

    const u16* relP_i = relP + i_loc * 34;
    const u16* relM_i = relM + i_loc * 34;

    for (int kt = 0; kt < NT; ++kt){
        int j0 = jbase + kt * 64;
        if (kt + 1 < NT) LOAD(j0 + 64);

        // S^T = K . Q^T : st0 = rows j 0..31, st1 = rows j 32..63; col i = lane&31
        f32x16 st0 = zero16(), st1 = zero16();
        __builtin_amdgcn_s_setprio(1);
        #pragma unroll
        for (int kc = 0; kc < 4; ++kc){
            bf16x8 k0 = ldfrag(&Ks[(l31)      * 72 + kc * 16 + h8]);
            bf16x8 k1 = ldfrag(&Ks[(32 + l31) * 72 + kc * 16 + h8]);
            st0 = MFMA32(k0, qcF[kc], st0);
            st1 = MFMA32(k1, qcF[kc], st1);
        }
        __builtin_amdgcn_s_setprio(0);

        // rel merge: fast path keeps st raw and folds relv into the exp bias
        int D = j0 - i0;
        int Di = D - i_loc;
        float relv = 0.f;
        bool fast = false; int fmU = 0; const u16* tabU = relP_i;
        if (D >= 128){
            int fa = fmt[D - 127], fb = fmt[D + 63];
            fast = (fa == fb); fmU = fa; tabU = relP_i;
        } else if (D <= -64){
            int fa = fmt[-D - 63], fb = fmt[-D + 127];
            fast = (fa == fb); fmU = fa; tabU = relM_i;
        }
        if (fast){
            relv = b2f(tabU[fmU]);
        } else {
            #pragma unroll
            for (int r = 0; r < 16; ++r){
                const int jb = (r & 3) + 8 * (r >> 2);
                int jbh = jb + 4 * hbit;
                {
                    int dd = Di + jbh;
                    int ad = dd < 0 ? -dd : dd;
                    int fm = fmt[ad];
                    const u16* tab = (dd >= 0) ? relP_i : relM_i;
                    st0[r] += b2f(tab[fm]);
                }
                {
                    int dd = Di + 32 + jbh;
                    int ad = dd < 0 ? -dd : dd;
                    int fm = fmt[ad];
                    const u16* tab = (dd >= 0) ? relP_i : relM_i;
                    st1[r] += b2f(tab[fm]);
                }
            }
        }

        // row max (lane-local + one cross-half shuffle); relv added once
        float mx = st0[0];
        #pragma unroll
        for (int r = 1; r < 16; ++r) mx = fmaxf(mx, st0[r]);
        #pragma unroll
        for (int r = 0; r < 16; ++r) mx = fmaxf(mx, st1[r]);
        mx = fmaxf(mx, __shfl_xor(mx, 32)) + relv;

        // defer-max (log2 domain, THR = 11 ~ e^7.6)
        if (!__all(mx - mrow <= 11.0f)){
            float mnew = fmaxf(mrow, mx);
            float alpha = EXP2(mrow - mnew);
            mrow = mnew;
            lacc *= alpha;
            #pragma unroll
            for (int r = 0; r < 16; ++r){
                float ar = __shfl(alpha, (r & 3) + 8 * (r >> 2) + 4 * hbit);
                oacc0[r] *= ar; oacc1[r] *= ar;
            }
        }

        // P = exp2(st - bias), bias = mrow - relv; l from unrounded floats
        float bias = mrow - relv;
        float lsum = 0.f;
        unsigned int wds0[8], wds1[8];
        PACK8(st0, wds0)
        PACK8(st1, wds1)
        lacc += lsum + __shfl_xor(lsum, 32);

        // in-register transpose to PV A-fragments (rows i = lane&31)
        bf16x8 pf0, pf1, pf2, pf3;
        MKFRAG(pf0, wds0, 0)   // j  0..15
        MKFRAG(pf1, wds0, 1)   // j 16..31
        MKFRAG(pf2, wds1, 0)   // j 32..47
        MKFRAG(pf3, wds1, 1)   // j 48..63
        __builtin_amdgcn_s_setprio(1);
        PVSTEP(pf0,  0)
        PVSTEP(pf1, 16)
        PVSTEP(pf2, 32)
        PVSTEP(pf3, 48)
        __builtin_amdgcn_s_setprio(0);

        __syncthreads();
        if (kt + 1 < NT) STORE();
        __syncthreads();
    }

    // ---- write partials ----
    size_t pb = ((size_t)half * 128 + bid) * 128;
    #pragma unroll
    for (int r = 0; r < 16; ++r){
        int iO = w * 32 + (r & 3) + 8 * (r >> 2) + 4 * hbit;
        OpU[(pb + iO) * 64 + l31]      = f2b(oacc0[r]);
        OpU[(pb + iO) * 64 + 32 + l31] = f2b(oacc1[r]);
    }
    if (hbit == 0){
        mpart[pb + i_loc] = mrow;
        lpart[pb + i_loc] = lacc;
    }
#undef MFMA32
#undef PACK8
#undef MKFRAG
#undef PVSTEP
}

// ---------------------------------------------------------------------------
// Combine 8 K-eighths -> normalized bf16 Oatt (512 blocks).
// ---------------------------------------------------------------------------
__global__ __launch_bounds__(256) void combine_kernel(const u16* __restrict__ OpU,
    const float* __restrict__ mpart, const float* __restrict__ lpart,
    u16* __restrict__ Oatt){
    int h = blockIdx.y;
    int t = threadIdx.x;
    int r = t >> 3, cb = (t & 7) * 8;
    int i = blockIdx.x * 32 + r;
    int bid = (i >> 7) * NH + h;
    int ri = i & 127;
    size_t pr[8];
    float ms[8], ls[8];
    float m = -1e30f;
    #pragma unroll
    for (int s = 0; s < 8; ++s){
        pr[s] = ((size_t)s * 128 + bid) * 128 + ri;
        ms[s] = mpart[pr[s]];
        ls[s] = lpart[pr[s]];
        m = fmaxf(m, ms[s]);
    }
    float den = 0.f, wgt[8];
    #pragma unroll
    for (int s = 0; s < 8; ++s){ wgt[s] = EXP2(ms[s] - m); den += wgt[s] * ls[s]; }
    float inv = 1.0f / fmaxf(den, 1e-30f);
    float o[8];
    #pragma unroll
    for (int e = 0; e < 8; ++e) o[e] = 0.f;
    #pragma unroll
    for (int s = 0; s < 8; ++s){
        u16x8 a = *(const u16x8*)&OpU[pr[s] * 64 + cb];
        #pragma unroll
        for (int e = 0; e < 8; ++e) o[e] += wgt[s] * b2f(a[e]);
    }
    u16x8 rv;
    #pragma unroll
    for (int e = 0; e < 8; ++e) rv[e] = f2b(o[e] * inv);
    *(u16x8*)&Oatt[(size_t)i * HD + h * DK + cb] = rv;
}

// ---------------------------------------------------------------------------
// Output projection (bf16 WoT path), BK=128: 2 iterations, LDS 34.8 KB
// (4 blocks/CU), all-vector staging.
// ---------------------------------------------------------------------------
__global__ __launch_bounds__(256) void oproj_kernel(const u16* __restrict__ A,
    const u16* __restrict__ WoT, const float* __restrict__ bo,
    float* __restrict__ out, int m_base){
    __shared__ __align__(16) u16 xs[64 * 136];
    __shared__ __align__(16) u16 bs[64 * 136];
    int m0 = m_base + blockIdx.y * 64;
    int n0 = blockIdx.x * 64;
    int t = threadIdx.x;
    int w = t >> 6, lane = t & 63, qd = lane >> 4, l15 = lane & 15;
    int r  = t >> 3;                      // 0..31
    int cv = (t & 7) * 16;
    f32x4 acc[4] = {{0,0,0,0},{0,0,0,0},{0,0,0,0},{0,0,0,0}};
    for (int k0 = 0; k0 < HD; k0 += 128){
        #pragma unroll
        for (int rep = 0; rep < 2; ++rep){
            int rr = rep * 32 + r;
            const u16* ap = &A[(size_t)(m0 + rr) * HD + k0 + cv];
            const u16* wp = &WoT[(size_t)(n0 + rr) * HD + k0 + cv];
            *(u16x8*)&xs[rr * 136 + cv]     = *(const u16x8*)ap;
            *(u16x8*)&xs[rr * 136 + cv + 8] = *(const u16x8*)(ap + 8);
            *(u16x8*)&bs[rr * 136 + cv]     = *(const u16x8*)wp;
            *(u16x8*)&bs[rr * 136 + cv + 8] = *(const u16x8*)(wp + 8);
        }
        __syncthreads();
        #pragma unroll
        for (int kc = 0; kc < 4; ++kc){
            bf16x8 a = ldfrag(&xs[(w * 16 + l15) * 136 + kc * 32 + qd * 8]);
            #pragma unroll
            for (int nt = 0; nt < 4; ++nt){
                bf16x8 b = ldfrag(&bs[(nt * 16 + l15) * 136 + kc * 32 + qd * 8]);
                acc[nt] = __builtin_amdgcn_mfma_f32_16x16x32_bf16(a, b, acc[nt], 0, 0, 0);
            }
        }
        __syncthreads();
    }
    #pragma unroll
    for (int nt = 0; nt < 4; ++nt)
        #pragma unroll
        for (int reg = 0; reg < 4; ++reg){
            int row = m0 + w * 16 + qd * 4 + reg;
            int col = n0 + nt * 16 + l15;
            out[(size_t)row * DIMM + col] = acc[nt][reg] + bo[col];
        }
}

// ---------------------------------------------------------------------------
// Output projection (fp32 Wo fallback, BK=64 — unchanged semantics).
// ---------------------------------------------------------------------------
__global__ __launch_bounds__(256) void oproj_f32_kernel(const u16* __restrict__ A,
    const float* __restrict__ Wo, const float* __restrict__ bo,
    float* __restrict__ out, int m_base){
    __shared__ __align__(16) u16 xs[64 * 72];
    __shared__ __align__(16) u16 bs[64 * 72];
    int m0 = m_base + blockIdx.y * 64;
    int n0 = blockIdx.x * 64;
    int t = threadIdx.x;
    int w = t >> 6, lane = t & 63, qd = lane >> 4, l15 = lane & 15;
    f32x4 acc[4] = {{0,0,0,0},{0,0,0,0},{0,0,0,0},{0,0,0,0}};
    for (int k0 = 0; k0 < HD; k0 += 64){
        #pragma unroll
        for (int rep = 0; rep < 2; ++rep){
            int vid = rep * 256 + t;
            int r  = vid >> 3;
            int cv = (vid & 7) * 8;
            *(u16x8*)&xs[r * 72 + cv] = *(const u16x8*)&A[(size_t)(m0 + r) * HD + k0 + cv];
            size_t wi = (size_t)(k0 + r) * DIMM + n0 + cv;
            f32x4 wa = *(const f32x4*)(Wo + wi), wb = *(const f32x4*)(Wo + wi + 4);
            u16x8 wv;
            #pragma unroll
            for (int e = 0; e < 4; ++e){ wv[e] = f2b(wa[e]); wv[4 + e] = f2b(wb[e]); }
            #pragma unroll
            for (int e = 0; e < 8; ++e) bs[(cv + e) * 72 + r] = wv[e];
        }
        __syncthreads();
        bf16x8 a0 = ldfrag(&xs[(w * 16 + l15) * 72 +  0 + qd * 8]);
        bf16x8 a1 = ldfrag(&xs[(w * 16 + l15) * 72 + 32 + qd * 8]);
        #pragma unroll
        for (int nt = 0; nt < 4; ++nt){
            bf16x8 b0 = ldfrag(&bs[(nt * 16 + l15) * 72 +  0 + qd * 8]);
            bf16x8 b1 = ldfrag(&bs[(nt * 16 + l15) * 72 + 32 + qd * 8]);
            acc[nt] = __builtin_amdgcn_mfma_f32_16x16x32_bf16(a0, b0, acc[nt], 0, 0, 0);
            acc[nt] = __builtin_amdgcn_mfma_f32_16x16x32_bf16(a1, b1, acc[nt], 0, 0, 0);
        }
        __syncthreads();
    }
    #pragma unroll
    for (int nt = 0; nt < 4; ++nt)
        #pragma unroll
        for (int reg = 0; reg < 4; ++reg){
            int row = m0 + w * 16 + qd * 4 + reg;
            int col = n0 + nt * 16 + l15;
            out[(size_t)row * DIMM + col] = acc[nt][reg] + bo[col];
        }
}

extern "C" void kernel_launch(void* const* d_in, const int* in_sizes, int n_in,
                              void* d_out, int out_size, void* d_ws, size_t ws_size,
                              hipStream_t stream){
    const float* X  = (const float*)d_in[0];
    const float* Wq = (const float*)d_in[1];
    const float* Wk = (const float*)d_in[2];
    const float* Wv = (const float*)d_in[3];
    const float* Wr = (const float*)d_in[4];
    const float* Wo = (const float*)d_in[5];
    const float* bo = (const float*)d_in[6];
    const float* CB = (const float*)d_in[7];
    const float* PB = (const float*)d_in[8];
    float* out = (float*)d_out;
    u16* base = (u16*)d_out;   // 12,582,912 u16 slots

    // d_out scratch (u16 offsets): Qb[0,1048576) Kb[1048576,2097152)
    // Vt[2097152,3145728) Wt[3145728,4325376) (dead after qkv; OpU overlays)
    // OpU[3145728,11534336) mpart/lpart f32 after.
    u16* Qb   = base;
    u16* Kb   = base + 1048576;
    u16* Vt   = base + 2097152;
    u16* Wt   = base + 3145728;
    u16* OpU  = base + 3145728;
    float* mpart = out + 5767168;
    float* lpart = out + 5898240;

    // d_ws layout: fmt[0,4096) WsP[4096,20480) WsM[20480,36864)
    //   WoT u16 @36864 (786,432 B) -> 823,296
    //   Oatt u16 @823,296 (2,097,152 B) -> 2,920,448
    unsigned char* fmtg = (unsigned char*)d_ws;
    u16* WsP = (u16*)((char*)d_ws + 4096);
    u16* WsM = (u16*)((char*)d_ws + 20480);
    u16* WoT = (u16*)((char*)d_ws + 36864);
    bool ws_ok = ws_size >= 2920448;

    prep_kernel<<<dim3(ws_ok ? 401 : 305), 256, 0, stream>>>(
        Wq, Wk, Wv, Wt, fmtg, Wr, WsP, WsM, Wo, WoT);
    qkv_kernel<<<dim3(1536), 256, 0, stream>>>(X, Wt, Qb, Kb, Vt);
    attn_kernel<<<dim3(32, NH, KSPLIT), 256, 0, stream>>>(Qb, Kb, Vt, WsP, WsM,
                                                          fmtg, CB, PB,
                                                          OpU, mpart, lpart);

    if (ws_ok){
        u16* Oatt = (u16*)((char*)d_ws + 823296);
        combine_kernel<<<dim3(128, NH), 256, 0, stream>>>(OpU, mpart, lpart, Oatt);
        oproj_kernel<<<dim3(24, 64), 256, 0, stream>>>(Oatt, WoT, bo, out, 0);
    } else {
        // fallback: Oatt in d_out (overlays dead Qb) with descending-row
        // 3-split fp32-Wo oproj for WAR safety.
        u16* Oatt = base;
        combine_kernel<<<dim3(128, NH), 256, 0, stream>>>(OpU, mpart, lpart, Oatt);
        oproj_f32_kernel<<<dim3(24, 58), 256, 0, stream>>>(Oatt, Wo, bo, out, 384);
        oproj_f32_kernel<<<dim3(24,  5), 256, 0, stream>>>(Oatt, Wo, bo, out, 64);
        oproj_f32_kernel<<<dim3(24,  1), 256, 0, stream>>>(Oatt, Wo, bo, out, 0);
    }
}

// Round 15
// 194.363 us; speedup vs baseline: 2.2320x; 1.0132x over previous
//
#include <hip/hip_runtime.h>
#include <hip/hip_bf16.h>

#define N_SEQ 4096
#define DIMM  1536
#define NH    4
#define DK    64
#define HD    256     // NH*DK
#define QK_SCALE 0.125f
#define WSZ   393216  // 1536*256 per weight
#define KSPLIT 8
#define LOG2E 1.44269504f

typedef __bf16 bf16x8 __attribute__((ext_vector_type(8)));
typedef unsigned short u16;
typedef unsigned int u32;
typedef u16   u16x8  __attribute__((ext_vector_type(8)));
typedef u16   u16x4  __attribute__((ext_vector_type(4)));
typedef float f32x4  __attribute__((ext_vector_type(4)));
typedef float f32x16 __attribute__((ext_vector_type(16)));
typedef unsigned int u32x4 __attribute__((ext_vector_type(4)));

__device__ inline float b2f(u16 u){
    union { float f; unsigned int i; } v; v.i = ((unsigned int)u) << 16; return v.f;
}
__device__ inline u16 f2b(float f){
    __bf16 h = (__bf16)f;               // native cvt, RNE
    return __builtin_bit_cast(u16, h);
}
__device__ inline bf16x8 ldfrag(const u16* p){
    return __builtin_bit_cast(bf16x8, *(const u16x8*)p);
}
__device__ inline f32x16 zero16(){
    f32x16 v;
    #pragma unroll
    for (int i = 0; i < 16; ++i) v[i] = 0.f;
    return v;
}
#define EXP2(x) exp2f(x)   // lowers to a single v_exp_f32 on gfx950

// ---------------------------------------------------------------------------
// Prep (one launch): [0,288) Wq|Wk|Wv fp32 -> bf16 Wt[n][k] transpose;
// [288,304) fmtab; 304 suffix-summed rel weights; [305,401) Wo fp32 ->
// bf16 WoT[n][k] transpose (only launched when workspace fits).
// ---------------------------------------------------------------------------
__global__ __launch_bounds__(256) void prep_kernel(const float* __restrict__ Wq,
    const float* __restrict__ Wk, const float* __restrict__ Wv, u16* __restrict__ Wt,
    unsigned char* __restrict__ fmt, const float* __restrict__ Wrel,
    u16* __restrict__ WsP, u16* __restrict__ WsM,
    const float* __restrict__ Wo, u16* __restrict__ WoT){
    int bid = blockIdx.x;
    int t = threadIdx.x;
    if (bid < 288){
        __shared__ float T[64 * 65];
        int s = bid / 96, tile = bid % 96;
        int n0 = (tile / 24) * 64;
        int k0 = (tile % 24) * 64;
        const float* W = (s == 0) ? Wq : (s == 1 ? Wk : Wv);
        int rA = t >> 3, c8 = (t & 7) * 8;
        #pragma unroll
        for (int rep = 0; rep < 2; ++rep){
            int rr = rep * 32 + rA;
            const float* p = W + (size_t)(k0 + rr) * HD + n0 + c8;
            f32x4 a = *(const f32x4*)p, b = *(const f32x4*)(p + 4);
            #pragma unroll
            for (int e = 0; e < 4; ++e){
                T[rr * 65 + c8 + e]     = a[e];
                T[rr * 65 + c8 + 4 + e] = b[e];
            }
        }
        __syncthreads();
        #pragma unroll
        for (int rep = 0; rep < 2; ++rep){
            int rn = rep * 32 + rA;
            u16x8 o;
            #pragma unroll
            for (int e = 0; e < 8; ++e) o[e] = f2b(T[(c8 + e) * 65 + rn]);
            *(u16x8*)&Wt[(size_t)s * WSZ + (size_t)(n0 + rn) * DIMM + k0 + c8] = o;
        }
        return;
    }
    if (bid >= 305){
        // Wo [256][1536] fp32 -> WoT [1536][256] bf16
        __shared__ float T[64 * 65];
        int tile = bid - 305;             // 0..95
        int n0 = (tile / 4) * 64;         // 24 n-tiles
        int k0 = (tile % 4) * 64;         // 4 k-tiles
        int rA = t >> 3, c8 = (t & 7) * 8;
        #pragma unroll
        for (int rep = 0; rep < 2; ++rep){
            int rr = rep * 32 + rA;
            const float* p = Wo + (size_t)(k0 + rr) * DIMM + n0 + c8;
            f32x4 a = *(const f32x4*)p, b = *(const f32x4*)(p + 4);
            #pragma unroll
            for (int e = 0; e < 4; ++e){
                T[rr * 65 + c8 + e]     = a[e];
                T[rr * 65 + c8 + 4 + e] = b[e];
            }
        }
        __syncthreads();
        #pragma unroll
        for (int rep = 0; rep < 2; ++rep){
            int rn = rep * 32 + rA;
            u16x8 o;
            #pragma unroll
            for (int e = 0; e < 8; ++e) o[e] = f2b(T[(c8 + e) * 65 + rn]);
            *(u16x8*)&WoT[(size_t)(n0 + rn) * HD + k0 + c8] = o;
        }
        return;
    }
    if (bid == 304){
        int h = t >> 6, d = t & 63;
        float w1[32], w2[32];
        #pragma unroll
        for (int fm = 0; fm < 32; ++fm){
            w1[fm] = Wrel[(size_t)fm * HD + h * DK + d];
            w2[fm] = Wrel[(size_t)(32 + fm) * HD + h * DK + d];
        }
        float a1 = 0.f, a2 = 0.f;
        #pragma unroll
        for (int fm = 31; fm >= 0; --fm){
            a1 += w1[fm];
            a2 += w2[fm];
            WsP[(h * 32 + fm) * 64 + d] = f2b(a1 + a2);
            WsM[(h * 32 + fm) * 64 + d] = f2b(a1 - a2);
        }
        return;
    }
    int d = (bid - 288) * 256 + t;
    float lg = logf((float)(N_SEQ + 1)) * (1.0f / 32.0f);
    float ad = (float)d;
    int fm = 0;
    for (int f = 0; f < 32; ++f){
        float cw = expf(lg * (float)(f + 1)) - 1.0f;
        fm += (cw <= ad) ? 1 : 0;
    }
    fmt[d] = (unsigned char)fm;
}

// ---------------------------------------------------------------------------
// QKV projection v6: M-tile 64 + BK=128 (6 iterations, 16 MFMA per barrier
// pair) + chunked XCD swizzle. Grid 768 (3/CU), LDS 34.8 KB (4/CU capacity).
// Per m-group, the 12 sharer blocks (3 proj x 4 n-tiles) stay on one XCD.
// ---------------------------------------------------------------------------
__global__ __launch_bounds__(256) void qkv_kernel(const float* __restrict__ X,
    const u16* __restrict__ Wt,
    u16* __restrict__ Q, u16* __restrict__ K, u16* __restrict__ Vt){
    __shared__ __align__(16) u16 xs[64 * 136];
    __shared__ __align__(16) u16 bs[64 * 136];
    int lid = blockIdx.x;                 // 0..767
    int xcd = lid & 7, loc = lid >> 3;
    int sw  = xcd * 96 + loc;             // chunked work id (768 = 8*96)
    int mg  = sw / 12, inner = sw % 12;
    int s  = inner >> 2;                  // 0:Q 1:K 2:V
    int n0 = (inner & 3) * 64;
    int m0 = mg * 64;
    int t = threadIdx.x;
    int w = t >> 6, lane = t & 63, qd = lane >> 4, l15 = lane & 15;
    int r  = t >> 3;                      // 0..31
    int cv = (t & 7) * 16;                // 16-wide column chunk
    f32x4 acc[4] = {{0,0,0,0},{0,0,0,0},{0,0,0,0},{0,0,0,0}};

    f32x4 xa[2][4];
    u16x8 wv[2][2];
    auto LOAD = [&](int k0){
        #pragma unroll
        for (int rep = 0; rep < 2; ++rep){
            int rr = rep * 32 + r;
            size_t xi = (size_t)(m0 + rr) * DIMM + k0 + cv;
            #pragma unroll
            for (int e = 0; e < 4; ++e) xa[rep][e] = *(const f32x4*)(X + xi + e * 4);
            const u16* wp = &Wt[(size_t)s * WSZ + (size_t)(n0 + rr) * DIMM + k0 + cv];
            wv[rep][0] = *(const u16x8*)wp;
            wv[rep][1] = *(const u16x8*)(wp + 8);
        }
    };
    auto STORE = [&](){
        #pragma unroll
        for (int rep = 0; rep < 2; ++rep){
            int rr = rep * 32 + r;
            u16x8 xv0, xv1;
            #pragma unroll
            for (int e = 0; e < 4; ++e){
                xv0[e] = f2b(xa[rep][0][e]); xv0[4 + e] = f2b(xa[rep][1][e]);
                xv1[e] = f2b(xa[rep][2][e]); xv1[4 + e] = f2b(xa[rep][3][e]);
            }
            *(u16x8*)&xs[rr * 136 + cv]     = xv0;
            *(u16x8*)&xs[rr * 136 + cv + 8] = xv1;
            *(u16x8*)&bs[rr * 136 + cv]     = wv[rep][0];
            *(u16x8*)&bs[rr * 136 + cv + 8] = wv[rep][1];
        }
    };

    LOAD(0);
    for (int k0 = 0; k0 < DIMM; k0 += 128){
        STORE();
        __syncthreads();
        if (k0 + 128 < DIMM) LOAD(k0 + 128);
        #pragma unroll
        for (int kc = 0; kc < 4; ++kc){
            bf16x8 a = ldfrag(&xs[(w * 16 + l15) * 136 + kc * 32 + qd * 8]);
            #pragma unroll
            for (int nt = 0; nt < 4; ++nt){
                bf16x8 b = ldfrag(&bs[(nt * 16 + l15) * 136 + kc * 32 + qd * 8]);
                acc[nt] = __builtin_amdgcn_mfma_f32_16x16x32_bf16(a, b, acc[nt], 0, 0, 0);
            }
        }
        __syncthreads();
    }

    int row0 = m0 + w * 16 + qd * 4;
    if (s == 0){
        #pragma unroll
        for (int nt = 0; nt < 4; ++nt){
            int col = n0 + nt * 16 + l15;
            #pragma unroll
            for (int reg = 0; reg < 4; ++reg)
                Q[(size_t)(row0 + reg) * HD + col] = f2b(acc[nt][reg] * QK_SCALE);
        }
    } else if (s == 1){
        #pragma unroll
        for (int nt = 0; nt < 4; ++nt){
            int col = n0 + nt * 16 + l15;
            #pragma unroll
            for (int reg = 0; reg < 4; ++reg)
                K[(size_t)(row0 + reg) * HD + col] = f2b(acc[nt][reg]);
        }
    } else {
        #pragma unroll
        for (int nt = 0; nt < 4; ++nt){
            int col = n0 + nt * 16 + l15;
            u16x4 pv;
            #pragma unroll
            for (int reg = 0; reg < 4; ++reg) pv[reg] = f2b(acc[nt][reg]);
            *(u16x4*)&Vt[(size_t)col * N_SEQ + row0] = pv;
        }
    }
}

// ---------------------------------------------------------------------------
// Flash attention — R5-proven kernel, byte-identical (68.5 µs at ref clock).
// ---------------------------------------------------------------------------
__global__ __launch_bounds__(256) void attn_kernel(const u16* __restrict__ Q,
    const u16* __restrict__ Kg, const u16* __restrict__ Vt,
    const u16* __restrict__ WsPg, const u16* __restrict__ WsMg,
    const unsigned char* __restrict__ fmtg,
    const float* __restrict__ CB, const float* __restrict__ PB,
    u16* __restrict__ OpU, float* __restrict__ mpart, float* __restrict__ lpart){
    __shared__ __align__(16) unsigned char smem[39936];
    u16* Ks   = (u16*)(smem);             // [64][72]  main loop
    u16* Vts  = (u16*)(smem + 9216);      // [64][72]  main loop
    u16* Qs   = (u16*)(smem);             // init alias: [128][72]
    u16* relP = (u16*)(smem + 18432);     // [128][34] u16 (slot 0 = d==0 value)
    u16* relM = (u16*)(smem + 27136);     // [128][34] u16
    unsigned char* fmt = smem + 35840;    // 4096
    u16* WsPs = (u16*)(smem + 18432);     // init alias: [32][72]
    u16* WsMs = (u16*)(smem + 23040);

    int i0   = blockIdx.x * 128;
    int h    = blockIdx.y;
    int half = blockIdx.z;                // 0..7
    int bid  = blockIdx.x * NH + h;       // 0..127
    int jbase = half * (N_SEQ / KSPLIT);
    const int NT = (N_SEQ / KSPLIT) / 64; // 8 tiles
    int t = threadIdx.x;
    int w = t >> 6, lane = t & 63, l31 = lane & 31, hbit = lane >> 5;
    int h8 = hbit * 8;
    int i_loc = w * 32 + l31;             // this lane's softmax row (block-local)

    int sr = t >> 3, scv = (t & 7) * 8;
    u16x8 kr0, kr1, vr0, vr1;
    auto LOAD = [&](int j0){
        kr0 = *(const u16x8*)&Kg[(size_t)(j0 + sr)      * HD + h * DK + scv];
        kr1 = *(const u16x8*)&Kg[(size_t)(j0 + 32 + sr) * HD + h * DK + scv];
        vr0 = *(const u16x8*)&Vt[(size_t)(h * 64 + sr)      * N_SEQ + j0 + scv];
        vr1 = *(const u16x8*)&Vt[(size_t)(h * 64 + 32 + sr) * N_SEQ + j0 + scv];
    };
    auto STORE = [&](){
        *(u16x8*)&Ks [(sr)      * 72 + scv] = kr0;
        *(u16x8*)&Ks [(32 + sr) * 72 + scv] = kr1;
        *(u16x8*)&Vts[(sr)      * 72 + scv] = vr0;
        *(u16x8*)&Vts[(32 + sr) * 72 + scv] = vr1;
    };
    LOAD(jbase);

    // ---- init staging: Q rows (raw bf16), Wsuf slices, fmt ----
    #pragma unroll
    for (int rep = 0; rep < 4; ++rep){
        int vid = rep * 256 + t;
        int r  = vid >> 3;
        int cv = (vid & 7) * 8;
        *(u16x8*)&Qs[r * 72 + cv] = *(const u16x8*)&Q[(size_t)(i0 + r) * HD + h * DK + cv];
    }
    {
        int r = t >> 3, cv = (t & 7) * 8;
        *(u16x8*)&WsPs[r * 72 + cv] = *(const u16x8*)&WsPg[(h * 32 + r) * 64 + cv];
        *(u16x8*)&WsMs[r * 72 + cv] = *(const u16x8*)&WsMg[(h * 32 + r) * 64 + cv];
    }
    ((uint4*)fmt)[t] = ((const uint4*)fmtg)[t];
    __syncthreads();

    // ---- per-lane Q fragments (B-operand layout), bias + LOG2E folded ----
    bf16x8 qcF[4], qpF[4];
    #pragma unroll
    for (int kc = 0; kc < 4; ++kc){
        bf16x8 raw = ldfrag(&Qs[i_loc * 72 + kc * 16 + h8]);
        const float* cbp = CB + h * DK + kc * 16 + h8;
        const float* pbp = PB + h * DK + kc * 16 + h8;
        bf16x8 qc, qp;
        #pragma unroll
        for (int e = 0; e < 8; ++e){
            float qf = (float)raw[e];
            qc[e] = (__bf16)((qf + cbp[e]) * LOG2E);
            qp[e] = (__bf16)((qf + pbp[e]) * LOG2E);
        }
        qcF[kc] = qc; qpF[kc] = qp;
    }

    // ---- rel tables via MFMA: C[fm][i] = Wsuf[fm] . qp[i]  (log2 domain) ----
    f32x16 rP = zero16(), rM = zero16();
    #pragma unroll
    for (int kc = 0; kc < 4; ++kc){
        bf16x8 aP = ldfrag(&WsPs[l31 * 72 + kc * 16 + h8]);
        bf16x8 aM = ldfrag(&WsMs[l31 * 72 + kc * 16 + h8]);
        rP = __builtin_amdgcn_mfma_f32_32x32x16_bf16(aP, qpF[kc], rP, 0, 0, 0);
        rM = __builtin_amdgcn_mfma_f32_32x32x16_bf16(aM, qpF[kc], rM, 0, 0, 0);
    }
    __syncthreads();   // all LDS reads (Qs, Wsuf) done before overwrites

    // fm==0 happens only at dd==0 (cw_1 > 0), so slot 0 stores the d==0
    // value (s1 only) and the slow path indexes by fm with NO select.
    #pragma unroll
    for (int r = 0; r < 16; ++r){
        int fm = (r & 3) + 8 * (r >> 2) + 4 * hbit;
        relP[i_loc * 34 + fm] = f2b(rP[r]);
        relM[i_loc * 34 + fm] = f2b(rM[r]);
    }
    if (hbit == 0)
        relP[i_loc * 34 + 0] = f2b((rP[0] + rM[0]) * 0.5f);  // d==0: s1
    STORE();           // K/V tile 0 into seg0 (Qs dead)
    __syncthreads();

    // ---- main K-loop ----
    float mrow = -1e30f, lacc = 0.f;
    f32x16 oacc0 = zero16(), oacc1 = zero16();

#define MFMA32(A, B, C) __builtin_amdgcn_mfma_f32_32x32x16_bf16(A, B, C, 0, 0, 0)

#define PACK8(ST, WD) { \
    _Pragma("unroll") \
    for (int q_ = 0; q_ < 8; ++q_){ \
        float pa_ = EXP2(ST[2 * q_]     - bias); \
        float pc_ = EXP2(ST[2 * q_ + 1] - bias); \
        lsum += pa_ + pc_; \
        WD[q_] = (unsigned int)f2b(pa_) | ((unsigned int)f2b(pc_) << 16); \
    } }

    // halved-shuffle fragment build: send (hbit ? a : b), receive the
    // other half's counterpart; 2 shuffles per fragment instead of 4.
#define MKFRAG(DST, WD, ZZ) { \
    unsigned int a0_ = WD[(ZZ) * 4 + 0], a1_ = WD[(ZZ) * 4 + 1]; \
    unsigned int b0_ = WD[(ZZ) * 4 + 2], b1_ = WD[(ZZ) * 4 + 3]; \
    unsigned int sh0_ = (unsigned int)__shfl_xor((int)(hbit ? a0_ : b0_), 32); \
    unsigned int sh1_ = (unsigned int)__shfl_xor((int)(hbit ? a1_ : b1_), 32); \
    u32x4 fw_; \
    fw_[0] = hbit ? sh0_ : a0_; \
    fw_[1] = hbit ? sh1_ : a1_; \
    fw_[2] = hbit ? b0_  : sh0_; \
    fw_[3] = hbit ? b1_  : sh1_; \
    DST = __builtin_bit_cast(bf16x8, fw_); }

#define PVSTEP(PF, COL) { \
    oacc0 = MFMA32(PF, ldfrag(&Vts[(l31)      * 72 + (COL) + h8]), oacc0); \
    oacc1 = MFMA32(PF, ldfrag(&Vts[(32 + l31) * 72 + (COL) + h8]), oacc1); }

    const u16* relP_i = relP + i_loc * 34;
    const u16* relM_i = relM + i_loc * 34;

    for (int kt = 0; kt < NT; ++kt){
        int j0 = jbase + kt * 64;
        if (kt + 1 < NT) LOAD(j0 + 64);

        // S^T = K . Q^T : st0 = rows j 0..31, st1 = rows j 32..63; col i = lane&31
        f32x16 st0 = zero16(), st1 = zero16();
        __builtin_amdgcn_s_setprio(1);
        #pragma unroll
        for (int kc = 0; kc < 4; ++kc){
            bf16x8 k0 = ldfrag(&Ks[(l31)      * 72 + kc * 16 + h8]);
            bf16x8 k1 = ldfrag(&Ks[(32 + l31) * 72 + kc * 16 + h8]);
            st0 = MFMA32(k0, qcF[kc], st0);
            st1 = MFMA32(k1, qcF[kc], st1);
        }
        __builtin_amdgcn_s_setprio(0);

        // rel merge: fast path keeps st raw and folds relv into the exp bias
        int D = j0 - i0;
        int Di = D - i_loc;
        float relv = 0.f;
        bool fast = false; int fmU = 0; const u16* tabU = relP_i;
        if (D >= 128){
            int fa = fmt[D - 127], fb = fmt[D + 63];
            fast = (fa == fb); fmU = fa; tabU = relP_i;
        } else if (D <= -64){
            int fa = fmt[-D - 63], fb = fmt[-D + 127];
            fast = (fa == fb); fmU = fa; tabU = relM_i;
        }
        if (fast){
            relv = b2f(tabU[fmU]);
        } else {
            #pragma unroll
            for (int r = 0; r < 16; ++r){
                const int jb = (r & 3) + 8 * (r >> 2);
                int jbh = jb + 4 * hbit;
                {
                    int dd = Di + jbh;
                    int ad = dd < 0 ? -dd : dd;
                    int fm = fmt[ad];
                    const u16* tab = (dd >= 0) ? relP_i : relM_i;
                    st0[r] += b2f(tab[fm]);
                }
                {
                    int dd = Di + 32 + jbh;
                    int ad = dd < 0 ? -dd : dd;
                    int fm = fmt[ad];
                    const u16* tab = (dd >= 0) ? relP_i : relM_i;
                    st1[r] += b2f(tab[fm]);
                }
            }
        }

        // row max (lane-local + one cross-half shuffle); relv added once
        float mx = st0[0];
        #pragma unroll
        for (int r = 1; r < 16; ++r) mx = fmaxf(mx, st0[r]);
        #pragma unroll
        for (int r = 0; r < 16; ++r) mx = fmaxf(mx, st1[r]);
        mx = fmaxf(mx, __shfl_xor(mx, 32)) + relv;

        // defer-max (log2 domain, THR = 11 ~ e^7.6)
        if (!__all(mx - mrow <= 11.0f)){
            float mnew = fmaxf(mrow, mx);
            float alpha = EXP2(mrow - mnew);
            mrow = mnew;
            lacc *= alpha;
            #pragma unroll
            for (int r = 0; r < 16; ++r){
                float ar = __shfl(alpha, (r & 3) + 8 * (r >> 2) + 4 * hbit);
                oacc0[r] *= ar; oacc1[r] *= ar;
            }
        }

        // P = exp2(st - bias), bias = mrow - relv; l from unrounded floats
        float bias = mrow - relv;
        float lsum = 0.f;
        unsigned int wds0[8], wds1[8];
        PACK8(st0, wds0)
        PACK8(st1, wds1)
        lacc += lsum + __shfl_xor(lsum, 32);

        // in-register transpose to PV A-fragments (rows i = lane&31)
        bf16x8 pf0, pf1, pf2, pf3;
        MKFRAG(pf0, wds0, 0)   // j  0..15
        MKFRAG(pf1, wds0, 1)   // j 16..31
        MKFRAG(pf2, wds1, 0)   // j 32..47
        MKFRAG(pf3, wds1, 1)   // j 48..63
        __builtin_amdgcn_s_setprio(1);
        PVSTEP(pf0,  0)
        PVSTEP(pf1, 16)
        PVSTEP(pf2, 32)
        PVSTEP(pf3, 48)
        __builtin_amdgcn_s_setprio(0);

        __syncthreads();
        if (kt + 1 < NT) STORE();
        __syncthreads();
    }

    // ---- write partials ----
    size_t pb = ((size_t)half * 128 + bid) * 128;
    #pragma unroll
    for (int r = 0; r < 16; ++r){
        int iO = w * 32 + (r & 3) + 8 * (r >> 2) + 4 * hbit;
        OpU[(pb + iO) * 64 + l31]      = f2b(oacc0[r]);
        OpU[(pb + iO) * 64 + 32 + l31] = f2b(oacc1[r]);
    }
    if (hbit == 0){
        mpart[pb + i_loc] = mrow;
        lpart[pb + i_loc] = lacc;
    }
#undef MFMA32
#undef PACK8
#undef MKFRAG
#undef PVSTEP
}

// ---------------------------------------------------------------------------
// Combine 8 K-eighths -> normalized bf16 Oatt (512 blocks).
// ---------------------------------------------------------------------------
__global__ __launch_bounds__(256) void combine_kernel(const u16* __restrict__ OpU,
    const float* __restrict__ mpart, const float* __restrict__ lpart,
    u16* __restrict__ Oatt){
    int h = blockIdx.y;
    int t = threadIdx.x;
    int r = t >> 3, cb = (t & 7) * 8;
    int i = blockIdx.x * 32 + r;
    int bid = (i >> 7) * NH + h;
    int ri = i & 127;
    size_t pr[8];
    float ms[8], ls[8];
    float m = -1e30f;
    #pragma unroll
    for (int s = 0; s < 8; ++s){
        pr[s] = ((size_t)s * 128 + bid) * 128 + ri;
        ms[s] = mpart[pr[s]];
        ls[s] = lpart[pr[s]];
        m = fmaxf(m, ms[s]);
    }
    float den = 0.f, wgt[8];
    #pragma unroll
    for (int s = 0; s < 8; ++s){ wgt[s] = EXP2(ms[s] - m); den += wgt[s] * ls[s]; }
    float inv = 1.0f / fmaxf(den, 1e-30f);
    float o[8];
    #pragma unroll
    for (int e = 0; e < 8; ++e) o[e] = 0.f;
    #pragma unroll
    for (int s = 0; s < 8; ++s){
        u16x8 a = *(const u16x8*)&OpU[pr[s] * 64 + cb];
        #pragma unroll
        for (int e = 0; e < 8; ++e) o[e] += wgt[s] * b2f(a[e]);
    }
    u16x8 rv;
    #pragma unroll
    for (int e = 0; e < 8; ++e) rv[e] = f2b(o[e] * inv);
    *(u16x8*)&Oatt[(size_t)i * HD + h * DK + cb] = rv;
}

// ---------------------------------------------------------------------------
// Output projection (bf16 WoT path), BK=128: 2 iterations, LDS 34.8 KB
// (4 blocks/CU), all-vector staging.
// ---------------------------------------------------------------------------
__global__ __launch_bounds__(256) void oproj_kernel(const u16* __restrict__ A,
    const u16* __restrict__ WoT, const float* __restrict__ bo,
    float* __restrict__ out, int m_base){
    __shared__ __align__(16) u16 xs[64 * 136];
    __shared__ __align__(16) u16 bs[64 * 136];
    int m0 = m_base + blockIdx.y * 64;
    int n0 = blockIdx.x * 64;
    int t = threadIdx.x;
    int w = t >> 6, lane = t & 63, qd = lane >> 4, l15 = lane & 15;
    int r  = t >> 3;                      // 0..31
    int cv = (t & 7) * 16;
    f32x4 acc[4] = {{0,0,0,0},{0,0,0,0},{0,0,0,0},{0,0,0,0}};
    for (int k0 = 0; k0 < HD; k0 += 128){
        #pragma unroll
        for (int rep = 0; rep < 2; ++rep){
            int rr = rep * 32 + r;
            const u16* ap = &A[(size_t)(m0 + rr) * HD + k0 + cv];
            const u16* wp = &WoT[(size_t)(n0 + rr) * HD + k0 + cv];
            *(u16x8*)&xs[rr * 136 + cv]     = *(const u16x8*)ap;
            *(u16x8*)&xs[rr * 136 + cv + 8] = *(const u16x8*)(ap + 8);
            *(u16x8*)&bs[rr * 136 + cv]     = *(const u16x8*)wp;
            *(u16x8*)&bs[rr * 136 + cv + 8] = *(const u16x8*)(wp + 8);
        }
        __syncthreads();
        #pragma unroll
        for (int kc = 0; kc < 4; ++kc){
            bf16x8 a = ldfrag(&xs[(w * 16 + l15) * 136 + kc * 32 + qd * 8]);
            #pragma unroll
            for (int nt = 0; nt < 4; ++nt){
                bf16x8 b = ldfrag(&bs[(nt * 16 + l15) * 136 + kc * 32 + qd * 8]);
                acc[nt] = __builtin_amdgcn_mfma_f32_16x16x32_bf16(a, b, acc[nt], 0, 0, 0);
            }
        }
        __syncthreads();
    }
    #pragma unroll
    for (int nt = 0; nt < 4; ++nt)
        #pragma unroll
        for (int reg = 0; reg < 4; ++reg){
            int row = m0 + w * 16 + qd * 4 + reg;
            int col = n0 + nt * 16 + l15;
            out[(size_t)row * DIMM + col] = acc[nt][reg] + bo[col];
        }
}

// ---------------------------------------------------------------------------
// Output projection (fp32 Wo fallback, BK=64 — unchanged semantics).
// ---------------------------------------------------------------------------
__global__ __launch_bounds__(256) void oproj_f32_kernel(const u16* __restrict__ A,
    const float* __restrict__ Wo, const float* __restrict__ bo,
    float* __restrict__ out, int m_base){
    __shared__ __align__(16) u16 xs[64 * 72];
    __shared__ __align__(16) u16 bs[64 * 72];
    int m0 = m_base + blockIdx.y * 64;
    int n0 = blockIdx.x * 64;
    int t = threadIdx.x;
    int w = t >> 6, lane = t & 63, qd = lane >> 4, l15 = lane & 15;
    f32x4 acc[4] = {{0,0,0,0},{0,0,0,0},{0,0,0,0},{0,0,0,0}};
    for (int k0 = 0; k0 < HD; k0 += 64){
        #pragma unroll
        for (int rep = 0; rep < 2; ++rep){
            int vid = rep * 256 + t;
            int r  = vid >> 3;
            int cv = (vid & 7) * 8;
            *(u16x8*)&xs[r * 72 + cv] = *(const u16x8*)&A[(size_t)(m0 + r) * HD + k0 + cv];
            size_t wi = (size_t)(k0 + r) * DIMM + n0 + cv;
            f32x4 wa = *(const f32x4*)(Wo + wi), wb = *(const f32x4*)(Wo + wi + 4);
            u16x8 wv;
            #pragma unroll
            for (int e = 0; e < 4; ++e){ wv[e] = f2b(wa[e]); wv[4 + e] = f2b(wb[e]); }
            #pragma unroll
            for (int e = 0; e < 8; ++e) bs[(cv + e) * 72 + r] = wv[e];
        }
        __syncthreads();
        bf16x8 a0 = ldfrag(&xs[(w * 16 + l15) * 72 +  0 + qd * 8]);
        bf16x8 a1 = ldfrag(&xs[(w * 16 + l15) * 72 + 32 + qd * 8]);
        #pragma unroll
        for (int nt = 0; nt < 4; ++nt){
            bf16x8 b0 = ldfrag(&bs[(nt * 16 + l15) * 72 +  0 + qd * 8]);
            bf16x8 b1 = ldfrag(&bs[(nt * 16 + l15) * 72 + 32 + qd * 8]);
            acc[nt] = __builtin_amdgcn_mfma_f32_16x16x32_bf16(a0, b0, acc[nt], 0, 0, 0);
            acc[nt] = __builtin_amdgcn_mfma_f32_16x16x32_bf16(a1, b1, acc[nt], 0, 0, 0);
        }
        __syncthreads();
    }
    #pragma unroll
    for (int nt = 0; nt < 4; ++nt)
        #pragma unroll
        for (int reg = 0; reg < 4; ++reg){
            int row = m0 + w * 16 + qd * 4 + reg;
            int col = n0 + nt * 16 + l15;
            out[(size_t)row * DIMM + col] = acc[nt][reg] + bo[col];
        }
}

extern "C" void kernel_launch(void* const* d_in, const int* in_sizes, int n_in,
                              void* d_out, int out_size, void* d_ws, size_t ws_size,
                              hipStream_t stream){
    const float* X  = (const float*)d_in[0];
    const float* Wq = (const float*)d_in[1];
    const float* Wk = (const float*)d_in[2];
    const float* Wv = (const float*)d_in[3];
    const float* Wr = (const float*)d_in[4];
    const float* Wo = (const float*)d_in[5];
    const float* bo = (const float*)d_in[6];
    const float* CB = (const float*)d_in[7];
    const float* PB = (const float*)d_in[8];
    float* out = (float*)d_out;
    u16* base = (u16*)d_out;   // 12,582,912 u16 slots

    // d_out scratch (u16 offsets): Qb[0,1048576) Kb[1048576,2097152)
    // Vt[2097152,3145728) Wt[3145728,4325376) (dead after qkv; OpU overlays)
    // OpU[3145728,11534336) mpart/lpart f32 after.
    u16* Qb   = base;
    u16* Kb   = base + 1048576;
    u16* Vt   = base + 2097152;
    u16* Wt   = base + 3145728;
    u16* OpU  = base + 3145728;
    float* mpart = out + 5767168;
    float* lpart = out + 5898240;

    // d_ws layout: fmt[0,4096) WsP[4096,20480) WsM[20480,36864)
    //   WoT u16 @36864 (786,432 B) -> 823,296
    //   Oatt u16 @823,296 (2,097,152 B) -> 2,920,448
    unsigned char* fmtg = (unsigned char*)d_ws;
    u16* WsP = (u16*)((char*)d_ws + 4096);
    u16* WsM = (u16*)((char*)d_ws + 20480);
    u16* WoT = (u16*)((char*)d_ws + 36864);
    bool ws_ok = ws_size >= 2920448;

    prep_kernel<<<dim3(ws_ok ? 401 : 305), 256, 0, stream>>>(
        Wq, Wk, Wv, Wt, fmtg, Wr, WsP, WsM, Wo, WoT);
    qkv_kernel<<<dim3(768), 256, 0, stream>>>(X, Wt, Qb, Kb, Vt);
    attn_kernel<<<dim3(32, NH, KSPLIT), 256, 0, stream>>>(Qb, Kb, Vt, WsP, WsM,
                                                          fmtg, CB, PB,
                                                          OpU, mpart, lpart);

    if (ws_ok){
        u16* Oatt = (u16*)((char*)d_ws + 823296);
        combine_kernel<<<dim3(128, NH), 256, 0, stream>>>(OpU, mpart, lpart, Oatt);
        oproj_kernel<<<dim3(24, 64), 256, 0, stream>>>(Oatt, WoT, bo, out, 0);
    } else {
        // fallback: Oatt in d_out (overlays dead Qb) with descending-row
        // 3-split fp32-Wo oproj for WAR safety.
        u16* Oatt = base;
        combine_kernel<<<dim3(128, NH), 256, 0, stream>>>(OpU, mpart, lpart, Oatt);
        oproj_f32_kernel<<<dim3(24, 58), 256, 0, stream>>>(Oatt, Wo, bo, out, 384);
        oproj_f32_kernel<<<dim3(24,  5), 256, 0, stream>>>(Oatt, Wo, bo, out, 64);
        oproj_f32_kernel<<<dim3(24,  1), 256, 0, stream>>>(Oatt, Wo, bo, out, 0);
    }
}